// Round 4
// baseline (4281.530 us; speedup 1.0000x reference)
//
#include <hip/hip_runtime.h>
#include <stdint.h>

#define BATCH 16
#define NPTS  8192
#define KNN   16
#define NROWS (BATCH*NPTS)     // 131072
#define EPSBN 1e-5f
#define DEGINV (1.0f/17.0f)

// order-preserving float <-> uint encoding (for atomic min/max)
__device__ __forceinline__ unsigned fenc(float f) {
    unsigned u = __float_as_uint(f);
    return (int)u >= 0 ? (u | 0x80000000u) : ~u;
}
__device__ __forceinline__ float fdec(unsigned k) {
    return (k & 0x80000000u) ? __uint_as_float(k & 0x7FFFFFFFu) : __uint_as_float(~k);
}

// stats zone layout (floats):
#define SZ_S1    0        // stats1: [64]=sum, [64..127]=sumsq
#define SZ_S2P   128      // stats2p: 16 x (128 sum + 128 sumsq) = 4096
#define SZ_S3P   4224     // stats3p: 16 x (512 sum + 512 sumsq) = 16384
#define SZ_S4    20608    // stats4: 512 sum + 512 sumsq = 1024
#define SZ_C1    21632    // c1stats: 3 sum + 3 sumsq (8 padded)
#define SZ_GN    21640    // gnstats: 3 sum + 3 sumsq (8 padded)
#define SZ_D2    21648    // statsd2: 3 sum + 3 sumsq (8 padded)
#define SZ_TOT   21656

// ---------------------------------------------------------------------------
// k_prep: zero stats zone, init min/max sentinels,
// precompute per-node grid features gn[n][3] = grid_n @ d1_w[512:514] + d1_b
// ---------------------------------------------------------------------------
__global__ __launch_bounds__(256) void k_prep(
    const float* __restrict__ d1w, const float* __restrict__ d1b,
    float* __restrict__ gn, float* __restrict__ statszone, unsigned* __restrict__ mm)
{
    int t = blockIdx.x * 256 + threadIdx.x;
    int NT_ = gridDim.x * 256;
    for (int i = t; i < SZ_TOT; i += NT_) statszone[i] = 0.f;
    for (int i = t; i < 8192; i += NT_) mm[i] = 0u;                 // max enc
    for (int i = t; i < 8192; i += NT_) mm[8192 + i] = 0xFFFFFFFFu; // min enc
    for (int n = t; n < 8192; n += NT_) {
        int ix = n / 65, iy = n % 65;
        float gx = 1.f + ix * (119.f / 128.f);
        float gy = 1.f + iy * (59.f / 64.f);
        #pragma unroll
        for (int j = 0; j < 3; j++)
            gn[n * 3 + j] = gx * d1w[512 * 3 + j] + gy * d1w[513 * 3 + j] + d1b[j];
    }
}

// ---------------------------------------------------------------------------
// k_cov_e1: local covariance features + Linear(12,64)  -> a1 [131072][64] f32
// ---------------------------------------------------------------------------
__global__ __launch_bounds__(256) void k_cov_e1(
    const float* __restrict__ data, const int* __restrict__ knn,
    const float* __restrict__ e1w, const float* __restrict__ e1b,
    float* __restrict__ a1)
{
    __shared__ float w[12 * 64];
    __shared__ float bias[64];
    int tid = threadIdx.x;
    for (int i = tid; i < 768; i += 256) w[i] = e1w[i];
    if (tid < 64) bias[tid] = e1b[tid];
    __syncthreads();

    int gid = blockIdx.x * 256 + tid;      // global node row
    int b = gid >> 13;
    const float* db = data + (size_t)b * NPTS * 3;
    const int4* k4 = (const int4*)knn + gid * 4;

    float sx = 0, sy = 0, sz = 0, Sxx = 0, Sxy = 0, Sxz = 0, Syy = 0, Syz = 0, Szz = 0;
    #pragma unroll
    for (int jj = 0; jj < 4; jj++) {
        int4 q = k4[jj];
        int id[4] = {q.x, q.y, q.z, q.w};
        #pragma unroll
        for (int u = 0; u < 4; u++) {
            const float* p = db + (size_t)id[u] * 3;
            float x = p[0], y = p[1], z = p[2];
            sx += x; sy += y; sz += z;
            Sxx += x * x; Sxy += x * y; Sxz += x * z;
            Syy += y * y; Syz += y * z; Szz += z * z;
        }
    }
    float mx = sx * (1.f / 16.f), my = sy * (1.f / 16.f), mz = sz * (1.f / 16.f);
    const float inv15 = 1.f / 15.f;
    float x12[12];
    x12[0] = data[(size_t)gid * 3 + 0];
    x12[1] = data[(size_t)gid * 3 + 1];
    x12[2] = data[(size_t)gid * 3 + 2];
    x12[3] = (Sxx - 16.f * mx * mx) * inv15;
    x12[4] = (Sxy - 16.f * mx * my) * inv15;
    x12[5] = (Sxz - 16.f * mx * mz) * inv15;
    x12[6] = x12[4];
    x12[7] = (Syy - 16.f * my * my) * inv15;
    x12[8] = (Syz - 16.f * my * mz) * inv15;
    x12[9] = x12[5];
    x12[10] = x12[8];
    x12[11] = (Szz - 16.f * mz * mz) * inv15;

    float* arow = a1 + (size_t)gid * 64;
    for (int c0 = 0; c0 < 64; c0 += 4) {
        float4 v;
        float* vv = (float*)&v;
        #pragma unroll
        for (int u = 0; u < 4; u++) {
            int c = c0 + u;
            float acc = bias[c];
            #pragma unroll
            for (int i = 0; i < 12; i++) acc += x12[i] * w[i * 64 + c];
            vv[u] = acc;
        }
        *(float4*)(arow + c0) = v;
    }
}

// ---------------------------------------------------------------------------
// k_reduce_a1: per-channel sum/sumsq of a1 (C=64) -> stats1
// ---------------------------------------------------------------------------
__global__ __launch_bounds__(256) void k_reduce_a1(
    const float* __restrict__ a1, float* __restrict__ stats1)
{
    int tid = threadIdx.x;
    int c = tid & 63, rq = tid >> 6;
    float s = 0.f, q = 0.f;
    for (int row = blockIdx.x * 4 + rq; row < NROWS; row += gridDim.x * 4) {
        float v = a1[(size_t)row * 64 + c];
        s += v; q += v * v;
    }
    __shared__ float red[2][256];
    red[0][tid] = s; red[1][tid] = q;
    __syncthreads();
    if (tid < 64) {
        s = red[0][tid] + red[0][tid + 64] + red[0][tid + 128] + red[0][tid + 192];
        q = red[1][tid] + red[1][tid + 64] + red[1][tid + 128] + red[1][tid + 192];
        atomicAdd(stats1 + tid, s);
        atomicAdd(stats1 + 64 + tid, q);
    }
}

// ---------------------------------------------------------------------------
// k_gcnv<CIN,COUT,NPARTS,STORE>: fused bn_relu(input) -> neighbor-sum ->
// plain-VALU fp32 matmul (correctness-checkpoint version, no MFMA).
// STORE=true : writes aout (pre-BN) + per-batch stats partials
// STORE=false: no store; per-batch stats partials + per-(b,c) min/max
// Block = 256 threads = 16 nodes x 16 channel-groups. Grid = NROWS/16.
// ---------------------------------------------------------------------------
template <int CIN, int COUT, int NPARTS, bool STORE>
__global__ __launch_bounds__(256) void k_gcnv(
    const float* __restrict__ ain, const int* __restrict__ knn,
    const float* __restrict__ Wf, const float* __restrict__ bias,
    const float* __restrict__ statsIn, const float* __restrict__ gamma, const float* __restrict__ beta,
    float* __restrict__ aout, float* __restrict__ statsOut, unsigned* __restrict__ mm)
{
    constexpr int NC = COUT / 16;           // channels per thread
    __shared__ float scsh[2][CIN];
    __shared__ int nidx[16 * KNN];
    __shared__ float s_lds[16][CIN + 1];
    __shared__ float red_s[4][COUT];
    __shared__ float red_q[4][COUT];
    __shared__ float red_mx[STORE ? 1 : 4][STORE ? 1 : COUT];
    __shared__ float red_mn[STORE ? 1 : 4][STORE ? 1 : COUT];

    int tid = threadIdx.x;
    int node0 = blockIdx.x * 16;
    int batch = node0 >> 13;

    // BN coefficients from (possibly partitioned) stats
    for (int ch = tid; ch < CIN; ch += 256) {
        float s = 0.f, q = 0.f;
        #pragma unroll
        for (int p = 0; p < NPARTS; p++) {
            s += statsIn[p * 2 * CIN + ch];
            q += statsIn[p * 2 * CIN + CIN + ch];
        }
        float m = s * (1.f / NROWS);
        float var = fmaxf(q * (1.f / NROWS) - m * m, 0.f);   // clamp: no NaN from rsqrt
        float sc = gamma[ch] * rsqrtf(var + EPSBN);
        scsh[0][ch] = sc;
        scsh[1][ch] = beta[ch] - m * sc;
    }
    for (int i = tid; i < 16 * KNN; i += 256) nidx[i] = knn[(size_t)node0 * KNN + i];
    __syncthreads();

    // gather: s = bn_relu(self) + sum_j bn_relu(neighbor_j), fp32 into LDS
    {
        constexpr int NG = 256 / CIN;
        int ch = tid & (CIN - 1);
        int grp = tid / CIN;
        float sc = scsh[0][ch], sh = scsh[1][ch];
        const float* abase = ain + (size_t)batch * NPTS * CIN;
        for (int r = grp; r < 16; r += NG) {
            int row = node0 + r;
            float acc = fmaxf(ain[(size_t)row * CIN + ch] * sc + sh, 0.f);
            #pragma unroll
            for (int j = 0; j < KNN; j++) {
                int src = nidx[r * KNN + j];
                acc += fmaxf(abase[(size_t)src * CIN + ch] * sc + sh, 0.f);
            }
            s_lds[r][ch] = acc;
        }
    }
    __syncthreads();

    // matmul: thread (nl, g) computes node nl, channels [g*NC, g*NC+NC)
    int g = tid & 15, nl = tid >> 4;
    int cbase = g * NC;
    int node = node0 + nl;

    float acc[NC];
    #pragma unroll
    for (int j = 0; j < NC; j++) acc[j] = 0.f;

    for (int k = 0; k < CIN; k++) {
        float sv = s_lds[nl][k];
        const float* wrow = Wf + (size_t)k * COUT + cbase;
        #pragma unroll
        for (int j = 0; j < NC; j += 4) {
            float4 w4 = *(const float4*)(wrow + j);
            acc[j + 0] += sv * w4.x;
            acc[j + 1] += sv * w4.y;
            acc[j + 2] += sv * w4.z;
            acc[j + 3] += sv * w4.w;
        }
    }

    // epilogue: /17 + bias; store; per-channel partials over this thread's node
    float vs[NC];
    #pragma unroll
    for (int j = 0; j < NC; j++)
        vs[j] = acc[j] * DEGINV + bias[cbase + j];
    if (STORE) {
        float* orow = aout + (size_t)node * COUT + cbase;
        #pragma unroll
        for (int j = 0; j < NC; j += 4) {
            float4 o; o.x = vs[j]; o.y = vs[j+1]; o.z = vs[j+2]; o.w = vs[j+3];
            *(float4*)(orow + j) = o;
        }
    }

    // reduce over the wave's 4 nodes (lanes l, l^16, l^32, l^48 share g)
    float ss[NC], qq2[NC], mx[NC], mn[NC];
    #pragma unroll
    for (int j = 0; j < NC; j++) {
        float v = vs[j];
        ss[j] = v; qq2[j] = v * v; mx[j] = v; mn[j] = v;
    }
    #pragma unroll
    for (int j = 0; j < NC; j++) {
        ss[j] += __shfl_xor(ss[j], 16);  ss[j] += __shfl_xor(ss[j], 32);
        qq2[j] += __shfl_xor(qq2[j], 16); qq2[j] += __shfl_xor(qq2[j], 32);
        if (!STORE) {
            mx[j] = fmaxf(mx[j], __shfl_xor(mx[j], 16)); mx[j] = fmaxf(mx[j], __shfl_xor(mx[j], 32));
            mn[j] = fminf(mn[j], __shfl_xor(mn[j], 16)); mn[j] = fminf(mn[j], __shfl_xor(mn[j], 32));
        }
    }
    int lane = tid & 63, wv = tid >> 6;
    if (lane < 16) {
        #pragma unroll
        for (int j = 0; j < NC; j++) {
            red_s[wv][cbase + j] = ss[j];
            red_q[wv][cbase + j] = qq2[j];
            if (!STORE) { red_mx[wv][cbase + j] = mx[j]; red_mn[wv][cbase + j] = mn[j]; }
        }
    }
    __syncthreads();
    for (int c = tid; c < COUT; c += 256) {
        float s4 = red_s[0][c] + red_s[1][c] + red_s[2][c] + red_s[3][c];
        float q4 = red_q[0][c] + red_q[1][c] + red_q[2][c] + red_q[3][c];
        atomicAdd(statsOut + (size_t)batch * 2 * COUT + c, s4);
        atomicAdd(statsOut + (size_t)batch * 2 * COUT + COUT + c, q4);
        if (!STORE) {
            float m4 = fmaxf(fmaxf(red_mx[0][c], red_mx[1][c]), fmaxf(red_mx[2][c], red_mx[3][c]));
            float n4 = fminf(fminf(red_mn[0][c], red_mn[1][c]), fminf(red_mn[2][c], red_mn[3][c]));
            atomicMax(mm + batch * COUT + c, fenc(m4));
            atomicMin(mm + BATCH * COUT + batch * COUT + c, fenc(n4));
        }
    }
}

// ---------------------------------------------------------------------------
// k_e2: pooled codeword from min/max + BN3, then Linear(512,512) -> a4, stats4
// one block per batch
// ---------------------------------------------------------------------------
__global__ __launch_bounds__(256) void k_e2(
    const float* __restrict__ stats3p, const unsigned* __restrict__ mm,
    const float* __restrict__ g2g, const float* __restrict__ g2be,
    const float* __restrict__ e2w, const float* __restrict__ e2b,
    float* __restrict__ a4, float* __restrict__ stats4)
{
    __shared__ float pooled[512];
    int b = blockIdx.x, tid = threadIdx.x;
    for (int c = tid; c < 512; c += 256) {
        float s = 0.f, qq = 0.f;
        #pragma unroll
        for (int p = 0; p < 16; p++) {
            s += stats3p[p * 1024 + c];
            qq += stats3p[p * 1024 + 512 + c];
        }
        float m = s * (1.f / NROWS);
        float var = fmaxf(qq * (1.f / NROWS) - m * m, 0.f);
        float sc = g2g[c] * rsqrtf(var + EPSBN);
        float sh = g2be[c] - m * sc;
        float amax = fdec(mm[b * 512 + c]);
        float amin = fdec(mm[8192 + b * 512 + c]);
        // max over nodes of relu(bn(a3)): affine+relu is monotone -> at an extreme
        pooled[c] = fmaxf(fmaxf(sc * amax + sh, 0.f), fmaxf(sc * amin + sh, 0.f));
    }
    __syncthreads();
    int ca = tid, cb = tid + 256;
    float acc1 = e2b[ca], acc2 = e2b[cb];
    for (int f = 0; f < 512; f++) {
        float pv = pooled[f];
        acc1 += pv * e2w[f * 512 + ca];
        acc2 += pv * e2w[f * 512 + cb];
    }
    a4[b * 512 + ca] = acc1; a4[b * 512 + cb] = acc2;
    atomicAdd(stats4 + ca, acc1); atomicAdd(stats4 + 512 + ca, acc1 * acc1);
    atomicAdd(stats4 + cb, acc2); atomicAdd(stats4 + 512 + cb, acc2 * acc2);
}

// ---------------------------------------------------------------------------
// k_code: BN4+relu -> code; c1 = code@d1_w[:512], c2 = code@d2_w[:512];
// c1 stats (over b) via atomics; block 0 also reduces gn stats (over n)
// ---------------------------------------------------------------------------
__global__ __launch_bounds__(256) void k_code(
    const float* __restrict__ a4, const float* __restrict__ stats4,
    const float* __restrict__ e2g, const float* __restrict__ e2be,
    const float* __restrict__ d1w, const float* __restrict__ d2w,
    const float* __restrict__ gn,
    float* __restrict__ c1, float* __restrict__ c2,
    float* __restrict__ c1stats, float* __restrict__ gnstats)
{
    int b = blockIdx.x, tid = threadIdx.x;
    int lane = tid & 63, wv = tid >> 6;
    float p1[3] = {0, 0, 0}, p2[3] = {0, 0, 0};
    for (int c = tid; c < 512; c += 256) {
        float s = stats4[c], qq = stats4[512 + c];
        float m = s * (1.f / 16.f);
        float var = fmaxf(qq * (1.f / 16.f) - m * m, 0.f);
        float sc = e2g[c] * rsqrtf(var + EPSBN);
        float sh = e2be[c] - m * sc;
        float cv = fmaxf(sc * a4[b * 512 + c] + sh, 0.f);
        #pragma unroll
        for (int j = 0; j < 3; j++) {
            p1[j] += cv * d1w[c * 3 + j];
            p2[j] += cv * d2w[c * 3 + j];
        }
    }
    __shared__ float red[4][6];
    #pragma unroll
    for (int j = 0; j < 3; j++)
        for (int off = 32; off; off >>= 1) {
            p1[j] += __shfl_xor(p1[j], off);
            p2[j] += __shfl_xor(p2[j], off);
        }
    if (lane == 0) {
        #pragma unroll
        for (int j = 0; j < 3; j++) { red[wv][j] = p1[j]; red[wv][3 + j] = p2[j]; }
    }
    __syncthreads();
    if (tid < 3) {
        float v = red[0][tid] + red[1][tid] + red[2][tid] + red[3][tid];
        c1[b * 3 + tid] = v;
        atomicAdd(c1stats + tid, v);
        atomicAdd(c1stats + 3 + tid, v * v);
    } else if (tid < 6) {
        int j = tid - 3;
        float v = red[0][tid] + red[1][tid] + red[2][tid] + red[3][tid];
        c2[b * 3 + j] = v;
    }
    if (blockIdx.x == 0) {
        float g1[3] = {0, 0, 0}, g2s[3] = {0, 0, 0};
        for (int n = tid; n < NPTS; n += 256) {
            #pragma unroll
            for (int j = 0; j < 3; j++) {
                float g = gn[n * 3 + j];
                g1[j] += g; g2s[j] += g * g;
            }
        }
        #pragma unroll
        for (int j = 0; j < 3; j++)
            for (int off = 32; off; off >>= 1) {
                g1[j] += __shfl_xor(g1[j], off);
                g2s[j] += __shfl_xor(g2s[j], off);
            }
        __shared__ float redg[4][6];
        if (lane == 0) {
            #pragma unroll
            for (int j = 0; j < 3; j++) { redg[wv][j] = g1[j]; redg[wv][3 + j] = g2s[j]; }
        }
        __syncthreads();
        if (tid < 6)
            gnstats[tid] = redg[0][tid] + redg[1][tid] + redg[2][tid] + redg[3][tid];
    }
}

// ---------------------------------------------------------------------------
// d1 BN coefs (exact product-grid decomposition)
// ---------------------------------------------------------------------------
__device__ __forceinline__ void d1_coefs(
    const float* c1stats, const float* gnstats,
    const float* d1g, const float* d1be, float* scd, float* shd)
{
    #pragma unroll
    for (int j = 0; j < 3; j++) {
        float mc = c1stats[j] * (1.f / 16.f), qc = c1stats[3 + j] * (1.f / 16.f);
        float mg = gnstats[j] * (1.f / 8192.f), qg = gnstats[3 + j] * (1.f / 8192.f);
        float m = mc + mg;
        float var = fmaxf((qc - mc * mc) + (qg - mg * mg), 0.f);  // cross term exactly 0
        float sc = d1g[j] * rsqrtf(var + EPSBN);
        scd[j] = sc;
        shd[j] = d1be[j] - m * sc;
    }
}

// ---------------------------------------------------------------------------
// k_d2stats: stats of a_d2 over (b,n)  (z3 recomputed from low-rank parts)
// ---------------------------------------------------------------------------
__global__ __launch_bounds__(256) void k_d2stats(
    const float* __restrict__ c1, const float* __restrict__ c2, const float* __restrict__ gn,
    const float* __restrict__ c1stats, const float* __restrict__ gnstats,
    const float* __restrict__ d1g, const float* __restrict__ d1be,
    const float* __restrict__ d2w, const float* __restrict__ d2b,
    float* __restrict__ statsd2)
{
    int gid = blockIdx.x * 256 + threadIdx.x;
    int b = gid >> 13, n = gid & 8191;
    int lane = threadIdx.x & 63, wv = threadIdx.x >> 6;
    float scd[3], shd[3];
    d1_coefs(c1stats, gnstats, d1g, d1be, scd, shd);
    float z3[3];
    #pragma unroll
    for (int j = 0; j < 3; j++)
        z3[j] = fmaxf(scd[j] * (c1[b * 3 + j] + gn[n * 3 + j]) + shd[j], 0.f);
    float vals[6];
    #pragma unroll
    for (int u = 0; u < 3; u++) {
        float a = c2[b * 3 + u]
                + z3[0] * d2w[512 * 3 + u]
                + z3[1] * d2w[513 * 3 + u]
                + z3[2] * d2w[514 * 3 + u]
                + d2b[u];
        vals[u] = a; vals[3 + u] = a * a;
    }
    #pragma unroll
    for (int j = 0; j < 6; j++)
        for (int off = 32; off; off >>= 1) vals[j] += __shfl_xor(vals[j], off);
    __shared__ float red[4][6];
    if (lane == 0) {
        #pragma unroll
        for (int j = 0; j < 6; j++) red[wv][j] = vals[j];
    }
    __syncthreads();
    if (threadIdx.x < 6)
        atomicAdd(statsd2 + threadIdx.x,
                  red[0][threadIdx.x] + red[1][threadIdx.x] + red[2][threadIdx.x] + red[3][threadIdx.x]);
}

// ---------------------------------------------------------------------------
// k_out: final BN+relu -> fp32 output [b][n][3]
// ---------------------------------------------------------------------------
__global__ __launch_bounds__(256) void k_out(
    const float* __restrict__ c1, const float* __restrict__ c2, const float* __restrict__ gn,
    const float* __restrict__ c1stats, const float* __restrict__ gnstats,
    const float* __restrict__ statsd2,
    const float* __restrict__ d1g, const float* __restrict__ d1be,
    const float* __restrict__ d2w, const float* __restrict__ d2b,
    const float* __restrict__ d2g, const float* __restrict__ d2be,
    float* __restrict__ out)
{
    int gid = blockIdx.x * 256 + threadIdx.x;
    int b = gid >> 13, n = gid & 8191;
    float scd[3], shd[3];
    d1_coefs(c1stats, gnstats, d1g, d1be, scd, shd);
    float z3[3];
    #pragma unroll
    for (int j = 0; j < 3; j++)
        z3[j] = fmaxf(scd[j] * (c1[b * 3 + j] + gn[n * 3 + j]) + shd[j], 0.f);
    #pragma unroll
    for (int u = 0; u < 3; u++) {
        float a = c2[b * 3 + u]
                + z3[0] * d2w[512 * 3 + u]
                + z3[1] * d2w[513 * 3 + u]
                + z3[2] * d2w[514 * 3 + u]
                + d2b[u];
        float m2 = statsd2[u] * (1.f / (float)NROWS);
        float v2 = fmaxf(statsd2[3 + u] * (1.f / (float)NROWS) - m2 * m2, 0.f);
        float sc = d2g[u] * rsqrtf(v2 + EPSBN);
        float sh = d2be[u] - m2 * sc;
        out[(size_t)gid * 3 + u] = fmaxf(sc * a + sh, 0.f);
    }
}

// ---------------------------------------------------------------------------
extern "C" void kernel_launch(void* const* d_in, const int* in_sizes, int n_in,
                              void* d_out, int out_size, void* d_ws, size_t ws_size,
                              hipStream_t stream)
{
    (void)in_sizes; (void)n_in; (void)out_size; (void)ws_size;
    // All float inputs are FP32 per the reference (only knn is int32).
    const float* data = (const float*)d_in[0];
    const int*   knn  = (const int*)d_in[1];
    const float* e1w = (const float*)d_in[2],  *e1b = (const float*)d_in[3];
    const float* e1g = (const float*)d_in[4],  *e1be = (const float*)d_in[5];
    const float* gc1w = (const float*)d_in[6], *gc1b = (const float*)d_in[7];
    const float* g1g = (const float*)d_in[8],  *g1be = (const float*)d_in[9];
    const float* gc2w = (const float*)d_in[10], *gc2b = (const float*)d_in[11];
    const float* g2g = (const float*)d_in[12], *g2be = (const float*)d_in[13];
    const float* e2w = (const float*)d_in[14], *e2b = (const float*)d_in[15];
    const float* e2g = (const float*)d_in[16], *e2be = (const float*)d_in[17];
    const float* d1w = (const float*)d_in[18], *d1b = (const float*)d_in[19];
    const float* d1g = (const float*)d_in[20], *d1be = (const float*)d_in[21];
    const float* d2w = (const float*)d_in[22], *d2b = (const float*)d_in[23];
    const float* d2g = (const float*)d_in[24], *d2be = (const float*)d_in[25];

    char* p = (char*)d_ws;
    auto alloc = [&](size_t bytes) -> void* {
        void* r = (void*)p;
        p += (bytes + 255) & ~(size_t)255;
        return r;
    };
    float* a1 = (float*)alloc((size_t)NROWS * 64 * 4);     // 33.5 MB
    float* a2 = (float*)alloc((size_t)NROWS * 128 * 4);    // 67 MB
    float* statszone = (float*)alloc(SZ_TOT * 4);
    float* stats1  = statszone + SZ_S1;
    float* stats2p = statszone + SZ_S2P;
    float* stats3p = statszone + SZ_S3P;
    float* stats4  = statszone + SZ_S4;
    float* c1stats = statszone + SZ_C1;
    float* gnstats = statszone + SZ_GN;
    float* statsd2 = statszone + SZ_D2;
    unsigned* mm = (unsigned*)alloc(16384 * 4);
    float* a4 = (float*)alloc(16 * 512 * 4);
    float* c1 = (float*)alloc(64 * 4);
    float* c2 = (float*)alloc(64 * 4);
    float* gn = (float*)alloc(8192 * 3 * 4);

    k_prep<<<64, 256, 0, stream>>>(d1w, d1b, gn, statszone, mm);
    k_cov_e1<<<512, 256, 0, stream>>>(data, knn, e1w, e1b, a1);
    k_reduce_a1<<<256, 256, 0, stream>>>(a1, stats1);
    k_gcnv<64, 128, 1, true><<<NROWS / 16, 256, 0, stream>>>(
        a1, knn, gc1w, gc1b, stats1, e1g, e1be, a2, stats2p, nullptr);
    k_gcnv<128, 512, 16, false><<<NROWS / 16, 256, 0, stream>>>(
        a2, knn, gc2w, gc2b, stats2p, g1g, g1be, nullptr, stats3p, mm);
    k_e2<<<16, 256, 0, stream>>>(stats3p, mm, g2g, g2be, e2w, e2b, a4, stats4);
    k_code<<<16, 256, 0, stream>>>(a4, stats4, e2g, e2be, d1w, d2w, gn, c1, c2, c1stats, gnstats);
    k_d2stats<<<512, 256, 0, stream>>>(c1, c2, gn, c1stats, gnstats, d1g, d1be, d2w, d2b, statsd2);
    k_out<<<512, 256, 0, stream>>>(c1, c2, gn, c1stats, gnstats, statsd2,
                                   d1g, d1be, d2w, d2b, d2g, d2be, (float*)d_out);
}

// Round 6
// 497.378 us; speedup vs baseline: 8.6082x; 8.6082x over previous
//
#include <hip/hip_runtime.h>
#include <hip/hip_bf16.h>
#include <stdint.h>

#define BATCH 16
#define NPTS  8192
#define KNN   16
#define NROWS (BATCH*NPTS)     // 131072
#define EPSBN 1e-5f
#define DEGINV (1.0f/17.0f)

typedef short bf16x8 __attribute__((ext_vector_type(8)));
typedef float f32x4  __attribute__((ext_vector_type(4)));

__device__ __forceinline__ unsigned short f2bu(float f) {
    __hip_bfloat16 h = __float2bfloat16(f);
    return *reinterpret_cast<unsigned short*>(&h);
}
__device__ __forceinline__ float bu2f(unsigned short u) {
    return __uint_as_float(((unsigned)u) << 16);
}
// order-preserving float <-> uint encoding (for atomic min/max)
__device__ __forceinline__ unsigned fenc(float f) {
    unsigned u = __float_as_uint(f);
    return (int)u >= 0 ? (u | 0x80000000u) : ~u;
}
__device__ __forceinline__ float fdec(unsigned k) {
    return (k & 0x80000000u) ? __uint_as_float(k & 0x7FFFFFFFu) : __uint_as_float(~k);
}

// stats zone layout (floats):
#define SZ_S1    0        // stats1: [64]=sum, [64..127]=sumsq
#define SZ_S2P   128      // stats2p: 16 x (128 sum + 128 sumsq) = 4096
#define SZ_S3P   4224     // stats3p: 16 x (512 sum + 512 sumsq) = 16384
#define SZ_S4    20608    // stats4: 512 sum + 512 sumsq = 1024
#define SZ_C1    21632    // c1stats
#define SZ_GN    21640    // gnstats
#define SZ_D2    21648    // statsd2
#define SZ_TOT   21656

// ---------------------------------------------------------------------------
// k_prep: zero stats, init min/max sentinels, build split-bf16 W^T copies,
// grid feats
// ---------------------------------------------------------------------------
__global__ __launch_bounds__(256) void k_prep(
    const float* __restrict__ gc1w, const float* __restrict__ gc2w,
    const float* __restrict__ d1w, const float* __restrict__ d1b,
    unsigned short* __restrict__ W1Th, unsigned short* __restrict__ W1Tl,
    unsigned short* __restrict__ W2Th, unsigned short* __restrict__ W2Tl,
    float* __restrict__ gn, float* __restrict__ statszone, unsigned* __restrict__ mm)
{
    int t = blockIdx.x * 256 + threadIdx.x;
    int NT_ = gridDim.x * 256;
    for (int i = t; i < 65536; i += NT_) {          // W2T[c][k] = gc2_w[k][c], c<512,k<128
        int c = i >> 7, k = i & 127;
        float w = gc2w[k * 512 + c];
        unsigned short hi = f2bu(w);
        W2Th[i] = hi;
        W2Tl[i] = f2bu(w - bu2f(hi));
    }
    for (int i = t; i < 8192; i += NT_) {           // W1T[c][k] = gc1_w[k][c], c<128,k<64
        int c = i >> 6, k = i & 63;
        float w = gc1w[k * 128 + c];
        unsigned short hi = f2bu(w);
        W1Th[i] = hi;
        W1Tl[i] = f2bu(w - bu2f(hi));
    }
    for (int i = t; i < SZ_TOT; i += NT_) statszone[i] = 0.f;
    for (int i = t; i < 8192; i += NT_) mm[i] = 0u;                 // max enc
    for (int i = t; i < 8192; i += NT_) mm[8192 + i] = 0xFFFFFFFFu; // min enc
    for (int n = t; n < 8192; n += NT_) {
        int ix = n / 65, iy = n % 65;
        float gx = 1.f + ix * (119.f / 128.f);
        float gy = 1.f + iy * (59.f / 64.f);
        #pragma unroll
        for (int j = 0; j < 3; j++)
            gn[n * 3 + j] = gx * d1w[512 * 3 + j] + gy * d1w[513 * 3 + j] + d1b[j];
    }
}

// ---------------------------------------------------------------------------
// k_cov_e1: covariance features + Linear(12,64) -> a1 [131072][64] fp32
// ---------------------------------------------------------------------------
__global__ __launch_bounds__(256) void k_cov_e1(
    const float* __restrict__ data, const int* __restrict__ knn,
    const float* __restrict__ e1w, const float* __restrict__ e1b,
    float* __restrict__ a1)
{
    __shared__ float w[12 * 64];
    __shared__ float bias[64];
    int tid = threadIdx.x;
    for (int i = tid; i < 768; i += 256) w[i] = e1w[i];
    if (tid < 64) bias[tid] = e1b[tid];
    __syncthreads();

    int gid = blockIdx.x * 256 + tid;
    int b = gid >> 13;
    const float* db = data + (size_t)b * NPTS * 3;
    const int4* k4 = (const int4*)knn + gid * 4;

    float sx = 0, sy = 0, sz = 0, Sxx = 0, Sxy = 0, Sxz = 0, Syy = 0, Syz = 0, Szz = 0;
    #pragma unroll
    for (int jj = 0; jj < 4; jj++) {
        int4 q = k4[jj];
        int id[4] = {q.x, q.y, q.z, q.w};
        #pragma unroll
        for (int u = 0; u < 4; u++) {
            const float* p = db + (size_t)id[u] * 3;
            float x = p[0], y = p[1], z = p[2];
            sx += x; sy += y; sz += z;
            Sxx += x * x; Sxy += x * y; Sxz += x * z;
            Syy += y * y; Syz += y * z; Szz += z * z;
        }
    }
    float mx = sx * (1.f / 16.f), my = sy * (1.f / 16.f), mz = sz * (1.f / 16.f);
    const float inv15 = 1.f / 15.f;
    float x12[12];
    x12[0] = data[(size_t)gid * 3 + 0];
    x12[1] = data[(size_t)gid * 3 + 1];
    x12[2] = data[(size_t)gid * 3 + 2];
    x12[3] = (Sxx - 16.f * mx * mx) * inv15;
    x12[4] = (Sxy - 16.f * mx * my) * inv15;
    x12[5] = (Sxz - 16.f * mx * mz) * inv15;
    x12[6] = x12[4];
    x12[7] = (Syy - 16.f * my * my) * inv15;
    x12[8] = (Syz - 16.f * my * mz) * inv15;
    x12[9] = x12[5];
    x12[10] = x12[8];
    x12[11] = (Szz - 16.f * mz * mz) * inv15;

    float* arow = a1 + (size_t)gid * 64;
    for (int c0 = 0; c0 < 64; c0 += 4) {
        float4 v;
        float* vv = (float*)&v;
        #pragma unroll
        for (int u = 0; u < 4; u++) {
            int c = c0 + u;
            float acc = bias[c];
            #pragma unroll
            for (int i = 0; i < 12; i++) acc += x12[i] * w[i * 64 + c];
            vv[u] = acc;
        }
        *(float4*)(arow + c0) = v;
    }
}

// ---------------------------------------------------------------------------
// k_reduce_a1: per-channel sum/sumsq of a1 (C=64) -> stats1
// ---------------------------------------------------------------------------
__global__ __launch_bounds__(256) void k_reduce_a1(
    const float* __restrict__ a1, float* __restrict__ stats1)
{
    int tid = threadIdx.x;
    int c = tid & 63, rq = tid >> 6;
    float s = 0.f, q = 0.f;
    for (int row = blockIdx.x * 4 + rq; row < NROWS; row += gridDim.x * 4) {
        float v = a1[(size_t)row * 64 + c];
        s += v; q += v * v;
    }
    __shared__ float red[2][256];
    red[0][tid] = s; red[1][tid] = q;
    __syncthreads();
    if (tid < 64) {
        s = red[0][tid] + red[0][tid + 64] + red[0][tid + 128] + red[0][tid + 192];
        q = red[1][tid] + red[1][tid + 64] + red[1][tid + 128] + red[1][tid + 192];
        atomicAdd(stats1 + tid, s);
        atomicAdd(stats1 + 64 + tid, q);
    }
}

// ---------------------------------------------------------------------------
// k_gcn<CIN,COUT,NPARTS,STORE>: bn_relu(fp32 in) -> neighbor-sum ->
// split-bf16 3-term MFMA matmul (fp32-equivalent precision).
// STORE=true : writes aout fp32 (pre-BN) + per-batch stats partials
// STORE=false: per-batch stats partials + per-(b,c) min/max (for maxpool)
// Block 256 threads, MT=32 nodes/block. Grid = NROWS/32 = 4096.
// ---------------------------------------------------------------------------
template <int CIN, int COUT, int NPARTS, bool STORE>
__global__ __launch_bounds__(256) void k_gcn(
    const float* __restrict__ ain, const int* __restrict__ knn,
    const unsigned short* __restrict__ WTh, const unsigned short* __restrict__ WTl,
    const float* __restrict__ bias,
    const float* __restrict__ statsIn, const float* __restrict__ gamma, const float* __restrict__ beta,
    float* __restrict__ aout, float* __restrict__ statsOut, unsigned* __restrict__ mm)
{
    constexpr int MT = 32;
    constexpr int SST = CIN + 8;            // LDS row stride (ushorts): 16B-aligned rows
    constexpr int KC = CIN / 32;
    constexpr int NT = COUT / 64;           // 16-wide n-tiles per wave

    __shared__ float sc_s[CIN];
    __shared__ float sh_s[CIN];
    __shared__ int nidx[MT * KNN];
    __shared__ alignas(16) unsigned short smh[MT * SST];
    __shared__ alignas(16) unsigned short sml[MT * SST];

    int tid = threadIdx.x;
    // XCD-affinity swizzle: 2 batches per XCD -> per-XCD L2 holds 2 activation slices
    int blk = blockIdx.x;                   // 4096 blocks
    int xcd = blk & 7, seq = blk >> 3;      // seq in [0,512)
    int batch = xcd * 2 + (seq >> 8);
    int within = seq & 255;
    int node0 = batch * NPTS + within * MT;

    for (int ch = tid; ch < CIN; ch += 256) {
        float s = 0.f, q = 0.f;
        #pragma unroll
        for (int p = 0; p < NPARTS; p++) {
            s += statsIn[p * 2 * CIN + ch];
            q += statsIn[p * 2 * CIN + CIN + ch];
        }
        float m = s * (1.f / NROWS);
        float var = fmaxf(q * (1.f / NROWS) - m * m, 0.f);
        float sc = gamma[ch] * rsqrtf(var + EPSBN);
        sc_s[ch] = sc;
        sh_s[ch] = beta[ch] - m * sc;
    }
    for (int i = tid; i < MT * KNN; i += 256) nidx[i] = knn[(size_t)node0 * KNN + i];
    __syncthreads();

    // ---- gather: s = bn_relu(self) + sum_j bn_relu(neighbor_j); float4 loads;
    //      split s exactly into bf16 hi + lo
    {
        constexpr int GPR = CIN / 4;        // threads per row
        constexpr int RP = 256 / GPR;       // rows in parallel
        int t = tid & (GPR - 1);
        int grp = tid / GPR;
        int col4 = t * 4;
        float sc4[4], sh4[4];
        #pragma unroll
        for (int j = 0; j < 4; j++) { sc4[j] = sc_s[col4 + j]; sh4[j] = sh_s[col4 + j]; }
        const float* abase = ain + (size_t)batch * NPTS * CIN;
        for (int r = grp; r < MT; r += RP) {
            float a4v[4];
            float4 v = *(const float4*)(ain + (size_t)(node0 + r) * CIN + col4);
            a4v[0] = fmaxf(v.x * sc4[0] + sh4[0], 0.f);
            a4v[1] = fmaxf(v.y * sc4[1] + sh4[1], 0.f);
            a4v[2] = fmaxf(v.z * sc4[2] + sh4[2], 0.f);
            a4v[3] = fmaxf(v.w * sc4[3] + sh4[3], 0.f);
            #pragma unroll
            for (int jn = 0; jn < KNN; jn++) {
                int src = nidx[r * KNN + jn];
                float4 wv = *(const float4*)(abase + (size_t)src * CIN + col4);
                a4v[0] += fmaxf(wv.x * sc4[0] + sh4[0], 0.f);
                a4v[1] += fmaxf(wv.y * sc4[1] + sh4[1], 0.f);
                a4v[2] += fmaxf(wv.z * sc4[2] + sh4[2], 0.f);
                a4v[3] += fmaxf(wv.w * sc4[3] + sh4[3], 0.f);
            }
            unsigned short hi[4], lo[4];
            #pragma unroll
            for (int j = 0; j < 4; j++) {
                hi[j] = f2bu(a4v[j]);
                lo[j] = f2bu(a4v[j] - bu2f(hi[j]));
            }
            uint2 oh, ol;
            oh.x = hi[0] | ((unsigned)hi[1] << 16); oh.y = hi[2] | ((unsigned)hi[3] << 16);
            ol.x = lo[0] | ((unsigned)lo[1] << 16); ol.y = lo[2] | ((unsigned)lo[3] << 16);
            *(uint2*)&smh[r * SST + col4] = oh;
            *(uint2*)&sml[r * SST + col4] = ol;
        }
    }
    __syncthreads();

    // ---- MFMA: 3-term split product, D = Ah*Wh + Ah*Wl + Al*Wh
    int lane = tid & 63, wv = tid >> 6;
    int n15 = lane & 15, qd = lane >> 4;
    int c0 = wv * (COUT / 4);

    f32x4 acc[2][NT];
    #pragma unroll
    for (int m = 0; m < 2; m++)
        #pragma unroll
        for (int t2 = 0; t2 < NT; t2++) acc[m][t2] = (f32x4)(0.f);

    #pragma unroll
    for (int kc = 0; kc < KC; kc++) {
        bf16x8 ah0 = *(const bf16x8*)&smh[n15 * SST + kc * 32 + qd * 8];
        bf16x8 ah1 = *(const bf16x8*)&smh[(16 + n15) * SST + kc * 32 + qd * 8];
        bf16x8 al0 = *(const bf16x8*)&sml[n15 * SST + kc * 32 + qd * 8];
        bf16x8 al1 = *(const bf16x8*)&sml[(16 + n15) * SST + kc * 32 + qd * 8];
        #pragma unroll
        for (int nt = 0; nt < NT; nt++) {
            size_t woff = (size_t)(c0 + nt * 16 + n15) * CIN + kc * 32 + qd * 8;
            bf16x8 wh = *(const bf16x8*)(WTh + woff);
            bf16x8 wl = *(const bf16x8*)(WTl + woff);
            acc[0][nt] = __builtin_amdgcn_mfma_f32_16x16x32_bf16(ah0, wh, acc[0][nt], 0, 0, 0);
            acc[0][nt] = __builtin_amdgcn_mfma_f32_16x16x32_bf16(ah0, wl, acc[0][nt], 0, 0, 0);
            acc[0][nt] = __builtin_amdgcn_mfma_f32_16x16x32_bf16(al0, wh, acc[0][nt], 0, 0, 0);
            acc[1][nt] = __builtin_amdgcn_mfma_f32_16x16x32_bf16(ah1, wh, acc[1][nt], 0, 0, 0);
            acc[1][nt] = __builtin_amdgcn_mfma_f32_16x16x32_bf16(ah1, wl, acc[1][nt], 0, 0, 0);
            acc[1][nt] = __builtin_amdgcn_mfma_f32_16x16x32_bf16(al1, wh, acc[1][nt], 0, 0, 0);
        }
    }

    // ---- epilogue: /17 + bias, optional fp32 store, stats (+min/max)
    #pragma unroll
    for (int nt = 0; nt < NT; nt++) {
        int c = c0 + nt * 16 + n15;
        float bz = bias[c];
        float s = 0.f, q = 0.f, mx = -3.4e38f, mn = 3.4e38f;
        #pragma unroll
        for (int m = 0; m < 2; m++) {
            #pragma unroll
            for (int r = 0; r < 4; r++) {
                float v = acc[m][nt][r] * DEGINV + bz;
                if (STORE) {
                    int node = node0 + m * 16 + qd * 4 + r;
                    aout[(size_t)node * COUT + c] = v;
                }
                s += v; q += v * v;
                mx = fmaxf(mx, v); mn = fminf(mn, v);
            }
        }
        s += __shfl_xor(s, 16); s += __shfl_xor(s, 32);
        q += __shfl_xor(q, 16); q += __shfl_xor(q, 32);
        if (!STORE) {
            mx = fmaxf(mx, __shfl_xor(mx, 16)); mx = fmaxf(mx, __shfl_xor(mx, 32));
            mn = fminf(mn, __shfl_xor(mn, 16)); mn = fminf(mn, __shfl_xor(mn, 32));
        }
        if (lane < 16) {
            atomicAdd(statsOut + (size_t)batch * 2 * COUT + c, s);
            atomicAdd(statsOut + (size_t)batch * 2 * COUT + COUT + c, q);
            if (!STORE) {
                atomicMax(mm + batch * COUT + c, fenc(mx));
                atomicMin(mm + BATCH * COUT + batch * COUT + c, fenc(mn));
            }
        }
    }
}

// ---------------------------------------------------------------------------
// k_e2: pooled codeword from min/max + BN3, then Linear(512,512) -> a4, stats4
// ---------------------------------------------------------------------------
__global__ __launch_bounds__(256) void k_e2(
    const float* __restrict__ stats3p, const unsigned* __restrict__ mm,
    const float* __restrict__ g2g, const float* __restrict__ g2be,
    const float* __restrict__ e2w, const float* __restrict__ e2b,
    float* __restrict__ a4, float* __restrict__ stats4)
{
    __shared__ float pooled[512];
    int b = blockIdx.x, tid = threadIdx.x;
    for (int c = tid; c < 512; c += 256) {
        float s = 0.f, qq = 0.f;
        #pragma unroll
        for (int p = 0; p < 16; p++) {
            s += stats3p[p * 1024 + c];
            qq += stats3p[p * 1024 + 512 + c];
        }
        float m = s * (1.f / NROWS);
        float var = fmaxf(qq * (1.f / NROWS) - m * m, 0.f);
        float sc = g2g[c] * rsqrtf(var + EPSBN);
        float sh = g2be[c] - m * sc;
        float amax = fdec(mm[b * 512 + c]);
        float amin = fdec(mm[8192 + b * 512 + c]);
        pooled[c] = fmaxf(fmaxf(sc * amax + sh, 0.f), fmaxf(sc * amin + sh, 0.f));
    }
    __syncthreads();
    int ca = tid, cb = tid + 256;
    float acc1 = e2b[ca], acc2 = e2b[cb];
    for (int f = 0; f < 512; f++) {
        float pv = pooled[f];
        acc1 += pv * e2w[f * 512 + ca];
        acc2 += pv * e2w[f * 512 + cb];
    }
    a4[b * 512 + ca] = acc1; a4[b * 512 + cb] = acc2;
    atomicAdd(stats4 + ca, acc1); atomicAdd(stats4 + 512 + ca, acc1 * acc1);
    atomicAdd(stats4 + cb, acc2); atomicAdd(stats4 + 512 + cb, acc2 * acc2);
}

// ---------------------------------------------------------------------------
// k_code: BN4+relu -> code; c1 = code@d1_w[:512], c2 = code@d2_w[:512]
// ---------------------------------------------------------------------------
__global__ __launch_bounds__(256) void k_code(
    const float* __restrict__ a4, const float* __restrict__ stats4,
    const float* __restrict__ e2g, const float* __restrict__ e2be,
    const float* __restrict__ d1w, const float* __restrict__ d2w,
    const float* __restrict__ gn,
    float* __restrict__ c1, float* __restrict__ c2,
    float* __restrict__ c1stats, float* __restrict__ gnstats)
{
    int b = blockIdx.x, tid = threadIdx.x;
    int lane = tid & 63, wv = tid >> 6;
    float p1[3] = {0, 0, 0}, p2[3] = {0, 0, 0};
    for (int c = tid; c < 512; c += 256) {
        float s = stats4[c], qq = stats4[512 + c];
        float m = s * (1.f / 16.f);
        float var = fmaxf(qq * (1.f / 16.f) - m * m, 0.f);
        float sc = e2g[c] * rsqrtf(var + EPSBN);
        float sh = e2be[c] - m * sc;
        float cv = fmaxf(sc * a4[b * 512 + c] + sh, 0.f);
        #pragma unroll
        for (int j = 0; j < 3; j++) {
            p1[j] += cv * d1w[c * 3 + j];
            p2[j] += cv * d2w[c * 3 + j];
        }
    }
    __shared__ float red[4][6];
    #pragma unroll
    for (int j = 0; j < 3; j++)
        for (int off = 32; off; off >>= 1) {
            p1[j] += __shfl_xor(p1[j], off);
            p2[j] += __shfl_xor(p2[j], off);
        }
    if (lane == 0) {
        #pragma unroll
        for (int j = 0; j < 3; j++) { red[wv][j] = p1[j]; red[wv][3 + j] = p2[j]; }
    }
    __syncthreads();
    if (tid < 3) {
        float v = red[0][tid] + red[1][tid] + red[2][tid] + red[3][tid];
        c1[b * 3 + tid] = v;
        atomicAdd(c1stats + tid, v);
        atomicAdd(c1stats + 3 + tid, v * v);
    } else if (tid < 6) {
        int j = tid - 3;
        float v = red[0][tid] + red[1][tid] + red[2][tid] + red[3][tid];
        c2[b * 3 + j] = v;
    }
    if (blockIdx.x == 0) {
        float g1[3] = {0, 0, 0}, g2s[3] = {0, 0, 0};
        for (int n = tid; n < NPTS; n += 256) {
            #pragma unroll
            for (int j = 0; j < 3; j++) {
                float g = gn[n * 3 + j];
                g1[j] += g; g2s[j] += g * g;
            }
        }
        #pragma unroll
        for (int j = 0; j < 3; j++)
            for (int off = 32; off; off >>= 1) {
                g1[j] += __shfl_xor(g1[j], off);
                g2s[j] += __shfl_xor(g2s[j], off);
            }
        __shared__ float redg[4][6];
        if (lane == 0) {
            #pragma unroll
            for (int j = 0; j < 3; j++) { redg[wv][j] = g1[j]; redg[wv][3 + j] = g2s[j]; }
        }
        __syncthreads();
        if (tid < 6)
            gnstats[tid] = redg[0][tid] + redg[1][tid] + redg[2][tid] + redg[3][tid];
    }
}

// ---------------------------------------------------------------------------
__device__ __forceinline__ void d1_coefs(
    const float* c1stats, const float* gnstats,
    const float* d1g, const float* d1be, float* scd, float* shd)
{
    #pragma unroll
    for (int j = 0; j < 3; j++) {
        float mc = c1stats[j] * (1.f / 16.f), qc = c1stats[3 + j] * (1.f / 16.f);
        float mg = gnstats[j] * (1.f / 8192.f), qg = gnstats[3 + j] * (1.f / 8192.f);
        float m = mc + mg;
        float var = fmaxf((qc - mc * mc) + (qg - mg * mg), 0.f);
        float sc = d1g[j] * rsqrtf(var + EPSBN);
        scd[j] = sc;
        shd[j] = d1be[j] - m * sc;
    }
}

// ---------------------------------------------------------------------------
__global__ __launch_bounds__(256) void k_d2stats(
    const float* __restrict__ c1, const float* __restrict__ c2, const float* __restrict__ gn,
    const float* __restrict__ c1stats, const float* __restrict__ gnstats,
    const float* __restrict__ d1g, const float* __restrict__ d1be,
    const float* __restrict__ d2w, const float* __restrict__ d2b,
    float* __restrict__ statsd2)
{
    int gid = blockIdx.x * 256 + threadIdx.x;
    int b = gid >> 13, n = gid & 8191;
    int lane = threadIdx.x & 63, wv = threadIdx.x >> 6;
    float scd[3], shd[3];
    d1_coefs(c1stats, gnstats, d1g, d1be, scd, shd);
    float z3[3];
    #pragma unroll
    for (int j = 0; j < 3; j++)
        z3[j] = fmaxf(scd[j] * (c1[b * 3 + j] + gn[n * 3 + j]) + shd[j], 0.f);
    float vals[6];
    #pragma unroll
    for (int u = 0; u < 3; u++) {
        float a = c2[b * 3 + u]
                + z3[0] * d2w[512 * 3 + u]
                + z3[1] * d2w[513 * 3 + u]
                + z3[2] * d2w[514 * 3 + u]
                + d2b[u];
        vals[u] = a; vals[3 + u] = a * a;
    }
    #pragma unroll
    for (int j = 0; j < 6; j++)
        for (int off = 32; off; off >>= 1) vals[j] += __shfl_xor(vals[j], off);
    __shared__ float red[4][6];
    if (lane == 0) {
        #pragma unroll
        for (int j = 0; j < 6; j++) red[wv][j] = vals[j];
    }
    __syncthreads();
    if (threadIdx.x < 6)
        atomicAdd(statsd2 + threadIdx.x,
                  red[0][threadIdx.x] + red[1][threadIdx.x] + red[2][threadIdx.x] + red[3][threadIdx.x]);
}

// ---------------------------------------------------------------------------
__global__ __launch_bounds__(256) void k_out(
    const float* __restrict__ c1, const float* __restrict__ c2, const float* __restrict__ gn,
    const float* __restrict__ c1stats, const float* __restrict__ gnstats,
    const float* __restrict__ statsd2,
    const float* __restrict__ d1g, const float* __restrict__ d1be,
    const float* __restrict__ d2w, const float* __restrict__ d2b,
    const float* __restrict__ d2g, const float* __restrict__ d2be,
    float* __restrict__ out)
{
    int gid = blockIdx.x * 256 + threadIdx.x;
    int b = gid >> 13, n = gid & 8191;
    float scd[3], shd[3];
    d1_coefs(c1stats, gnstats, d1g, d1be, scd, shd);
    float z3[3];
    #pragma unroll
    for (int j = 0; j < 3; j++)
        z3[j] = fmaxf(scd[j] * (c1[b * 3 + j] + gn[n * 3 + j]) + shd[j], 0.f);
    #pragma unroll
    for (int u = 0; u < 3; u++) {
        float a = c2[b * 3 + u]
                + z3[0] * d2w[512 * 3 + u]
                + z3[1] * d2w[513 * 3 + u]
                + z3[2] * d2w[514 * 3 + u]
                + d2b[u];
        float m2 = statsd2[u] * (1.f / (float)NROWS);
        float v2 = fmaxf(statsd2[3 + u] * (1.f / (float)NROWS) - m2 * m2, 0.f);
        float sc = d2g[u] * rsqrtf(v2 + EPSBN);
        float sh = d2be[u] - m2 * sc;
        out[(size_t)gid * 3 + u] = fmaxf(sc * a + sh, 0.f);
    }
}

// ---------------------------------------------------------------------------
extern "C" void kernel_launch(void* const* d_in, const int* in_sizes, int n_in,
                              void* d_out, int out_size, void* d_ws, size_t ws_size,
                              hipStream_t stream)
{
    (void)in_sizes; (void)n_in; (void)out_size; (void)ws_size;
    const float* data = (const float*)d_in[0];
    const int*   knn  = (const int*)d_in[1];
    const float* e1w = (const float*)d_in[2],  *e1b = (const float*)d_in[3];
    const float* e1g = (const float*)d_in[4],  *e1be = (const float*)d_in[5];
    const float* gc1w = (const float*)d_in[6], *gc1b = (const float*)d_in[7];
    const float* g1g = (const float*)d_in[8],  *g1be = (const float*)d_in[9];
    const float* gc2w = (const float*)d_in[10], *gc2b = (const float*)d_in[11];
    const float* g2g = (const float*)d_in[12], *g2be = (const float*)d_in[13];
    const float* e2w = (const float*)d_in[14], *e2b = (const float*)d_in[15];
    const float* e2g = (const float*)d_in[16], *e2be = (const float*)d_in[17];
    const float* d1w = (const float*)d_in[18], *d1b = (const float*)d_in[19];
    const float* d1g = (const float*)d_in[20], *d1be = (const float*)d_in[21];
    const float* d2w = (const float*)d_in[22], *d2b = (const float*)d_in[23];
    const float* d2g = (const float*)d_in[24], *d2be = (const float*)d_in[25];

    char* p = (char*)d_ws;
    auto alloc = [&](size_t bytes) -> void* {
        void* r = (void*)p;
        p += (bytes + 255) & ~(size_t)255;
        return r;
    };
    float* a1 = (float*)alloc((size_t)NROWS * 64 * 4);     // 33.5 MB
    float* a2 = (float*)alloc((size_t)NROWS * 128 * 4);    // 67 MB
    unsigned short* W1Th = (unsigned short*)alloc(8192 * 2);
    unsigned short* W1Tl = (unsigned short*)alloc(8192 * 2);
    unsigned short* W2Th = (unsigned short*)alloc(65536 * 2);
    unsigned short* W2Tl = (unsigned short*)alloc(65536 * 2);
    float* statszone = (float*)alloc(SZ_TOT * 4);
    float* stats1  = statszone + SZ_S1;
    float* stats2p = statszone + SZ_S2P;
    float* stats3p = statszone + SZ_S3P;
    float* stats4  = statszone + SZ_S4;
    float* c1stats = statszone + SZ_C1;
    float* gnstats = statszone + SZ_GN;
    float* statsd2 = statszone + SZ_D2;
    unsigned* mm = (unsigned*)alloc(16384 * 4);
    float* a4 = (float*)alloc(16 * 512 * 4);
    float* c1 = (float*)alloc(64 * 4);
    float* c2 = (float*)alloc(64 * 4);
    float* gn = (float*)alloc(8192 * 3 * 4);

    k_prep<<<64, 256, 0, stream>>>(gc1w, gc2w, d1w, d1b, W1Th, W1Tl, W2Th, W2Tl,
                                   gn, statszone, mm);
    k_cov_e1<<<512, 256, 0, stream>>>(data, knn, e1w, e1b, a1);
    k_reduce_a1<<<256, 256, 0, stream>>>(a1, stats1);
    k_gcn<64, 128, 1, true><<<4096, 256, 0, stream>>>(
        a1, knn, W1Th, W1Tl, gc1b, stats1, e1g, e1be, a2, stats2p, nullptr);
    k_gcn<128, 512, 16, false><<<4096, 256, 0, stream>>>(
        a2, knn, W2Th, W2Tl, gc2b, stats2p, g1g, g1be, nullptr, stats3p, mm);
    k_e2<<<16, 256, 0, stream>>>(stats3p, mm, g2g, g2be, e2w, e2b, a4, stats4);
    k_code<<<16, 256, 0, stream>>>(a4, stats4, e2g, e2be, d1w, d2w, gn, c1, c2, c1stats, gnstats);
    k_d2stats<<<512, 256, 0, stream>>>(c1, c2, gn, c1stats, gnstats, d1g, d1be, d2w, d2b, statsd2);
    k_out<<<512, 256, 0, stream>>>(c1, c2, gn, c1stats, gnstats, statsd2,
                                   d1g, d1be, d2w, d2b, d2g, d2be, (float*)d_out);
}

// Round 7
// 490.880 us; speedup vs baseline: 8.7222x; 1.0132x over previous
//
#include <hip/hip_runtime.h>
#include <hip/hip_bf16.h>
#include <stdint.h>

#define BATCH 16
#define NPTS  8192
#define KNN   16
#define NROWS (BATCH*NPTS)     // 131072
#define EPSBN 1e-5f
#define DEGINV (1.0f/17.0f)

typedef short bf16x8 __attribute__((ext_vector_type(8)));
typedef float f32x4  __attribute__((ext_vector_type(4)));

__device__ __forceinline__ unsigned short f2bu(float f) {
    __hip_bfloat16 h = __float2bfloat16(f);
    return *reinterpret_cast<unsigned short*>(&h);
}
__device__ __forceinline__ float bu2f(unsigned short u) {
    return __uint_as_float(((unsigned)u) << 16);
}
// order-preserving float <-> uint encoding (for atomic min/max)
__device__ __forceinline__ unsigned fenc(float f) {
    unsigned u = __float_as_uint(f);
    return (int)u >= 0 ? (u | 0x80000000u) : ~u;
}
__device__ __forceinline__ float fdec(unsigned k) {
    return (k & 0x80000000u) ? __uint_as_float(k & 0x7FFFFFFFu) : __uint_as_float(~k);
}

// stats zone layout (floats):
#define SZ_S1    0        // stats1: [64]=sum, [64..127]=sumsq
#define SZ_S2P   128      // stats2p: 64 x (128 sum + 128 sumsq) = 16384
#define SZ_S3P   16512    // stats3p: 64 x (512 sum + 512 sumsq) = 65536
#define SZ_S4    82048    // stats4: 512 sum + 512 sumsq = 1024
#define SZ_C1    83072    // c1stats
#define SZ_GN    83080    // gnstats
#define SZ_D2    83088    // statsd2
#define SZ_TOT   83096

// ---------------------------------------------------------------------------
// k_prep: zero stats, init min/max sentinels, build split-bf16 W^T copies,
// grid feats
// ---------------------------------------------------------------------------
__global__ __launch_bounds__(256) void k_prep(
    const float* __restrict__ gc1w, const float* __restrict__ gc2w,
    const float* __restrict__ d1w, const float* __restrict__ d1b,
    unsigned short* __restrict__ W1Th, unsigned short* __restrict__ W1Tl,
    unsigned short* __restrict__ W2Th, unsigned short* __restrict__ W2Tl,
    float* __restrict__ gn, float* __restrict__ statszone, unsigned* __restrict__ mm)
{
    int t = blockIdx.x * 256 + threadIdx.x;
    int NT_ = gridDim.x * 256;
    for (int i = t; i < 65536; i += NT_) {          // W2T[c][k] = gc2_w[k][c], c<512,k<128
        int c = i >> 7, k = i & 127;
        float w = gc2w[k * 512 + c];
        unsigned short hi = f2bu(w);
        W2Th[i] = hi;
        W2Tl[i] = f2bu(w - bu2f(hi));
    }
    for (int i = t; i < 8192; i += NT_) {           // W1T[c][k] = gc1_w[k][c], c<128,k<64
        int c = i >> 6, k = i & 63;
        float w = gc1w[k * 128 + c];
        unsigned short hi = f2bu(w);
        W1Th[i] = hi;
        W1Tl[i] = f2bu(w - bu2f(hi));
    }
    for (int i = t; i < SZ_TOT; i += NT_) statszone[i] = 0.f;
    for (int i = t; i < 8192; i += NT_) mm[i] = 0u;                 // max enc
    for (int i = t; i < 8192; i += NT_) mm[8192 + i] = 0xFFFFFFFFu; // min enc
    for (int n = t; n < 8192; n += NT_) {
        int ix = n / 65, iy = n % 65;
        float gx = 1.f + ix * (119.f / 128.f);
        float gy = 1.f + iy * (59.f / 64.f);
        #pragma unroll
        for (int j = 0; j < 3; j++)
            gn[n * 3 + j] = gx * d1w[512 * 3 + j] + gy * d1w[513 * 3 + j] + d1b[j];
    }
}

// ---------------------------------------------------------------------------
// k_cov_e1: covariance features + Linear(12,64) -> a1 [131072][64] fp32
// ---------------------------------------------------------------------------
__global__ __launch_bounds__(256) void k_cov_e1(
    const float* __restrict__ data, const int* __restrict__ knn,
    const float* __restrict__ e1w, const float* __restrict__ e1b,
    float* __restrict__ a1)
{
    __shared__ float w[12 * 64];
    __shared__ float bias[64];
    int tid = threadIdx.x;
    for (int i = tid; i < 768; i += 256) w[i] = e1w[i];
    if (tid < 64) bias[tid] = e1b[tid];
    __syncthreads();

    int gid = blockIdx.x * 256 + tid;
    int b = gid >> 13;
    const float* db = data + (size_t)b * NPTS * 3;
    const int4* k4 = (const int4*)knn + gid * 4;

    float sx = 0, sy = 0, sz = 0, Sxx = 0, Sxy = 0, Sxz = 0, Syy = 0, Syz = 0, Szz = 0;
    #pragma unroll
    for (int jj = 0; jj < 4; jj++) {
        int4 q = k4[jj];
        int id[4] = {q.x, q.y, q.z, q.w};
        #pragma unroll
        for (int u = 0; u < 4; u++) {
            const float* p = db + (size_t)id[u] * 3;
            float x = p[0], y = p[1], z = p[2];
            sx += x; sy += y; sz += z;
            Sxx += x * x; Sxy += x * y; Sxz += x * z;
            Syy += y * y; Syz += y * z; Szz += z * z;
        }
    }
    float mx = sx * (1.f / 16.f), my = sy * (1.f / 16.f), mz = sz * (1.f / 16.f);
    const float inv15 = 1.f / 15.f;
    float x12[12];
    x12[0] = data[(size_t)gid * 3 + 0];
    x12[1] = data[(size_t)gid * 3 + 1];
    x12[2] = data[(size_t)gid * 3 + 2];
    x12[3] = (Sxx - 16.f * mx * mx) * inv15;
    x12[4] = (Sxy - 16.f * mx * my) * inv15;
    x12[5] = (Sxz - 16.f * mx * mz) * inv15;
    x12[6] = x12[4];
    x12[7] = (Syy - 16.f * my * my) * inv15;
    x12[8] = (Syz - 16.f * my * mz) * inv15;
    x12[9] = x12[5];
    x12[10] = x12[8];
    x12[11] = (Szz - 16.f * mz * mz) * inv15;

    float* arow = a1 + (size_t)gid * 64;
    for (int c0 = 0; c0 < 64; c0 += 4) {
        float4 v;
        float* vv = (float*)&v;
        #pragma unroll
        for (int u = 0; u < 4; u++) {
            int c = c0 + u;
            float acc = bias[c];
            #pragma unroll
            for (int i = 0; i < 12; i++) acc += x12[i] * w[i * 64 + c];
            vv[u] = acc;
        }
        *(float4*)(arow + c0) = v;
    }
}

// ---------------------------------------------------------------------------
// k_reduce_a1: per-channel sum/sumsq of a1 (C=64) -> stats1
// ---------------------------------------------------------------------------
__global__ __launch_bounds__(256) void k_reduce_a1(
    const float* __restrict__ a1, float* __restrict__ stats1)
{
    int tid = threadIdx.x;
    int c = tid & 63, rq = tid >> 6;
    float s = 0.f, q = 0.f;
    for (int row = blockIdx.x * 4 + rq; row < NROWS; row += gridDim.x * 4) {
        float v = a1[(size_t)row * 64 + c];
        s += v; q += v * v;
    }
    __shared__ float red[2][256];
    red[0][tid] = s; red[1][tid] = q;
    __syncthreads();
    if (tid < 64) {
        s = red[0][tid] + red[0][tid + 64] + red[0][tid + 128] + red[0][tid + 192];
        q = red[1][tid] + red[1][tid + 64] + red[1][tid + 128] + red[1][tid + 192];
        atomicAdd(stats1 + tid, s);
        atomicAdd(stats1 + 64 + tid, q);
    }
}

// ---------------------------------------------------------------------------
// k_gcn<CIN,COUT,NPARTS,STORE>: bn_relu(fp32 in) -> neighbor-sum ->
// split-bf16 3-term MFMA matmul (fp32-equivalent precision).
// MT=64 rows/block, 2048 blocks. One-batch-per-XCD phase swizzle (L2 fit).
// Output stats partitioned 64-way (batch*4 + quadrant) to cut atomic contention.
// ---------------------------------------------------------------------------
template <int CIN, int COUT, int NPARTS, bool STORE>
__global__ __launch_bounds__(256) void k_gcn(
    const float* __restrict__ ain, const int* __restrict__ knn,
    const unsigned short* __restrict__ WTh, const unsigned short* __restrict__ WTl,
    const float* __restrict__ bias,
    const float* __restrict__ statsIn, const float* __restrict__ gamma, const float* __restrict__ beta,
    float* __restrict__ aout, float* __restrict__ statsOut, unsigned* __restrict__ mm)
{
    constexpr int MT = 64;
    constexpr int SST = CIN + 8;            // LDS row stride (ushorts): 16B-aligned rows
    constexpr int KC = CIN / 32;
    constexpr int NT = COUT / 64;           // 16-wide n-tiles per wave

    __shared__ float sc_s[CIN];
    __shared__ float sh_s[CIN];
    __shared__ int nidx[MT * KNN];
    __shared__ alignas(16) unsigned short smh[MT * SST];
    __shared__ alignas(16) unsigned short sml[MT * SST];

    int tid = threadIdx.x;
    // one-batch-per-XCD phase swizzle: XCD x streams batch x, then batch x+8.
    int blk = blockIdx.x;                   // 2048 blocks
    int xcd = blk & 7;
    int seq = blk >> 3;                     // [0,256)
    int phase = seq >> 7;                   // {0,1}
    int within = seq & 127;                 // [0,128)
    int batch = xcd + 8 * phase;
    int node0 = batch * NPTS + within * MT;
    int pout = batch * 4 + (within >> 5);   // 64-way stats partition

    for (int ch = tid; ch < CIN; ch += 256) {
        float s = 0.f, q = 0.f;
        for (int p = 0; p < NPARTS; p++) {
            s += statsIn[p * 2 * CIN + ch];
            q += statsIn[p * 2 * CIN + CIN + ch];
        }
        float m = s * (1.f / NROWS);
        float var = fmaxf(q * (1.f / NROWS) - m * m, 0.f);
        float sc = gamma[ch] * rsqrtf(var + EPSBN);
        sc_s[ch] = sc;
        sh_s[ch] = beta[ch] - m * sc;
    }
    {   // knn staging: MT*KNN = 1024 ints = 256 int4
        const int4* ksrc = (const int4*)(knn + (size_t)node0 * KNN);
        ((int4*)nidx)[tid] = ksrc[tid];
    }
    __syncthreads();

    // ---- gather: s = bn_relu(self) + sum_j bn_relu(neighbor_j); float4 loads;
    //      split s exactly into bf16 hi + lo
    {
        constexpr int GPR = CIN / 4;        // threads per row
        constexpr int RP = 256 / GPR;       // rows in parallel
        int t = tid & (GPR - 1);
        int grp = tid / GPR;
        int col4 = t * 4;
        float sc4[4], sh4[4];
        #pragma unroll
        for (int j = 0; j < 4; j++) { sc4[j] = sc_s[col4 + j]; sh4[j] = sh_s[col4 + j]; }
        const float* abase = ain + (size_t)batch * NPTS * CIN;
        #pragma unroll 2
        for (int r = grp; r < MT; r += RP) {
            float a4v[4];
            float4 v = *(const float4*)(ain + (size_t)(node0 + r) * CIN + col4);
            a4v[0] = fmaxf(v.x * sc4[0] + sh4[0], 0.f);
            a4v[1] = fmaxf(v.y * sc4[1] + sh4[1], 0.f);
            a4v[2] = fmaxf(v.z * sc4[2] + sh4[2], 0.f);
            a4v[3] = fmaxf(v.w * sc4[3] + sh4[3], 0.f);
            #pragma unroll
            for (int jn = 0; jn < KNN; jn++) {
                int src = nidx[r * KNN + jn];
                float4 wv = *(const float4*)(abase + (size_t)src * CIN + col4);
                a4v[0] += fmaxf(wv.x * sc4[0] + sh4[0], 0.f);
                a4v[1] += fmaxf(wv.y * sc4[1] + sh4[1], 0.f);
                a4v[2] += fmaxf(wv.z * sc4[2] + sh4[2], 0.f);
                a4v[3] += fmaxf(wv.w * sc4[3] + sh4[3], 0.f);
            }
            unsigned short hi[4], lo[4];
            #pragma unroll
            for (int j = 0; j < 4; j++) {
                hi[j] = f2bu(a4v[j]);
                lo[j] = f2bu(a4v[j] - bu2f(hi[j]));
            }
            uint2 oh, ol;
            oh.x = hi[0] | ((unsigned)hi[1] << 16); oh.y = hi[2] | ((unsigned)hi[3] << 16);
            ol.x = lo[0] | ((unsigned)lo[1] << 16); ol.y = lo[2] | ((unsigned)lo[3] << 16);
            *(uint2*)&smh[r * SST + col4] = oh;
            *(uint2*)&sml[r * SST + col4] = ol;
        }
    }
    __syncthreads();

    // ---- MFMA: 3-term split product, D = Ah*Wh + Ah*Wl + Al*Wh; 4 m-tiles
    int lane = tid & 63, wv = tid >> 6;
    int n15 = lane & 15, qd = lane >> 4;
    int c0 = wv * (COUT / 4);

    f32x4 acc[4][NT];
    #pragma unroll
    for (int m = 0; m < 4; m++)
        #pragma unroll
        for (int t2 = 0; t2 < NT; t2++) acc[m][t2] = (f32x4)(0.f);

    #pragma unroll
    for (int kc = 0; kc < KC; kc++) {
        // hoist W fragments for this kc (shared across m)
        bf16x8 wh[NT], wl[NT];
        #pragma unroll
        for (int nt = 0; nt < NT; nt++) {
            size_t woff = (size_t)(c0 + nt * 16 + n15) * CIN + kc * 32 + qd * 8;
            wh[nt] = *(const bf16x8*)(WTh + woff);
            wl[nt] = *(const bf16x8*)(WTl + woff);
        }
        #pragma unroll
        for (int m = 0; m < 4; m++) {
            bf16x8 ah = *(const bf16x8*)&smh[(m * 16 + n15) * SST + kc * 32 + qd * 8];
            bf16x8 al = *(const bf16x8*)&sml[(m * 16 + n15) * SST + kc * 32 + qd * 8];
            #pragma unroll
            for (int nt = 0; nt < NT; nt++) {
                acc[m][nt] = __builtin_amdgcn_mfma_f32_16x16x32_bf16(ah, wh[nt], acc[m][nt], 0, 0, 0);
                acc[m][nt] = __builtin_amdgcn_mfma_f32_16x16x32_bf16(ah, wl[nt], acc[m][nt], 0, 0, 0);
                acc[m][nt] = __builtin_amdgcn_mfma_f32_16x16x32_bf16(al, wh[nt], acc[m][nt], 0, 0, 0);
            }
        }
    }

    // ---- epilogue: /17 + bias, optional fp32 store, stats (+min/max)
    #pragma unroll
    for (int nt = 0; nt < NT; nt++) {
        int c = c0 + nt * 16 + n15;
        float bz = bias[c];
        float s = 0.f, q = 0.f, mx = -3.4e38f, mn = 3.4e38f;
        #pragma unroll
        for (int m = 0; m < 4; m++) {
            #pragma unroll
            for (int r = 0; r < 4; r++) {
                float v = acc[m][nt][r] * DEGINV + bz;
                if (STORE) {
                    int node = node0 + m * 16 + qd * 4 + r;
                    aout[(size_t)node * COUT + c] = v;
                }
                s += v; q += v * v;
                mx = fmaxf(mx, v); mn = fminf(mn, v);
            }
        }
        s += __shfl_xor(s, 16); s += __shfl_xor(s, 32);
        q += __shfl_xor(q, 16); q += __shfl_xor(q, 32);
        if (!STORE) {
            mx = fmaxf(mx, __shfl_xor(mx, 16)); mx = fmaxf(mx, __shfl_xor(mx, 32));
            mn = fminf(mn, __shfl_xor(mn, 16)); mn = fminf(mn, __shfl_xor(mn, 32));
        }
        if (lane < 16) {
            atomicAdd(statsOut + (size_t)pout * 2 * COUT + c, s);
            atomicAdd(statsOut + (size_t)pout * 2 * COUT + COUT + c, q);
            if (!STORE) {
                atomicMax(mm + batch * COUT + c, fenc(mx));
                atomicMin(mm + BATCH * COUT + batch * COUT + c, fenc(mn));
            }
        }
    }
}

// ---------------------------------------------------------------------------
// k_e2: pooled codeword from min/max + BN3, then Linear(512,512) -> a4, stats4
// ---------------------------------------------------------------------------
__global__ __launch_bounds__(256) void k_e2(
    const float* __restrict__ stats3p, const unsigned* __restrict__ mm,
    const float* __restrict__ g2g, const float* __restrict__ g2be,
    const float* __restrict__ e2w, const float* __restrict__ e2b,
    float* __restrict__ a4, float* __restrict__ stats4)
{
    __shared__ float pooled[512];
    int b = blockIdx.x, tid = threadIdx.x;
    for (int c = tid; c < 512; c += 256) {
        float s = 0.f, qq = 0.f;
        for (int p = 0; p < 64; p++) {
            s += stats3p[p * 1024 + c];
            qq += stats3p[p * 1024 + 512 + c];
        }
        float m = s * (1.f / NROWS);
        float var = fmaxf(qq * (1.f / NROWS) - m * m, 0.f);
        float sc = g2g[c] * rsqrtf(var + EPSBN);
        float sh = g2be[c] - m * sc;
        float amax = fdec(mm[b * 512 + c]);
        float amin = fdec(mm[8192 + b * 512 + c]);
        pooled[c] = fmaxf(fmaxf(sc * amax + sh, 0.f), fmaxf(sc * amin + sh, 0.f));
    }
    __syncthreads();
    int ca = tid, cb = tid + 256;
    float acc1 = e2b[ca], acc2 = e2b[cb];
    for (int f = 0; f < 512; f++) {
        float pv = pooled[f];
        acc1 += pv * e2w[f * 512 + ca];
        acc2 += pv * e2w[f * 512 + cb];
    }
    a4[b * 512 + ca] = acc1; a4[b * 512 + cb] = acc2;
    atomicAdd(stats4 + ca, acc1); atomicAdd(stats4 + 512 + ca, acc1 * acc1);
    atomicAdd(stats4 + cb, acc2); atomicAdd(stats4 + 512 + cb, acc2 * acc2);
}

// ---------------------------------------------------------------------------
// k_code: BN4+relu -> code; c1 = code@d1_w[:512], c2 = code@d2_w[:512]
// ---------------------------------------------------------------------------
__global__ __launch_bounds__(256) void k_code(
    const float* __restrict__ a4, const float* __restrict__ stats4,
    const float* __restrict__ e2g, const float* __restrict__ e2be,
    const float* __restrict__ d1w, const float* __restrict__ d2w,
    const float* __restrict__ gn,
    float* __restrict__ c1, float* __restrict__ c2,
    float* __restrict__ c1stats, float* __restrict__ gnstats)
{
    int b = blockIdx.x, tid = threadIdx.x;
    int lane = tid & 63, wv = tid >> 6;
    float p1[3] = {0, 0, 0}, p2[3] = {0, 0, 0};
    for (int c = tid; c < 512; c += 256) {
        float s = stats4[c], qq = stats4[512 + c];
        float m = s * (1.f / 16.f);
        float var = fmaxf(qq * (1.f / 16.f) - m * m, 0.f);
        float sc = e2g[c] * rsqrtf(var + EPSBN);
        float sh = e2be[c] - m * sc;
        float cv = fmaxf(sc * a4[b * 512 + c] + sh, 0.f);
        #pragma unroll
        for (int j = 0; j < 3; j++) {
            p1[j] += cv * d1w[c * 3 + j];
            p2[j] += cv * d2w[c * 3 + j];
        }
    }
    __shared__ float red[4][6];
    #pragma unroll
    for (int j = 0; j < 3; j++)
        for (int off = 32; off; off >>= 1) {
            p1[j] += __shfl_xor(p1[j], off);
            p2[j] += __shfl_xor(p2[j], off);
        }
    if (lane == 0) {
        #pragma unroll
        for (int j = 0; j < 3; j++) { red[wv][j] = p1[j]; red[wv][3 + j] = p2[j]; }
    }
    __syncthreads();
    if (tid < 3) {
        float v = red[0][tid] + red[1][tid] + red[2][tid] + red[3][tid];
        c1[b * 3 + tid] = v;
        atomicAdd(c1stats + tid, v);
        atomicAdd(c1stats + 3 + tid, v * v);
    } else if (tid < 6) {
        int j = tid - 3;
        float v = red[0][tid] + red[1][tid] + red[2][tid] + red[3][tid];
        c2[b * 3 + j] = v;
    }
    if (blockIdx.x == 0) {
        float g1[3] = {0, 0, 0}, g2s[3] = {0, 0, 0};
        for (int n = tid; n < NPTS; n += 256) {
            #pragma unroll
            for (int j = 0; j < 3; j++) {
                float g = gn[n * 3 + j];
                g1[j] += g; g2s[j] += g * g;
            }
        }
        #pragma unroll
        for (int j = 0; j < 3; j++)
            for (int off = 32; off; off >>= 1) {
                g1[j] += __shfl_xor(g1[j], off);
                g2s[j] += __shfl_xor(g2s[j], off);
            }
        __shared__ float redg[4][6];
        if (lane == 0) {
            #pragma unroll
            for (int j = 0; j < 3; j++) { redg[wv][j] = g1[j]; redg[wv][3 + j] = g2s[j]; }
        }
        __syncthreads();
        if (tid < 6)
            gnstats[tid] = redg[0][tid] + redg[1][tid] + redg[2][tid] + redg[3][tid];
    }
}

// ---------------------------------------------------------------------------
__device__ __forceinline__ void d1_coefs(
    const float* c1stats, const float* gnstats,
    const float* d1g, const float* d1be, float* scd, float* shd)
{
    #pragma unroll
    for (int j = 0; j < 3; j++) {
        float mc = c1stats[j] * (1.f / 16.f), qc = c1stats[3 + j] * (1.f / 16.f);
        float mg = gnstats[j] * (1.f / 8192.f), qg = gnstats[3 + j] * (1.f / 8192.f);
        float m = mc + mg;
        float var = fmaxf((qc - mc * mc) + (qg - mg * mg), 0.f);
        float sc = d1g[j] * rsqrtf(var + EPSBN);
        scd[j] = sc;
        shd[j] = d1be[j] - m * sc;
    }
}

// ---------------------------------------------------------------------------
__global__ __launch_bounds__(256) void k_d2stats(
    const float* __restrict__ c1, const float* __restrict__ c2, const float* __restrict__ gn,
    const float* __restrict__ c1stats, const float* __restrict__ gnstats,
    const float* __restrict__ d1g, const float* __restrict__ d1be,
    const float* __restrict__ d2w, const float* __restrict__ d2b,
    float* __restrict__ statsd2)
{
    int gid = blockIdx.x * 256 + threadIdx.x;
    int b = gid >> 13, n = gid & 8191;
    int lane = threadIdx.x & 63, wv = threadIdx.x >> 6;
    float scd[3], shd[3];
    d1_coefs(c1stats, gnstats, d1g, d1be, scd, shd);
    float z3[3];
    #pragma unroll
    for (int j = 0; j < 3; j++)
        z3[j] = fmaxf(scd[j] * (c1[b * 3 + j] + gn[n * 3 + j]) + shd[j], 0.f);
    float vals[6];
    #pragma unroll
    for (int u = 0; u < 3; u++) {
        float a = c2[b * 3 + u]
                + z3[0] * d2w[512 * 3 + u]
                + z3[1] * d2w[513 * 3 + u]
                + z3[2] * d2w[514 * 3 + u]
                + d2b[u];
        vals[u] = a; vals[3 + u] = a * a;
    }
    #pragma unroll
    for (int j = 0; j < 6; j++)
        for (int off = 32; off; off >>= 1) vals[j] += __shfl_xor(vals[j], off);
    __shared__ float red[4][6];
    if (lane == 0) {
        #pragma unroll
        for (int j = 0; j < 6; j++) red[wv][j] = vals[j];
    }
    __syncthreads();
    if (threadIdx.x < 6)
        atomicAdd(statsd2 + threadIdx.x,
                  red[0][threadIdx.x] + red[1][threadIdx.x] + red[2][threadIdx.x] + red[3][threadIdx.x]);
}

// ---------------------------------------------------------------------------
__global__ __launch_bounds__(256) void k_out(
    const float* __restrict__ c1, const float* __restrict__ c2, const float* __restrict__ gn,
    const float* __restrict__ c1stats, const float* __restrict__ gnstats,
    const float* __restrict__ statsd2,
    const float* __restrict__ d1g, const float* __restrict__ d1be,
    const float* __restrict__ d2w, const float* __restrict__ d2b,
    const float* __restrict__ d2g, const float* __restrict__ d2be,
    float* __restrict__ out)
{
    int gid = blockIdx.x * 256 + threadIdx.x;
    int b = gid >> 13, n = gid & 8191;
    float scd[3], shd[3];
    d1_coefs(c1stats, gnstats, d1g, d1be, scd, shd);
    float z3[3];
    #pragma unroll
    for (int j = 0; j < 3; j++)
        z3[j] = fmaxf(scd[j] * (c1[b * 3 + j] + gn[n * 3 + j]) + shd[j], 0.f);
    #pragma unroll
    for (int u = 0; u < 3; u++) {
        float a = c2[b * 3 + u]
                + z3[0] * d2w[512 * 3 + u]
                + z3[1] * d2w[513 * 3 + u]
                + z3[2] * d2w[514 * 3 + u]
                + d2b[u];
        float m2 = statsd2[u] * (1.f / (float)NROWS);
        float v2 = fmaxf(statsd2[3 + u] * (1.f / (float)NROWS) - m2 * m2, 0.f);
        float sc = d2g[u] * rsqrtf(v2 + EPSBN);
        float sh = d2be[u] - m2 * sc;
        out[(size_t)gid * 3 + u] = fmaxf(sc * a + sh, 0.f);
    }
}

// ---------------------------------------------------------------------------
extern "C" void kernel_launch(void* const* d_in, const int* in_sizes, int n_in,
                              void* d_out, int out_size, void* d_ws, size_t ws_size,
                              hipStream_t stream)
{
    (void)in_sizes; (void)n_in; (void)out_size; (void)ws_size;
    const float* data = (const float*)d_in[0];
    const int*   knn  = (const int*)d_in[1];
    const float* e1w = (const float*)d_in[2],  *e1b = (const float*)d_in[3];
    const float* e1g = (const float*)d_in[4],  *e1be = (const float*)d_in[5];
    const float* gc1w = (const float*)d_in[6], *gc1b = (const float*)d_in[7];
    const float* g1g = (const float*)d_in[8],  *g1be = (const float*)d_in[9];
    const float* gc2w = (const float*)d_in[10], *gc2b = (const float*)d_in[11];
    const float* g2g = (const float*)d_in[12], *g2be = (const float*)d_in[13];
    const float* e2w = (const float*)d_in[14], *e2b = (const float*)d_in[15];
    const float* e2g = (const float*)d_in[16], *e2be = (const float*)d_in[17];
    const float* d1w = (const float*)d_in[18], *d1b = (const float*)d_in[19];
    const float* d1g = (const float*)d_in[20], *d1be = (const float*)d_in[21];
    const float* d2w = (const float*)d_in[22], *d2b = (const float*)d_in[23];
    const float* d2g = (const float*)d_in[24], *d2be = (const float*)d_in[25];

    char* p = (char*)d_ws;
    auto alloc = [&](size_t bytes) -> void* {
        void* r = (void*)p;
        p += (bytes + 255) & ~(size_t)255;
        return r;
    };
    float* a1 = (float*)alloc((size_t)NROWS * 64 * 4);     // 33.5 MB
    float* a2 = (float*)alloc((size_t)NROWS * 128 * 4);    // 67 MB
    unsigned short* W1Th = (unsigned short*)alloc(8192 * 2);
    unsigned short* W1Tl = (unsigned short*)alloc(8192 * 2);
    unsigned short* W2Th = (unsigned short*)alloc(65536 * 2);
    unsigned short* W2Tl = (unsigned short*)alloc(65536 * 2);
    float* statszone = (float*)alloc(SZ_TOT * 4);
    float* stats1  = statszone + SZ_S1;
    float* stats2p = statszone + SZ_S2P;
    float* stats3p = statszone + SZ_S3P;
    float* stats4  = statszone + SZ_S4;
    float* c1stats = statszone + SZ_C1;
    float* gnstats = statszone + SZ_GN;
    float* statsd2 = statszone + SZ_D2;
    unsigned* mm = (unsigned*)alloc(16384 * 4);
    float* a4 = (float*)alloc(16 * 512 * 4);
    float* c1 = (float*)alloc(64 * 4);
    float* c2 = (float*)alloc(64 * 4);
    float* gn = (float*)alloc(8192 * 3 * 4);

    k_prep<<<64, 256, 0, stream>>>(gc1w, gc2w, d1w, d1b, W1Th, W1Tl, W2Th, W2Tl,
                                   gn, statszone, mm);
    k_cov_e1<<<512, 256, 0, stream>>>(data, knn, e1w, e1b, a1);
    k_reduce_a1<<<256, 256, 0, stream>>>(a1, stats1);
    k_gcn<64, 128, 1, true><<<2048, 256, 0, stream>>>(
        a1, knn, W1Th, W1Tl, gc1b, stats1, e1g, e1be, a2, stats2p, nullptr);
    k_gcn<128, 512, 64, false><<<2048, 256, 0, stream>>>(
        a2, knn, W2Th, W2Tl, gc2b, stats2p, g1g, g1be, nullptr, stats3p, mm);
    k_e2<<<16, 256, 0, stream>>>(stats3p, mm, g2g, g2be, e2w, e2b, a4, stats4);
    k_code<<<16, 256, 0, stream>>>(a4, stats4, e2g, e2be, d1w, d2w, gn, c1, c2, c1stats, gnstats);
    k_d2stats<<<512, 256, 0, stream>>>(c1, c2, gn, c1stats, gnstats, d1g, d1be, d2w, d2b, statsd2);
    k_out<<<512, 256, 0, stream>>>(c1, c2, gn, c1stats, gnstats, statsd2,
                                   d1g, d1be, d2w, d2b, d2g, d2be, (float*)d_out);
}

// Round 8
// 425.333 us; speedup vs baseline: 10.0663x; 1.1541x over previous
//
#include <hip/hip_runtime.h>
#include <hip/hip_fp16.h>
#include <stdint.h>

#define BATCH 16
#define NPTS  8192
#define KNN   16
#define NROWS (BATCH*NPTS)     // 131072
#define EPSBN 1e-5f
#define DEGINV (1.0f/17.0f)

typedef _Float16 f16x8 __attribute__((ext_vector_type(8)));
typedef float    f32x4 __attribute__((ext_vector_type(4)));

__device__ __forceinline__ unsigned short f2hu(float f) {
    union { _Float16 h; unsigned short u; } cv;
    cv.h = (_Float16)f;
    return cv.u;
}
// order-preserving float <-> uint encoding (for atomic min/max)
__device__ __forceinline__ unsigned fenc(float f) {
    unsigned u = __float_as_uint(f);
    return (int)u >= 0 ? (u | 0x80000000u) : ~u;
}
__device__ __forceinline__ float fdec(unsigned k) {
    return (k & 0x80000000u) ? __uint_as_float(k & 0x7FFFFFFFu) : __uint_as_float(~k);
}

// stats zone layout (floats):
#define SZ_S1    0        // stats1: 64 sum + 64 sumsq
#define SZ_S2P   128      // stats2p: 64 x (128+128)
#define SZ_S3P   16512    // stats3p: 64 x (512+512)
#define SZ_S4    82048    // stats4: 512+512
#define SZ_C1    83072
#define SZ_GN    83080
#define SZ_D2    83088
#define SZ_SCSH1 83096    // 2*64 bn coefs for layer1 input
#define SZ_SCSH2 83224    // 2*128 bn coefs for layer2 input
#define SZ_TOT   83480

// ---------------------------------------------------------------------------
// k_prep: zero stats, init min/max sentinels, build fp16 W^T copies, grid feats
// ---------------------------------------------------------------------------
__global__ __launch_bounds__(256) void k_prep(
    const float* __restrict__ gc1w, const float* __restrict__ gc2w,
    const float* __restrict__ d1w, const float* __restrict__ d1b,
    unsigned short* __restrict__ W1T, unsigned short* __restrict__ W2T,
    float* __restrict__ gn, float* __restrict__ statszone, unsigned* __restrict__ mm)
{
    int t = blockIdx.x * 256 + threadIdx.x;
    int NT_ = gridDim.x * 256;
    for (int i = t; i < 65536; i += NT_) {          // W2T[c][k] = gc2_w[k][c]
        int c = i >> 7, k = i & 127;
        W2T[i] = f2hu(gc2w[k * 512 + c]);
    }
    for (int i = t; i < 8192; i += NT_) {           // W1T[c][k] = gc1_w[k][c]
        int c = i >> 6, k = i & 63;
        W1T[i] = f2hu(gc1w[k * 128 + c]);
    }
    for (int i = t; i < SZ_TOT; i += NT_) statszone[i] = 0.f;
    for (int i = t; i < 8192; i += NT_) mm[i] = 0u;                 // max enc
    for (int i = t; i < 8192; i += NT_) mm[8192 + i] = 0xFFFFFFFFu; // min enc
    for (int n = t; n < 8192; n += NT_) {
        int ix = n / 65, iy = n % 65;
        float gx = 1.f + ix * (119.f / 128.f);
        float gy = 1.f + iy * (59.f / 64.f);
        #pragma unroll
        for (int j = 0; j < 3; j++)
            gn[n * 3 + j] = gx * d1w[512 * 3 + j] + gy * d1w[513 * 3 + j] + d1b[j];
    }
}

// ---------------------------------------------------------------------------
// k_cov_e1: covariance features + Linear(12,64) -> a1 [131072][64] fp32
// ---------------------------------------------------------------------------
__global__ __launch_bounds__(256) void k_cov_e1(
    const float* __restrict__ data, const int* __restrict__ knn,
    const float* __restrict__ e1w, const float* __restrict__ e1b,
    float* __restrict__ a1)
{
    __shared__ float w[12 * 64];
    __shared__ float bias[64];
    int tid = threadIdx.x;
    for (int i = tid; i < 768; i += 256) w[i] = e1w[i];
    if (tid < 64) bias[tid] = e1b[tid];
    __syncthreads();

    int gid = blockIdx.x * 256 + tid;
    int b = gid >> 13;
    const float* db = data + (size_t)b * NPTS * 3;
    const int4* k4 = (const int4*)knn + gid * 4;

    float sx = 0, sy = 0, sz = 0, Sxx = 0, Sxy = 0, Sxz = 0, Syy = 0, Syz = 0, Szz = 0;
    #pragma unroll
    for (int jj = 0; jj < 4; jj++) {
        int4 q = k4[jj];
        int id[4] = {q.x, q.y, q.z, q.w};
        #pragma unroll
        for (int u = 0; u < 4; u++) {
            const float* p = db + (size_t)id[u] * 3;
            float x = p[0], y = p[1], z = p[2];
            sx += x; sy += y; sz += z;
            Sxx += x * x; Sxy += x * y; Sxz += x * z;
            Syy += y * y; Syz += y * z; Szz += z * z;
        }
    }
    float mx = sx * (1.f / 16.f), my = sy * (1.f / 16.f), mz = sz * (1.f / 16.f);
    const float inv15 = 1.f / 15.f;
    float x12[12];
    x12[0] = data[(size_t)gid * 3 + 0];
    x12[1] = data[(size_t)gid * 3 + 1];
    x12[2] = data[(size_t)gid * 3 + 2];
    x12[3] = (Sxx - 16.f * mx * mx) * inv15;
    x12[4] = (Sxy - 16.f * mx * my) * inv15;
    x12[5] = (Sxz - 16.f * mx * mz) * inv15;
    x12[6] = x12[4];
    x12[7] = (Syy - 16.f * my * my) * inv15;
    x12[8] = (Syz - 16.f * my * mz) * inv15;
    x12[9] = x12[5];
    x12[10] = x12[8];
    x12[11] = (Szz - 16.f * mz * mz) * inv15;

    float* arow = a1 + (size_t)gid * 64;
    for (int c0 = 0; c0 < 64; c0 += 4) {
        float4 v;
        float* vv = (float*)&v;
        #pragma unroll
        for (int u = 0; u < 4; u++) {
            int c = c0 + u;
            float acc = bias[c];
            #pragma unroll
            for (int i = 0; i < 12; i++) acc += x12[i] * w[i * 64 + c];
            vv[u] = acc;
        }
        *(float4*)(arow + c0) = v;
    }
}

// ---------------------------------------------------------------------------
// k_reduce_a1: per-channel sum/sumsq of a1 (C=64) -> stats1
// ---------------------------------------------------------------------------
__global__ __launch_bounds__(256) void k_reduce_a1(
    const float* __restrict__ a1, float* __restrict__ stats1)
{
    int tid = threadIdx.x;
    int c = tid & 63, rq = tid >> 6;
    float s = 0.f, q = 0.f;
    for (int row = blockIdx.x * 4 + rq; row < NROWS; row += gridDim.x * 4) {
        float v = a1[(size_t)row * 64 + c];
        s += v; q += v * v;
    }
    __shared__ float red[2][256];
    red[0][tid] = s; red[1][tid] = q;
    __syncthreads();
    if (tid < 64) {
        s = red[0][tid] + red[0][tid + 64] + red[0][tid + 128] + red[0][tid + 192];
        q = red[1][tid] + red[1][tid + 64] + red[1][tid + 128] + red[1][tid + 192];
        atomicAdd(stats1 + tid, s);
        atomicAdd(stats1 + 64 + tid, q);
    }
}

// ---------------------------------------------------------------------------
// k_bncoef<C,NPARTS>: collapse partitioned stats -> (sc, sh) coef arrays
// ---------------------------------------------------------------------------
template <int C, int NPARTS>
__global__ __launch_bounds__(256) void k_bncoef(
    const float* __restrict__ statsIn,
    const float* __restrict__ gamma, const float* __restrict__ beta,
    float* __restrict__ scsh)
{
    int ch = threadIdx.x;
    if (ch < C) {
        float s = 0.f, q = 0.f;
        for (int p = 0; p < NPARTS; p++) {
            s += statsIn[p * 2 * C + ch];
            q += statsIn[p * 2 * C + C + ch];
        }
        float m = s * (1.f / NROWS);
        float var = fmaxf(q * (1.f / NROWS) - m * m, 0.f);
        float sc = gamma[ch] * rsqrtf(var + EPSBN);
        scsh[ch] = sc;
        scsh[C + ch] = beta[ch] - m * sc;
    }
}

// ---------------------------------------------------------------------------
// k_gather<CIN>: s[row] = bn_relu(a[row]) + sum_j bn_relu(a[knn_j]) -> fp16
// One thread per (row, 4-channel chunk): 17 independent float4 loads in flight.
// High-occupancy latency machine: no MFMA, minimal LDS, ~90 VGPR.
// ---------------------------------------------------------------------------
template <int CIN>
__global__ __launch_bounds__(256) void k_gather(
    const float* __restrict__ ain, const int* __restrict__ knn,
    const float* __restrict__ scsh, unsigned short* __restrict__ S)
{
    constexpr int GPR = CIN / 4;            // threads per row
    constexpr int R = 256 / GPR;            // rows per block
    constexpr int BPB = NPTS / R;           // blocks per batch

    __shared__ int nidx[R * KNN];

    int tid = threadIdx.x;
    int blk = blockIdx.x;
    int xcd = blk & 7;
    int idx = blk >> 3;
    int batch = xcd + 8 * (idx / BPB);
    int within = idx % BPB;
    int node0 = batch * NPTS + within * R;

    if (tid < R * KNN / 4) {
        const int4* ksrc = (const int4*)(knn + (size_t)node0 * KNN);
        ((int4*)nidx)[tid] = ksrc[tid];
    }
    __syncthreads();

    int t = tid & (GPR - 1);
    int r = tid / GPR;
    int col4 = t * 4;
    float4 scv = *(const float4*)(scsh + col4);
    float4 shv = *(const float4*)(scsh + CIN + col4);

    int row = node0 + r;
    const float* abase = ain + (size_t)batch * NPTS * CIN;

    float4 v = *(const float4*)(ain + (size_t)row * CIN + col4);
    float a0 = fmaxf(v.x * scv.x + shv.x, 0.f);
    float a1v = fmaxf(v.y * scv.y + shv.y, 0.f);
    float a2v = fmaxf(v.z * scv.z + shv.z, 0.f);
    float a3v = fmaxf(v.w * scv.w + shv.w, 0.f);
    #pragma unroll
    for (int jn = 0; jn < KNN; jn++) {
        int src = nidx[r * KNN + jn];
        float4 wv = *(const float4*)(abase + (size_t)src * CIN + col4);
        a0  += fmaxf(wv.x * scv.x + shv.x, 0.f);
        a1v += fmaxf(wv.y * scv.y + shv.y, 0.f);
        a2v += fmaxf(wv.z * scv.z + shv.z, 0.f);
        a3v += fmaxf(wv.w * scv.w + shv.w, 0.f);
    }
    uint2 o;
    o.x = f2hu(a0)  | ((unsigned)f2hu(a1v) << 16);
    o.y = f2hu(a2v) | ((unsigned)f2hu(a3v) << 16);
    *(uint2*)(S + (size_t)row * CIN + col4) = o;
}

// ---------------------------------------------------------------------------
// k_gemm<CIN,COUT,STORE>: dense streaming GEMM on staged fp16 rows.
// No LDS, no barriers; direct 16-B fragment loads; fp16 MFMA, fp32 acc.
// MT=64 rows/block, 2048 blocks. Epilogue: /17+bias, store fp32, stats(+minmax).
// ---------------------------------------------------------------------------
template <int CIN, int COUT, bool STORE>
__global__ __launch_bounds__(256) void k_gemm(
    const unsigned short* __restrict__ S, const unsigned short* __restrict__ WT,
    const float* __restrict__ bias,
    float* __restrict__ aout, float* __restrict__ statsOut, unsigned* __restrict__ mm)
{
    constexpr int KC = CIN / 32;
    constexpr int NT = COUT / 64;           // 16-wide n-tiles per wave
    constexpr int BPB = NPTS / 64;          // 128 blocks per batch

    int tid = threadIdx.x;
    int blk = blockIdx.x;                   // 2048 blocks
    int xcd = blk & 7;
    int idx = blk >> 3;
    int batch = xcd + 8 * (idx / BPB);
    int within = idx % BPB;
    int node0 = batch * NPTS + within * 64;
    int pout = batch * 4 + (within >> 5);   // 64-way stats partition

    int lane = tid & 63, wv = tid >> 6;
    int n15 = lane & 15, qd = lane >> 4;
    int c0 = wv * (COUT / 4);

    f32x4 acc[4][NT];
    #pragma unroll
    for (int m = 0; m < 4; m++)
        #pragma unroll
        for (int t2 = 0; t2 < NT; t2++) acc[m][t2] = (f32x4)(0.f);

    const unsigned short* Sbase = S + (size_t)node0 * CIN;
    #pragma unroll
    for (int kc = 0; kc < KC; kc++) {
        f16x8 wf[NT];
        #pragma unroll
        for (int nt = 0; nt < NT; nt++)
            wf[nt] = *(const f16x8*)(WT + (size_t)(c0 + nt * 16 + n15) * CIN + kc * 32 + qd * 8);
        #pragma unroll
        for (int m = 0; m < 4; m++) {
            f16x8 af = *(const f16x8*)(Sbase + (size_t)(m * 16 + n15) * CIN + kc * 32 + qd * 8);
            #pragma unroll
            for (int nt = 0; nt < NT; nt++)
                acc[m][nt] = __builtin_amdgcn_mfma_f32_16x16x32_f16(af, wf[nt], acc[m][nt], 0, 0, 0);
        }
    }

    // ---- epilogue
    #pragma unroll
    for (int nt = 0; nt < NT; nt++) {
        int c = c0 + nt * 16 + n15;
        float bz = bias[c];
        float s = 0.f, q = 0.f, mx = -3.4e38f, mn = 3.4e38f;
        #pragma unroll
        for (int m = 0; m < 4; m++) {
            #pragma unroll
            for (int r = 0; r < 4; r++) {
                float v = acc[m][nt][r] * DEGINV + bz;
                if (STORE) {
                    int node = node0 + m * 16 + qd * 4 + r;
                    aout[(size_t)node * COUT + c] = v;
                }
                s += v; q += v * v;
                mx = fmaxf(mx, v); mn = fminf(mn, v);
            }
        }
        s += __shfl_xor(s, 16); s += __shfl_xor(s, 32);
        q += __shfl_xor(q, 16); q += __shfl_xor(q, 32);
        if (!STORE) {
            mx = fmaxf(mx, __shfl_xor(mx, 16)); mx = fmaxf(mx, __shfl_xor(mx, 32));
            mn = fminf(mn, __shfl_xor(mn, 16)); mn = fminf(mn, __shfl_xor(mn, 32));
        }
        if (lane < 16) {
            atomicAdd(statsOut + (size_t)pout * 2 * COUT + c, s);
            atomicAdd(statsOut + (size_t)pout * 2 * COUT + COUT + c, q);
            if (!STORE) {
                atomicMax(mm + batch * COUT + c, fenc(mx));
                atomicMin(mm + BATCH * COUT + batch * COUT + c, fenc(mn));
            }
        }
    }
}

// ---------------------------------------------------------------------------
// k_e2: pooled codeword from min/max + BN3, then Linear(512,512) -> a4, stats4
// ---------------------------------------------------------------------------
__global__ __launch_bounds__(256) void k_e2(
    const float* __restrict__ stats3p, const unsigned* __restrict__ mm,
    const float* __restrict__ g2g, const float* __restrict__ g2be,
    const float* __restrict__ e2w, const float* __restrict__ e2b,
    float* __restrict__ a4, float* __restrict__ stats4)
{
    __shared__ float pooled[512];
    int b = blockIdx.x, tid = threadIdx.x;
    for (int c = tid; c < 512; c += 256) {
        float s = 0.f, qq = 0.f;
        for (int p = 0; p < 64; p++) {
            s += stats3p[p * 1024 + c];
            qq += stats3p[p * 1024 + 512 + c];
        }
        float m = s * (1.f / NROWS);
        float var = fmaxf(qq * (1.f / NROWS) - m * m, 0.f);
        float sc = g2g[c] * rsqrtf(var + EPSBN);
        float sh = g2be[c] - m * sc;
        float amax = fdec(mm[b * 512 + c]);
        float amin = fdec(mm[8192 + b * 512 + c]);
        pooled[c] = fmaxf(fmaxf(sc * amax + sh, 0.f), fmaxf(sc * amin + sh, 0.f));
    }
    __syncthreads();
    int ca = tid, cb = tid + 256;
    float acc1 = e2b[ca], acc2 = e2b[cb];
    for (int f = 0; f < 512; f++) {
        float pv = pooled[f];
        acc1 += pv * e2w[f * 512 + ca];
        acc2 += pv * e2w[f * 512 + cb];
    }
    a4[b * 512 + ca] = acc1; a4[b * 512 + cb] = acc2;
    atomicAdd(stats4 + ca, acc1); atomicAdd(stats4 + 512 + ca, acc1 * acc1);
    atomicAdd(stats4 + cb, acc2); atomicAdd(stats4 + 512 + cb, acc2 * acc2);
}

// ---------------------------------------------------------------------------
// k_code: BN4+relu -> code; c1 = code@d1_w[:512], c2 = code@d2_w[:512]
// ---------------------------------------------------------------------------
__global__ __launch_bounds__(256) void k_code(
    const float* __restrict__ a4, const float* __restrict__ stats4,
    const float* __restrict__ e2g, const float* __restrict__ e2be,
    const float* __restrict__ d1w, const float* __restrict__ d2w,
    const float* __restrict__ gn,
    float* __restrict__ c1, float* __restrict__ c2,
    float* __restrict__ c1stats, float* __restrict__ gnstats)
{
    int b = blockIdx.x, tid = threadIdx.x;
    int lane = tid & 63, wv = tid >> 6;
    float p1[3] = {0, 0, 0}, p2[3] = {0, 0, 0};
    for (int c = tid; c < 512; c += 256) {
        float s = stats4[c], qq = stats4[512 + c];
        float m = s * (1.f / 16.f);
        float var = fmaxf(qq * (1.f / 16.f) - m * m, 0.f);
        float sc = e2g[c] * rsqrtf(var + EPSBN);
        float sh = e2be[c] - m * sc;
        float cv = fmaxf(sc * a4[b * 512 + c] + sh, 0.f);
        #pragma unroll
        for (int j = 0; j < 3; j++) {
            p1[j] += cv * d1w[c * 3 + j];
            p2[j] += cv * d2w[c * 3 + j];
        }
    }
    __shared__ float red[4][6];
    #pragma unroll
    for (int j = 0; j < 3; j++)
        for (int off = 32; off; off >>= 1) {
            p1[j] += __shfl_xor(p1[j], off);
            p2[j] += __shfl_xor(p2[j], off);
        }
    if (lane == 0) {
        #pragma unroll
        for (int j = 0; j < 3; j++) { red[wv][j] = p1[j]; red[wv][3 + j] = p2[j]; }
    }
    __syncthreads();
    if (tid < 3) {
        float v = red[0][tid] + red[1][tid] + red[2][tid] + red[3][tid];
        c1[b * 3 + tid] = v;
        atomicAdd(c1stats + tid, v);
        atomicAdd(c1stats + 3 + tid, v * v);
    } else if (tid < 6) {
        int j = tid - 3;
        float v = red[0][tid] + red[1][tid] + red[2][tid] + red[3][tid];
        c2[b * 3 + j] = v;
    }
    if (blockIdx.x == 0) {
        float g1[3] = {0, 0, 0}, g2s[3] = {0, 0, 0};
        for (int n = tid; n < NPTS; n += 256) {
            #pragma unroll
            for (int j = 0; j < 3; j++) {
                float g = gn[n * 3 + j];
                g1[j] += g; g2s[j] += g * g;
            }
        }
        #pragma unroll
        for (int j = 0; j < 3; j++)
            for (int off = 32; off; off >>= 1) {
                g1[j] += __shfl_xor(g1[j], off);
                g2s[j] += __shfl_xor(g2s[j], off);
            }
        __shared__ float redg[4][6];
        if (lane == 0) {
            #pragma unroll
            for (int j = 0; j < 3; j++) { redg[wv][j] = g1[j]; redg[wv][3 + j] = g2s[j]; }
        }
        __syncthreads();
        if (tid < 6)
            gnstats[tid] = redg[0][tid] + redg[1][tid] + redg[2][tid] + redg[3][tid];
    }
}

// ---------------------------------------------------------------------------
__device__ __forceinline__ void d1_coefs(
    const float* c1stats, const float* gnstats,
    const float* d1g, const float* d1be, float* scd, float* shd)
{
    #pragma unroll
    for (int j = 0; j < 3; j++) {
        float mc = c1stats[j] * (1.f / 16.f), qc = c1stats[3 + j] * (1.f / 16.f);
        float mg = gnstats[j] * (1.f / 8192.f), qg = gnstats[3 + j] * (1.f / 8192.f);
        float m = mc + mg;
        float var = fmaxf((qc - mc * mc) + (qg - mg * mg), 0.f);
        float sc = d1g[j] * rsqrtf(var + EPSBN);
        scd[j] = sc;
        shd[j] = d1be[j] - m * sc;
    }
}

// ---------------------------------------------------------------------------
__global__ __launch_bounds__(256) void k_d2stats(
    const float* __restrict__ c1, const float* __restrict__ c2, const float* __restrict__ gn,
    const float* __restrict__ c1stats, const float* __restrict__ gnstats,
    const float* __restrict__ d1g, const float* __restrict__ d1be,
    const float* __restrict__ d2w, const float* __restrict__ d2b,
    float* __restrict__ statsd2)
{
    int gid = blockIdx.x * 256 + threadIdx.x;
    int b = gid >> 13, n = gid & 8191;
    int lane = threadIdx.x & 63, wv = threadIdx.x >> 6;
    float scd[3], shd[3];
    d1_coefs(c1stats, gnstats, d1g, d1be, scd, shd);
    float z3[3];
    #pragma unroll
    for (int j = 0; j < 3; j++)
        z3[j] = fmaxf(scd[j] * (c1[b * 3 + j] + gn[n * 3 + j]) + shd[j], 0.f);
    float vals[6];
    #pragma unroll
    for (int u = 0; u < 3; u++) {
        float a = c2[b * 3 + u]
                + z3[0] * d2w[512 * 3 + u]
                + z3[1] * d2w[513 * 3 + u]
                + z3[2] * d2w[514 * 3 + u]
                + d2b[u];
        vals[u] = a; vals[3 + u] = a * a;
    }
    #pragma unroll
    for (int j = 0; j < 6; j++)
        for (int off = 32; off; off >>= 1) vals[j] += __shfl_xor(vals[j], off);
    __shared__ float red[4][6];
    if (lane == 0) {
        #pragma unroll
        for (int j = 0; j < 6; j++) red[wv][j] = vals[j];
    }
    __syncthreads();
    if (threadIdx.x < 6)
        atomicAdd(statsd2 + threadIdx.x,
                  red[0][threadIdx.x] + red[1][threadIdx.x] + red[2][threadIdx.x] + red[3][threadIdx.x]);
}

// ---------------------------------------------------------------------------
__global__ __launch_bounds__(256) void k_out(
    const float* __restrict__ c1, const float* __restrict__ c2, const float* __restrict__ gn,
    const float* __restrict__ c1stats, const float* __restrict__ gnstats,
    const float* __restrict__ statsd2,
    const float* __restrict__ d1g, const float* __restrict__ d1be,
    const float* __restrict__ d2w, const float* __restrict__ d2b,
    const float* __restrict__ d2g, const float* __restrict__ d2be,
    float* __restrict__ out)
{
    int gid = blockIdx.x * 256 + threadIdx.x;
    int b = gid >> 13, n = gid & 8191;
    float scd[3], shd[3];
    d1_coefs(c1stats, gnstats, d1g, d1be, scd, shd);
    float z3[3];
    #pragma unroll
    for (int j = 0; j < 3; j++)
        z3[j] = fmaxf(scd[j] * (c1[b * 3 + j] + gn[n * 3 + j]) + shd[j], 0.f);
    #pragma unroll
    for (int u = 0; u < 3; u++) {
        float a = c2[b * 3 + u]
                + z3[0] * d2w[512 * 3 + u]
                + z3[1] * d2w[513 * 3 + u]
                + z3[2] * d2w[514 * 3 + u]
                + d2b[u];
        float m2 = statsd2[u] * (1.f / (float)NROWS);
        float v2 = fmaxf(statsd2[3 + u] * (1.f / (float)NROWS) - m2 * m2, 0.f);
        float sc = d2g[u] * rsqrtf(v2 + EPSBN);
        float sh = d2be[u] - m2 * sc;
        out[(size_t)gid * 3 + u] = fmaxf(sc * a + sh, 0.f);
    }
}

// ---------------------------------------------------------------------------
extern "C" void kernel_launch(void* const* d_in, const int* in_sizes, int n_in,
                              void* d_out, int out_size, void* d_ws, size_t ws_size,
                              hipStream_t stream)
{
    (void)in_sizes; (void)n_in; (void)out_size; (void)ws_size;
    const float* data = (const float*)d_in[0];
    const int*   knn  = (const int*)d_in[1];
    const float* e1w = (const float*)d_in[2],  *e1b = (const float*)d_in[3];
    const float* e1g = (const float*)d_in[4],  *e1be = (const float*)d_in[5];
    const float* gc1w = (const float*)d_in[6], *gc1b = (const float*)d_in[7];
    const float* g1g = (const float*)d_in[8],  *g1be = (const float*)d_in[9];
    const float* gc2w = (const float*)d_in[10], *gc2b = (const float*)d_in[11];
    const float* g2g = (const float*)d_in[12], *g2be = (const float*)d_in[13];
    const float* e2w = (const float*)d_in[14], *e2b = (const float*)d_in[15];
    const float* e2g = (const float*)d_in[16], *e2be = (const float*)d_in[17];
    const float* d1w = (const float*)d_in[18], *d1b = (const float*)d_in[19];
    const float* d1g = (const float*)d_in[20], *d1be = (const float*)d_in[21];
    const float* d2w = (const float*)d_in[22], *d2b = (const float*)d_in[23];
    const float* d2g = (const float*)d_in[24], *d2be = (const float*)d_in[25];

    char* p = (char*)d_ws;
    auto alloc = [&](size_t bytes) -> void* {
        void* r = (void*)p;
        p += (bytes + 255) & ~(size_t)255;
        return r;
    };
    float* a1 = (float*)alloc((size_t)NROWS * 64 * 4);     // 33.5 MB (aliased by s2 later)
    float* a2 = (float*)alloc((size_t)NROWS * 128 * 4);    // 67 MB
    unsigned short* s1 = (unsigned short*)alloc((size_t)NROWS * 64 * 2);  // 16.8 MB fp16
    unsigned short* W1T = (unsigned short*)alloc(8192 * 2);
    unsigned short* W2T = (unsigned short*)alloc(65536 * 2);
    float* statszone = (float*)alloc(SZ_TOT * 4);
    float* stats1  = statszone + SZ_S1;
    float* stats2p = statszone + SZ_S2P;
    float* stats3p = statszone + SZ_S3P;
    float* stats4  = statszone + SZ_S4;
    float* c1stats = statszone + SZ_C1;
    float* gnstats = statszone + SZ_GN;
    float* statsd2 = statszone + SZ_D2;
    float* scsh1   = statszone + SZ_SCSH1;
    float* scsh2   = statszone + SZ_SCSH2;
    unsigned* mm = (unsigned*)alloc(16384 * 4);
    float* a4 = (float*)alloc(16 * 512 * 4);
    float* c1 = (float*)alloc(64 * 4);
    float* c2 = (float*)alloc(64 * 4);
    float* gn = (float*)alloc(8192 * 3 * 4);
    // s2 (131072x128 fp16 = 33.5 MB) aliases a1 (dead after k_gather<64>)
    unsigned short* s2 = (unsigned short*)a1;

    k_prep<<<64, 256, 0, stream>>>(gc1w, gc2w, d1w, d1b, W1T, W2T, gn, statszone, mm);
    k_cov_e1<<<512, 256, 0, stream>>>(data, knn, e1w, e1b, a1);
    k_reduce_a1<<<256, 256, 0, stream>>>(a1, stats1);
    k_bncoef<64, 1><<<1, 256, 0, stream>>>(stats1, e1g, e1be, scsh1);
    k_gather<64><<<NROWS / 16, 256, 0, stream>>>(a1, knn, scsh1, s1);
    k_gemm<64, 128, true><<<2048, 256, 0, stream>>>(s1, W1T, gc1b, a2, stats2p, nullptr);
    k_bncoef<128, 64><<<1, 256, 0, stream>>>(stats2p, g1g, g1be, scsh2);
    k_gather<128><<<NROWS / 8, 256, 0, stream>>>(a2, knn, scsh2, s2);
    k_gemm<128, 512, false><<<2048, 256, 0, stream>>>(s2, W2T, gc2b, nullptr, stats3p, mm);
    k_e2<<<16, 256, 0, stream>>>(stats3p, mm, g2g, g2be, e2w, e2b, a4, stats4);
    k_code<<<16, 256, 0, stream>>>(a4, stats4, e2g, e2be, d1w, d2w, gn, c1, c2, c1stats, gnstats);
    k_d2stats<<<512, 256, 0, stream>>>(c1, c2, gn, c1stats, gnstats, d1g, d1be, d2w, d2b, statsd2);
    k_out<<<512, 256, 0, stream>>>(c1, c2, gn, c1stats, gnstats, statsd2,
                                   d1g, d1be, d2w, d2b, d2g, d2be, (float*)d_out);
}

// Round 9
// 404.352 us; speedup vs baseline: 10.5886x; 1.0519x over previous
//
#include <hip/hip_runtime.h>
#include <hip/hip_fp16.h>
#include <stdint.h>

#define BATCH 16
#define NPTS  8192
#define KNN   16
#define NROWS (BATCH*NPTS)     // 131072
#define EPSBN 1e-5f
#define DEGINV (1.0f/17.0f)

typedef _Float16 f16x8 __attribute__((ext_vector_type(8)));
typedef float    f32x4 __attribute__((ext_vector_type(4)));

__device__ __forceinline__ unsigned short f2hu(float f) {
    union { _Float16 h; unsigned short u; } cv;
    cv.h = (_Float16)f;
    return cv.u;
}
__device__ __forceinline__ float hu2f(unsigned short u) {
    union { unsigned short u; _Float16 h; } cv;
    cv.u = u;
    return (float)cv.h;
}
// order-preserving float <-> uint encoding (for atomic min/max)
__device__ __forceinline__ unsigned fenc(float f) {
    unsigned u = __float_as_uint(f);
    return (int)u >= 0 ? (u | 0x80000000u) : ~u;
}
__device__ __forceinline__ float fdec(unsigned k) {
    return (k & 0x80000000u) ? __uint_as_float(k & 0x7FFFFFFFu) : __uint_as_float(~k);
}

// stats zone layout (floats):
#define SZ_S1    0        // stats1: 64 sum + 64 sumsq
#define SZ_S2P   128      // stats2p: 64 x (128+128)
#define SZ_S3P   16512    // stats3p: 64 x (512+512)
#define SZ_S4    82048    // stats4: 512+512
#define SZ_C1    83072
#define SZ_GN    83080
#define SZ_D2    83088
#define SZ_SCSH1 83096    // 2*64 bn coefs for layer1 input
#define SZ_SCSH2 83224    // 2*128 bn coefs for layer2 input
#define SZ_TOT   83480

// ---------------------------------------------------------------------------
// k_prep: zero stats, init min/max sentinels, build fp16 W^T copies, grid feats
// ---------------------------------------------------------------------------
__global__ __launch_bounds__(256) void k_prep(
    const float* __restrict__ gc1w, const float* __restrict__ gc2w,
    const float* __restrict__ d1w, const float* __restrict__ d1b,
    unsigned short* __restrict__ W1T, unsigned short* __restrict__ W2T,
    float* __restrict__ gn, float* __restrict__ statszone, unsigned* __restrict__ mm)
{
    int t = blockIdx.x * 256 + threadIdx.x;
    int NT_ = gridDim.x * 256;
    for (int i = t; i < 65536; i += NT_) {          // W2T[c][k] = gc2_w[k][c]
        int c = i >> 7, k = i & 127;
        W2T[i] = f2hu(gc2w[k * 512 + c]);
    }
    for (int i = t; i < 8192; i += NT_) {           // W1T[c][k] = gc1_w[k][c]
        int c = i >> 6, k = i & 63;
        W1T[i] = f2hu(gc1w[k * 128 + c]);
    }
    for (int i = t; i < SZ_TOT; i += NT_) statszone[i] = 0.f;
    for (int i = t; i < 8192; i += NT_) mm[i] = 0u;                 // max enc
    for (int i = t; i < 8192; i += NT_) mm[8192 + i] = 0xFFFFFFFFu; // min enc
    for (int n = t; n < 8192; n += NT_) {
        int ix = n / 65, iy = n % 65;
        float gx = 1.f + ix * (119.f / 128.f);
        float gy = 1.f + iy * (59.f / 64.f);
        #pragma unroll
        for (int j = 0; j < 3; j++)
            gn[n * 3 + j] = gx * d1w[512 * 3 + j] + gy * d1w[513 * 3 + j] + d1b[j];
    }
}

// ---------------------------------------------------------------------------
// k_cov_e1: covariance features + Linear(12,64) -> a1 [131072][64] fp32
// ---------------------------------------------------------------------------
__global__ __launch_bounds__(256) void k_cov_e1(
    const float* __restrict__ data, const int* __restrict__ knn,
    const float* __restrict__ e1w, const float* __restrict__ e1b,
    float* __restrict__ a1)
{
    __shared__ float w[12 * 64];
    __shared__ float bias[64];
    int tid = threadIdx.x;
    for (int i = tid; i < 768; i += 256) w[i] = e1w[i];
    if (tid < 64) bias[tid] = e1b[tid];
    __syncthreads();

    int gid = blockIdx.x * 256 + tid;
    int b = gid >> 13;
    const float* db = data + (size_t)b * NPTS * 3;
    const int4* k4 = (const int4*)knn + gid * 4;

    float sx = 0, sy = 0, sz = 0, Sxx = 0, Sxy = 0, Sxz = 0, Syy = 0, Syz = 0, Szz = 0;
    #pragma unroll
    for (int jj = 0; jj < 4; jj++) {
        int4 q = k4[jj];
        int id[4] = {q.x, q.y, q.z, q.w};
        #pragma unroll
        for (int u = 0; u < 4; u++) {
            const float* p = db + (size_t)id[u] * 3;
            float x = p[0], y = p[1], z = p[2];
            sx += x; sy += y; sz += z;
            Sxx += x * x; Sxy += x * y; Sxz += x * z;
            Syy += y * y; Syz += y * z; Szz += z * z;
        }
    }
    float mx = sx * (1.f / 16.f), my = sy * (1.f / 16.f), mz = sz * (1.f / 16.f);
    const float inv15 = 1.f / 15.f;
    float x12[12];
    x12[0] = data[(size_t)gid * 3 + 0];
    x12[1] = data[(size_t)gid * 3 + 1];
    x12[2] = data[(size_t)gid * 3 + 2];
    x12[3] = (Sxx - 16.f * mx * mx) * inv15;
    x12[4] = (Sxy - 16.f * mx * my) * inv15;
    x12[5] = (Sxz - 16.f * mx * mz) * inv15;
    x12[6] = x12[4];
    x12[7] = (Syy - 16.f * my * my) * inv15;
    x12[8] = (Syz - 16.f * my * mz) * inv15;
    x12[9] = x12[5];
    x12[10] = x12[8];
    x12[11] = (Szz - 16.f * mz * mz) * inv15;

    float* arow = a1 + (size_t)gid * 64;
    for (int c0 = 0; c0 < 64; c0 += 4) {
        float4 v;
        float* vv = (float*)&v;
        #pragma unroll
        for (int u = 0; u < 4; u++) {
            int c = c0 + u;
            float acc = bias[c];
            #pragma unroll
            for (int i = 0; i < 12; i++) acc += x12[i] * w[i * 64 + c];
            vv[u] = acc;
        }
        *(float4*)(arow + c0) = v;
    }
}

// ---------------------------------------------------------------------------
// k_reduce_a1: per-channel sum/sumsq of a1 (C=64) -> stats1
// ---------------------------------------------------------------------------
__global__ __launch_bounds__(256) void k_reduce_a1(
    const float* __restrict__ a1, float* __restrict__ stats1)
{
    int tid = threadIdx.x;
    int c = tid & 63, rq = tid >> 6;
    float s = 0.f, q = 0.f;
    for (int row = blockIdx.x * 4 + rq; row < NROWS; row += gridDim.x * 4) {
        float v = a1[(size_t)row * 64 + c];
        s += v; q += v * v;
    }
    __shared__ float red[2][256];
    red[0][tid] = s; red[1][tid] = q;
    __syncthreads();
    if (tid < 64) {
        s = red[0][tid] + red[0][tid + 64] + red[0][tid + 128] + red[0][tid + 192];
        q = red[1][tid] + red[1][tid + 64] + red[1][tid + 128] + red[1][tid + 192];
        atomicAdd(stats1 + tid, s);
        atomicAdd(stats1 + 64 + tid, q);
    }
}

// ---------------------------------------------------------------------------
// k_bncoef<C,NPARTS>: collapse partitioned stats -> (sc, sh) coef arrays
// ---------------------------------------------------------------------------
template <int C, int NPARTS>
__global__ __launch_bounds__(256) void k_bncoef(
    const float* __restrict__ statsIn,
    const float* __restrict__ gamma, const float* __restrict__ beta,
    float* __restrict__ scsh)
{
    int ch = threadIdx.x;
    if (ch < C) {
        float s = 0.f, q = 0.f;
        for (int p = 0; p < NPARTS; p++) {
            s += statsIn[p * 2 * C + ch];
            q += statsIn[p * 2 * C + C + ch];
        }
        float m = s * (1.f / NROWS);
        float var = fmaxf(q * (1.f / NROWS) - m * m, 0.f);
        float sc = gamma[ch] * rsqrtf(var + EPSBN);
        scsh[ch] = sc;
        scsh[C + ch] = beta[ch] - m * sc;
    }
}

// ---------------------------------------------------------------------------
// k_gather (fp32 in): s[row] = bn_relu(a[row]) + sum_j bn_relu(a[knn_j]) -> fp16
// One thread per (row, 4-ch chunk): 17 independent float4 loads in flight.
// ---------------------------------------------------------------------------
template <int CIN>
__global__ __launch_bounds__(256) void k_gather(
    const float* __restrict__ ain, const int* __restrict__ knn,
    const float* __restrict__ scsh, unsigned short* __restrict__ S)
{
    constexpr int GPR = CIN / 4;
    constexpr int R = 256 / GPR;
    constexpr int BPB = NPTS / R;

    __shared__ int nidx[R * KNN];

    int tid = threadIdx.x;
    int blk = blockIdx.x;
    int xcd = blk & 7;
    int idx = blk >> 3;
    int batch = xcd + 8 * (idx / BPB);
    int within = idx % BPB;
    int node0 = batch * NPTS + within * R;

    if (tid < R * KNN / 4) {
        const int4* ksrc = (const int4*)(knn + (size_t)node0 * KNN);
        ((int4*)nidx)[tid] = ksrc[tid];
    }
    __syncthreads();

    int t = tid & (GPR - 1);
    int r = tid / GPR;
    int col4 = t * 4;
    float4 scv = *(const float4*)(scsh + col4);
    float4 shv = *(const float4*)(scsh + CIN + col4);

    int row = node0 + r;
    const float* abase = ain + (size_t)batch * NPTS * CIN;

    float4 v = *(const float4*)(ain + (size_t)row * CIN + col4);
    float a0 = fmaxf(v.x * scv.x + shv.x, 0.f);
    float a1v = fmaxf(v.y * scv.y + shv.y, 0.f);
    float a2v = fmaxf(v.z * scv.z + shv.z, 0.f);
    float a3v = fmaxf(v.w * scv.w + shv.w, 0.f);
    #pragma unroll
    for (int jn = 0; jn < KNN; jn++) {
        int src = nidx[r * KNN + jn];
        float4 wv = *(const float4*)(abase + (size_t)src * CIN + col4);
        a0  += fmaxf(wv.x * scv.x + shv.x, 0.f);
        a1v += fmaxf(wv.y * scv.y + shv.y, 0.f);
        a2v += fmaxf(wv.z * scv.z + shv.z, 0.f);
        a3v += fmaxf(wv.w * scv.w + shv.w, 0.f);
    }
    uint2 o;
    o.x = f2hu(a0)  | ((unsigned)f2hu(a1v) << 16);
    o.y = f2hu(a2v) | ((unsigned)f2hu(a3v) << 16);
    *(uint2*)(S + (size_t)row * CIN + col4) = o;
}

// ---------------------------------------------------------------------------
// k_gather16 (fp16 in): same but input is fp16, 8 ch/thread, 16-B loads.
// ---------------------------------------------------------------------------
template <int CIN>
__global__ __launch_bounds__(256) void k_gather16(
    const unsigned short* __restrict__ ain, const int* __restrict__ knn,
    const float* __restrict__ scsh, unsigned short* __restrict__ S)
{
    constexpr int GPR = CIN / 8;            // 16 threads per row
    constexpr int R = 256 / GPR;            // 16 rows per block
    constexpr int BPB = NPTS / R;

    __shared__ int nidx[R * KNN];

    int tid = threadIdx.x;
    int blk = blockIdx.x;
    int xcd = blk & 7;
    int idx = blk >> 3;
    int batch = xcd + 8 * (idx / BPB);
    int within = idx % BPB;
    int node0 = batch * NPTS + within * R;

    if (tid < R * KNN / 4) {
        const int4* ksrc = (const int4*)(knn + (size_t)node0 * KNN);
        ((int4*)nidx)[tid] = ksrc[tid];
    }
    __syncthreads();

    int t = tid & (GPR - 1);
    int r = tid / GPR;
    int col8 = t * 8;
    float sc8[8], sh8[8];
    #pragma unroll
    for (int j = 0; j < 8; j++) { sc8[j] = scsh[col8 + j]; sh8[j] = scsh[CIN + col8 + j]; }

    int row = node0 + r;
    const unsigned short* abase = ain + (size_t)batch * NPTS * CIN;

    float acc8[8];
    {
        uint4 v = *(const uint4*)(ain + (size_t)row * CIN + col8);
        unsigned wds[4] = {v.x, v.y, v.z, v.w};
        #pragma unroll
        for (int j = 0; j < 4; j++) {
            acc8[2*j]   = fmaxf(hu2f((unsigned short)(wds[j] & 0xFFFF)) * sc8[2*j]   + sh8[2*j],   0.f);
            acc8[2*j+1] = fmaxf(hu2f((unsigned short)(wds[j] >> 16))    * sc8[2*j+1] + sh8[2*j+1], 0.f);
        }
    }
    #pragma unroll
    for (int jn = 0; jn < KNN; jn++) {
        int src = nidx[r * KNN + jn];
        uint4 v = *(const uint4*)(abase + (size_t)src * CIN + col8);
        unsigned wds[4] = {v.x, v.y, v.z, v.w};
        #pragma unroll
        for (int j = 0; j < 4; j++) {
            acc8[2*j]   += fmaxf(hu2f((unsigned short)(wds[j] & 0xFFFF)) * sc8[2*j]   + sh8[2*j],   0.f);
            acc8[2*j+1] += fmaxf(hu2f((unsigned short)(wds[j] >> 16))    * sc8[2*j+1] + sh8[2*j+1], 0.f);
        }
    }
    uint4 o;
    o.x = f2hu(acc8[0]) | ((unsigned)f2hu(acc8[1]) << 16);
    o.y = f2hu(acc8[2]) | ((unsigned)f2hu(acc8[3]) << 16);
    o.z = f2hu(acc8[4]) | ((unsigned)f2hu(acc8[5]) << 16);
    o.w = f2hu(acc8[6]) | ((unsigned)f2hu(acc8[7]) << 16);
    *(uint4*)(S + (size_t)row * CIN + col8) = o;
}

// ---------------------------------------------------------------------------
// k_gemm<CIN,COUT,STORE>: streaming GEMM with W held in registers.
// MT=128 rows/block, 1024 blocks. Wave owns COUT/4 channels, processed in two
// halves; per half all KC*NT/2 W fragments live in VGPRs and A streams through.
// Stats accumulate in registers across m-tiles (one atomic set per half).
// STORE=true writes aout fp16.
// ---------------------------------------------------------------------------
template <int CIN, int COUT, bool STORE>
__global__ __launch_bounds__(256) void k_gemm(
    const unsigned short* __restrict__ S, const unsigned short* __restrict__ WT,
    const float* __restrict__ bias,
    unsigned short* __restrict__ aout, float* __restrict__ statsOut, unsigned* __restrict__ mm)
{
    constexpr int KC = CIN / 32;
    constexpr int NT = COUT / 64;           // n-tiles per wave
    constexpr int NHALF = (NT >= 2) ? 2 : 1;
    constexpr int NTH = NT / NHALF;
    constexpr int MT = 128;
    constexpr int BPB = NPTS / MT;          // 64 blocks per batch

    int tid = threadIdx.x;
    int blk = blockIdx.x;                   // 1024 blocks
    int xcd = blk & 7;
    int idx = blk >> 3;
    int batch = xcd + 8 * (idx / BPB);
    int within = idx % BPB;
    int node0 = batch * NPTS + within * MT;
    int pout = batch * 4 + (within >> 4);   // 64-way stats partition

    int lane = tid & 63, wv = tid >> 6;
    int n15 = lane & 15, qd = lane >> 4;
    int c0 = wv * (COUT / 4);

    const unsigned short* Sbase = S + (size_t)node0 * CIN + (size_t)n15 * CIN + qd * 8;

    #pragma unroll
    for (int half = 0; half < NHALF; half++) {
        // W fragments for this half: resident in VGPRs for all m-tiles
        f16x8 wf[KC][NTH];
        float bz[NTH];
        #pragma unroll
        for (int nth = 0; nth < NTH; nth++) {
            int c = c0 + (half * NTH + nth) * 16 + n15;
            bz[nth] = bias[c];
            #pragma unroll
            for (int kc = 0; kc < KC; kc++)
                wf[kc][nth] = *(const f16x8*)(WT + (size_t)c * CIN + kc * 32 + qd * 8);
        }
        float sA[NTH], qA[NTH], mxA[NTH], mnA[NTH];
        #pragma unroll
        for (int nth = 0; nth < NTH; nth++) {
            sA[nth] = 0.f; qA[nth] = 0.f; mxA[nth] = -3.4e38f; mnA[nth] = 3.4e38f;
        }

        for (int mt = 0; mt < MT / 16; mt++) {
            f16x8 af[KC];
            #pragma unroll
            for (int kc = 0; kc < KC; kc++)
                af[kc] = *(const f16x8*)(Sbase + (size_t)mt * 16 * CIN + kc * 32);

            f32x4 acc[NTH];
            #pragma unroll
            for (int nth = 0; nth < NTH; nth++) acc[nth] = (f32x4)(0.f);
            #pragma unroll
            for (int kc = 0; kc < KC; kc++)
                #pragma unroll
                for (int nth = 0; nth < NTH; nth++)
                    acc[nth] = __builtin_amdgcn_mfma_f32_16x16x32_f16(af[kc], wf[kc][nth], acc[nth], 0, 0, 0);

            #pragma unroll
            for (int nth = 0; nth < NTH; nth++) {
                int c = c0 + (half * NTH + nth) * 16 + n15;
                #pragma unroll
                for (int r = 0; r < 4; r++) {
                    float v = acc[nth][r] * DEGINV + bz[nth];
                    if (STORE) {
                        int node = node0 + mt * 16 + qd * 4 + r;
                        aout[(size_t)node * COUT + c] = f2hu(v);
                    }
                    sA[nth] += v; qA[nth] += v * v;
                    mxA[nth] = fmaxf(mxA[nth], v); mnA[nth] = fminf(mnA[nth], v);
                }
            }
        }

        // reduce stats across the wave's 4 row-quadrants, one atomic set per half
        #pragma unroll
        for (int nth = 0; nth < NTH; nth++) {
            int c = c0 + (half * NTH + nth) * 16 + n15;
            float s = sA[nth], q = qA[nth];
            s += __shfl_xor(s, 16); s += __shfl_xor(s, 32);
            q += __shfl_xor(q, 16); q += __shfl_xor(q, 32);
            if (!STORE) {
                float mx = mxA[nth], mn = mnA[nth];
                mx = fmaxf(mx, __shfl_xor(mx, 16)); mx = fmaxf(mx, __shfl_xor(mx, 32));
                mn = fminf(mn, __shfl_xor(mn, 16)); mn = fminf(mn, __shfl_xor(mn, 32));
                if (lane < 16) {
                    atomicMax(mm + batch * COUT + c, fenc(mx));
                    atomicMin(mm + BATCH * COUT + batch * COUT + c, fenc(mn));
                }
            }
            if (lane < 16) {
                atomicAdd(statsOut + (size_t)pout * 2 * COUT + c, s);
                atomicAdd(statsOut + (size_t)pout * 2 * COUT + COUT + c, q);
            }
        }
    }
}

// ---------------------------------------------------------------------------
// k_e2: pooled codeword from min/max + BN3, then Linear(512,512) -> a4, stats4
// ---------------------------------------------------------------------------
__global__ __launch_bounds__(256) void k_e2(
    const float* __restrict__ stats3p, const unsigned* __restrict__ mm,
    const float* __restrict__ g2g, const float* __restrict__ g2be,
    const float* __restrict__ e2w, const float* __restrict__ e2b,
    float* __restrict__ a4, float* __restrict__ stats4)
{
    __shared__ float pooled[512];
    int b = blockIdx.x, tid = threadIdx.x;
    for (int c = tid; c < 512; c += 256) {
        float s = 0.f, qq = 0.f;
        for (int p = 0; p < 64; p++) {
            s += stats3p[p * 1024 + c];
            qq += stats3p[p * 1024 + 512 + c];
        }
        float m = s * (1.f / NROWS);
        float var = fmaxf(qq * (1.f / NROWS) - m * m, 0.f);
        float sc = g2g[c] * rsqrtf(var + EPSBN);
        float sh = g2be[c] - m * sc;
        float amax = fdec(mm[b * 512 + c]);
        float amin = fdec(mm[8192 + b * 512 + c]);
        pooled[c] = fmaxf(fmaxf(sc * amax + sh, 0.f), fmaxf(sc * amin + sh, 0.f));
    }
    __syncthreads();
    int ca = tid, cb = tid + 256;
    float acc1 = e2b[ca], acc2 = e2b[cb];
    for (int f = 0; f < 512; f++) {
        float pv = pooled[f];
        acc1 += pv * e2w[f * 512 + ca];
        acc2 += pv * e2w[f * 512 + cb];
    }
    a4[b * 512 + ca] = acc1; a4[b * 512 + cb] = acc2;
    atomicAdd(stats4 + ca, acc1); atomicAdd(stats4 + 512 + ca, acc1 * acc1);
    atomicAdd(stats4 + cb, acc2); atomicAdd(stats4 + 512 + cb, acc2 * acc2);
}

// ---------------------------------------------------------------------------
// k_code: BN4+relu -> code; c1 = code@d1_w[:512], c2 = code@d2_w[:512]
// ---------------------------------------------------------------------------
__global__ __launch_bounds__(256) void k_code(
    const float* __restrict__ a4, const float* __restrict__ stats4,
    const float* __restrict__ e2g, const float* __restrict__ e2be,
    const float* __restrict__ d1w, const float* __restrict__ d2w,
    const float* __restrict__ gn,
    float* __restrict__ c1, float* __restrict__ c2,
    float* __restrict__ c1stats, float* __restrict__ gnstats)
{
    int b = blockIdx.x, tid = threadIdx.x;
    int lane = tid & 63, wv = tid >> 6;
    float p1[3] = {0, 0, 0}, p2[3] = {0, 0, 0};
    for (int c = tid; c < 512; c += 256) {
        float s = stats4[c], qq = stats4[512 + c];
        float m = s * (1.f / 16.f);
        float var = fmaxf(qq * (1.f / 16.f) - m * m, 0.f);
        float sc = e2g[c] * rsqrtf(var + EPSBN);
        float sh = e2be[c] - m * sc;
        float cv = fmaxf(sc * a4[b * 512 + c] + sh, 0.f);
        #pragma unroll
        for (int j = 0; j < 3; j++) {
            p1[j] += cv * d1w[c * 3 + j];
            p2[j] += cv * d2w[c * 3 + j];
        }
    }
    __shared__ float red[4][6];
    #pragma unroll
    for (int j = 0; j < 3; j++)
        for (int off = 32; off; off >>= 1) {
            p1[j] += __shfl_xor(p1[j], off);
            p2[j] += __shfl_xor(p2[j], off);
        }
    if (lane == 0) {
        #pragma unroll
        for (int j = 0; j < 3; j++) { red[wv][j] = p1[j]; red[wv][3 + j] = p2[j]; }
    }
    __syncthreads();
    if (tid < 3) {
        float v = red[0][tid] + red[1][tid] + red[2][tid] + red[3][tid];
        c1[b * 3 + tid] = v;
        atomicAdd(c1stats + tid, v);
        atomicAdd(c1stats + 3 + tid, v * v);
    } else if (tid < 6) {
        int j = tid - 3;
        float v = red[0][tid] + red[1][tid] + red[2][tid] + red[3][tid];
        c2[b * 3 + j] = v;
    }
    if (blockIdx.x == 0) {
        float g1[3] = {0, 0, 0}, g2s[3] = {0, 0, 0};
        for (int n = tid; n < NPTS; n += 256) {
            #pragma unroll
            for (int j = 0; j < 3; j++) {
                float g = gn[n * 3 + j];
                g1[j] += g; g2s[j] += g * g;
            }
        }
        #pragma unroll
        for (int j = 0; j < 3; j++)
            for (int off = 32; off; off >>= 1) {
                g1[j] += __shfl_xor(g1[j], off);
                g2s[j] += __shfl_xor(g2s[j], off);
            }
        __shared__ float redg[4][6];
        if (lane == 0) {
            #pragma unroll
            for (int j = 0; j < 3; j++) { redg[wv][j] = g1[j]; redg[wv][3 + j] = g2s[j]; }
        }
        __syncthreads();
        if (tid < 6)
            gnstats[tid] = redg[0][tid] + redg[1][tid] + redg[2][tid] + redg[3][tid];
    }
}

// ---------------------------------------------------------------------------
__device__ __forceinline__ void d1_coefs(
    const float* c1stats, const float* gnstats,
    const float* d1g, const float* d1be, float* scd, float* shd)
{
    #pragma unroll
    for (int j = 0; j < 3; j++) {
        float mc = c1stats[j] * (1.f / 16.f), qc = c1stats[3 + j] * (1.f / 16.f);
        float mg = gnstats[j] * (1.f / 8192.f), qg = gnstats[3 + j] * (1.f / 8192.f);
        float m = mc + mg;
        float var = fmaxf((qc - mc * mc) + (qg - mg * mg), 0.f);
        float sc = d1g[j] * rsqrtf(var + EPSBN);
        scd[j] = sc;
        shd[j] = d1be[j] - m * sc;
    }
}

// ---------------------------------------------------------------------------
__global__ __launch_bounds__(256) void k_d2stats(
    const float* __restrict__ c1, const float* __restrict__ c2, const float* __restrict__ gn,
    const float* __restrict__ c1stats, const float* __restrict__ gnstats,
    const float* __restrict__ d1g, const float* __restrict__ d1be,
    const float* __restrict__ d2w, const float* __restrict__ d2b,
    float* __restrict__ statsd2)
{
    int gid = blockIdx.x * 256 + threadIdx.x;
    int b = gid >> 13, n = gid & 8191;
    int lane = threadIdx.x & 63, wv = threadIdx.x >> 6;
    float scd[3], shd[3];
    d1_coefs(c1stats, gnstats, d1g, d1be, scd, shd);
    float z3[3];
    #pragma unroll
    for (int j = 0; j < 3; j++)
        z3[j] = fmaxf(scd[j] * (c1[b * 3 + j] + gn[n * 3 + j]) + shd[j], 0.f);
    float vals[6];
    #pragma unroll
    for (int u = 0; u < 3; u++) {
        float a = c2[b * 3 + u]
                + z3[0] * d2w[512 * 3 + u]
                + z3[1] * d2w[513 * 3 + u]
                + z3[2] * d2w[514 * 3 + u]
                + d2b[u];
        vals[u] = a; vals[3 + u] = a * a;
    }
    #pragma unroll
    for (int j = 0; j < 6; j++)
        for (int off = 32; off; off >>= 1) vals[j] += __shfl_xor(vals[j], off);
    __shared__ float red[4][6];
    if (lane == 0) {
        #pragma unroll
        for (int j = 0; j < 6; j++) red[wv][j] = vals[j];
    }
    __syncthreads();
    if (threadIdx.x < 6)
        atomicAdd(statsd2 + threadIdx.x,
                  red[0][threadIdx.x] + red[1][threadIdx.x] + red[2][threadIdx.x] + red[3][threadIdx.x]);
}

// ---------------------------------------------------------------------------
__global__ __launch_bounds__(256) void k_out(
    const float* __restrict__ c1, const float* __restrict__ c2, const float* __restrict__ gn,
    const float* __restrict__ c1stats, const float* __restrict__ gnstats,
    const float* __restrict__ statsd2,
    const float* __restrict__ d1g, const float* __restrict__ d1be,
    const float* __restrict__ d2w, const float* __restrict__ d2b,
    const float* __restrict__ d2g, const float* __restrict__ d2be,
    float* __restrict__ out)
{
    int gid = blockIdx.x * 256 + threadIdx.x;
    int b = gid >> 13, n = gid & 8191;
    float scd[3], shd[3];
    d1_coefs(c1stats, gnstats, d1g, d1be, scd, shd);
    float z3[3];
    #pragma unroll
    for (int j = 0; j < 3; j++)
        z3[j] = fmaxf(scd[j] * (c1[b * 3 + j] + gn[n * 3 + j]) + shd[j], 0.f);
    #pragma unroll
    for (int u = 0; u < 3; u++) {
        float a = c2[b * 3 + u]
                + z3[0] * d2w[512 * 3 + u]
                + z3[1] * d2w[513 * 3 + u]
                + z3[2] * d2w[514 * 3 + u]
                + d2b[u];
        float m2 = statsd2[u] * (1.f / (float)NROWS);
        float v2 = fmaxf(statsd2[3 + u] * (1.f / (float)NROWS) - m2 * m2, 0.f);
        float sc = d2g[u] * rsqrtf(v2 + EPSBN);
        float sh = d2be[u] - m2 * sc;
        out[(size_t)gid * 3 + u] = fmaxf(sc * a + sh, 0.f);
    }
}

// ---------------------------------------------------------------------------
extern "C" void kernel_launch(void* const* d_in, const int* in_sizes, int n_in,
                              void* d_out, int out_size, void* d_ws, size_t ws_size,
                              hipStream_t stream)
{
    (void)in_sizes; (void)n_in; (void)out_size; (void)ws_size;
    const float* data = (const float*)d_in[0];
    const int*   knn  = (const int*)d_in[1];
    const float* e1w = (const float*)d_in[2],  *e1b = (const float*)d_in[3];
    const float* e1g = (const float*)d_in[4],  *e1be = (const float*)d_in[5];
    const float* gc1w = (const float*)d_in[6], *gc1b = (const float*)d_in[7];
    const float* g1g = (const float*)d_in[8],  *g1be = (const float*)d_in[9];
    const float* gc2w = (const float*)d_in[10], *gc2b = (const float*)d_in[11];
    const float* g2g = (const float*)d_in[12], *g2be = (const float*)d_in[13];
    const float* e2w = (const float*)d_in[14], *e2b = (const float*)d_in[15];
    const float* e2g = (const float*)d_in[16], *e2be = (const float*)d_in[17];
    const float* d1w = (const float*)d_in[18], *d1b = (const float*)d_in[19];
    const float* d1g = (const float*)d_in[20], *d1be = (const float*)d_in[21];
    const float* d2w = (const float*)d_in[22], *d2b = (const float*)d_in[23];
    const float* d2g = (const float*)d_in[24], *d2be = (const float*)d_in[25];

    char* p = (char*)d_ws;
    auto alloc = [&](size_t bytes) -> void* {
        void* r = (void*)p;
        p += (bytes + 255) & ~(size_t)255;
        return r;
    };
    float* a1 = (float*)alloc((size_t)NROWS * 64 * 4);      // 33.5 MB fp32 (s2 aliases later)
    unsigned short* a2h = (unsigned short*)alloc((size_t)NROWS * 128 * 2); // 33.5 MB fp16
    unsigned short* s1 = (unsigned short*)alloc((size_t)NROWS * 64 * 2);   // 16.8 MB fp16
    unsigned short* W1T = (unsigned short*)alloc(8192 * 2);
    unsigned short* W2T = (unsigned short*)alloc(65536 * 2);
    float* statszone = (float*)alloc(SZ_TOT * 4);
    float* stats1  = statszone + SZ_S1;
    float* stats2p = statszone + SZ_S2P;
    float* stats3p = statszone + SZ_S3P;
    float* stats4  = statszone + SZ_S4;
    float* c1stats = statszone + SZ_C1;
    float* gnstats = statszone + SZ_GN;
    float* statsd2 = statszone + SZ_D2;
    float* scsh1   = statszone + SZ_SCSH1;
    float* scsh2   = statszone + SZ_SCSH2;
    unsigned* mm = (unsigned*)alloc(16384 * 4);
    float* a4 = (float*)alloc(16 * 512 * 4);
    float* c1 = (float*)alloc(64 * 4);
    float* c2 = (float*)alloc(64 * 4);
    float* gn = (float*)alloc(8192 * 3 * 4);
    // s2 (131072x128 fp16 = 33.5 MB) aliases a1 (a1 dead after k_gather<64>)
    unsigned short* s2 = (unsigned short*)a1;

    k_prep<<<64, 256, 0, stream>>>(gc1w, gc2w, d1w, d1b, W1T, W2T, gn, statszone, mm);
    k_cov_e1<<<512, 256, 0, stream>>>(data, knn, e1w, e1b, a1);
    k_reduce_a1<<<256, 256, 0, stream>>>(a1, stats1);
    k_bncoef<64, 1><<<1, 256, 0, stream>>>(stats1, e1g, e1be, scsh1);
    k_gather<64><<<NROWS / 16, 256, 0, stream>>>(a1, knn, scsh1, s1);
    k_gemm<64, 128, true><<<1024, 256, 0, stream>>>(s1, W1T, gc1b, a2h, stats2p, nullptr);
    k_bncoef<128, 64><<<1, 256, 0, stream>>>(stats2p, g1g, g1be, scsh2);
    k_gather16<128><<<NROWS / 16, 256, 0, stream>>>(a2h, knn, scsh2, s2);
    k_gemm<128, 512, false><<<1024, 256, 0, stream>>>(s2, W2T, gc2b, nullptr, stats3p, mm);
    k_e2<<<16, 256, 0, stream>>>(stats3p, mm, g2g, g2be, e2w, e2b, a4, stats4);
    k_code<<<16, 256, 0, stream>>>(a4, stats4, e2g, e2be, d1w, d2w, gn, c1, c2, c1stats, gnstats);
    k_d2stats<<<512, 256, 0, stream>>>(c1, c2, gn, c1stats, gnstats, d1g, d1be, d2w, d2b, statsd2);
    k_out<<<512, 256, 0, stream>>>(c1, c2, gn, c1stats, gnstats, statsd2,
                                   d1g, d1be, d2w, d2b, d2g, d2be, (float*)d_out);
}

// Round 10
// 383.233 us; speedup vs baseline: 11.1721x; 1.0551x over previous
//
#include <hip/hip_runtime.h>
#include <hip/hip_fp16.h>
#include <stdint.h>

#define BATCH 16
#define NPTS  8192
#define KNN   16
#define NROWS (BATCH*NPTS)     // 131072
#define EPSBN 1e-5f
#define DEGINV (1.0f/17.0f)

typedef _Float16 f16x8 __attribute__((ext_vector_type(8)));
typedef float    f32x4 __attribute__((ext_vector_type(4)));

__device__ __forceinline__ unsigned short f2hu(float f) {
    union { _Float16 h; unsigned short u; } cv;
    cv.h = (_Float16)f;
    return cv.u;
}
__device__ __forceinline__ float hu2f(unsigned short u) {
    union { unsigned short u; _Float16 h; } cv;
    cv.u = u;
    return (float)cv.h;
}
// order-preserving float <-> uint encoding (for atomic min/max)
__device__ __forceinline__ unsigned fenc(float f) {
    unsigned u = __float_as_uint(f);
    return (int)u >= 0 ? (u | 0x80000000u) : ~u;
}
__device__ __forceinline__ float fdec(unsigned k) {
    return (k & 0x80000000u) ? __uint_as_float(k & 0x7FFFFFFFu) : __uint_as_float(~k);
}

// stats zone layout (floats):
#define SZ_S1    0        // stats1: 64 sum + 64 sumsq
#define SZ_S2P   128      // stats2p: 64 x (128+128)
#define SZ_S3P   16512    // stats3p: 64 x (512+512)
#define SZ_S4    82048    // stats4: 512+512
#define SZ_C1    83072
#define SZ_GN    83080
#define SZ_D2    83088
#define SZ_SCSH1 83096    // 2*64 bn coefs for layer1 input
#define SZ_SCSH2 83224    // 2*128 bn coefs for layer2 input
#define SZ_TOT   83480

// ---------------------------------------------------------------------------
// k_prep: zero stats, init min/max sentinels, build fp16 W^T copies, grid feats
// ---------------------------------------------------------------------------
__global__ __launch_bounds__(256) void k_prep(
    const float* __restrict__ gc1w, const float* __restrict__ gc2w,
    const float* __restrict__ d1w, const float* __restrict__ d1b,
    unsigned short* __restrict__ W1T, unsigned short* __restrict__ W2T,
    float* __restrict__ gn, float* __restrict__ statszone, unsigned* __restrict__ mm)
{
    int t = blockIdx.x * 256 + threadIdx.x;
    int NT_ = gridDim.x * 256;
    for (int i = t; i < 65536; i += NT_) {          // W2T[c][k] = gc2_w[k][c]
        int c = i >> 7, k = i & 127;
        W2T[i] = f2hu(gc2w[k * 512 + c]);
    }
    for (int i = t; i < 8192; i += NT_) {           // W1T[c][k] = gc1_w[k][c]
        int c = i >> 6, k = i & 63;
        W1T[i] = f2hu(gc1w[k * 128 + c]);
    }
    for (int i = t; i < SZ_TOT; i += NT_) statszone[i] = 0.f;
    for (int i = t; i < 8192; i += NT_) mm[i] = 0u;                 // max enc
    for (int i = t; i < 8192; i += NT_) mm[8192 + i] = 0xFFFFFFFFu; // min enc
    for (int n = t; n < 8192; n += NT_) {
        int ix = n / 65, iy = n % 65;
        float gx = 1.f + ix * (119.f / 128.f);
        float gy = 1.f + iy * (59.f / 64.f);
        #pragma unroll
        for (int j = 0; j < 3; j++)
            gn[n * 3 + j] = gx * d1w[512 * 3 + j] + gy * d1w[513 * 3 + j] + d1b[j];
    }
}

// ---------------------------------------------------------------------------
// k_cov_e1: covariance features + Linear(12,64) -> a1 [131072][64] fp32
// ---------------------------------------------------------------------------
__global__ __launch_bounds__(256) void k_cov_e1(
    const float* __restrict__ data, const int* __restrict__ knn,
    const float* __restrict__ e1w, const float* __restrict__ e1b,
    float* __restrict__ a1)
{
    __shared__ float w[12 * 64];
    __shared__ float bias[64];
    int tid = threadIdx.x;
    for (int i = tid; i < 768; i += 256) w[i] = e1w[i];
    if (tid < 64) bias[tid] = e1b[tid];
    __syncthreads();

    int gid = blockIdx.x * 256 + tid;
    int b = gid >> 13;
    const float* db = data + (size_t)b * NPTS * 3;
    const int4* k4 = (const int4*)knn + gid * 4;

    float sx = 0, sy = 0, sz = 0, Sxx = 0, Sxy = 0, Sxz = 0, Syy = 0, Syz = 0, Szz = 0;
    #pragma unroll
    for (int jj = 0; jj < 4; jj++) {
        int4 q = k4[jj];
        int id[4] = {q.x, q.y, q.z, q.w};
        #pragma unroll
        for (int u = 0; u < 4; u++) {
            const float* p = db + (size_t)id[u] * 3;
            float x = p[0], y = p[1], z = p[2];
            sx += x; sy += y; sz += z;
            Sxx += x * x; Sxy += x * y; Sxz += x * z;
            Syy += y * y; Syz += y * z; Szz += z * z;
        }
    }
    float mx = sx * (1.f / 16.f), my = sy * (1.f / 16.f), mz = sz * (1.f / 16.f);
    const float inv15 = 1.f / 15.f;
    float x12[12];
    x12[0] = data[(size_t)gid * 3 + 0];
    x12[1] = data[(size_t)gid * 3 + 1];
    x12[2] = data[(size_t)gid * 3 + 2];
    x12[3] = (Sxx - 16.f * mx * mx) * inv15;
    x12[4] = (Sxy - 16.f * mx * my) * inv15;
    x12[5] = (Sxz - 16.f * mx * mz) * inv15;
    x12[6] = x12[4];
    x12[7] = (Syy - 16.f * my * my) * inv15;
    x12[8] = (Syz - 16.f * my * mz) * inv15;
    x12[9] = x12[5];
    x12[10] = x12[8];
    x12[11] = (Szz - 16.f * mz * mz) * inv15;

    float* arow = a1 + (size_t)gid * 64;
    for (int c0 = 0; c0 < 64; c0 += 4) {
        float4 v;
        float* vv = (float*)&v;
        #pragma unroll
        for (int u = 0; u < 4; u++) {
            int c = c0 + u;
            float acc = bias[c];
            #pragma unroll
            for (int i = 0; i < 12; i++) acc += x12[i] * w[i * 64 + c];
            vv[u] = acc;
        }
        *(float4*)(arow + c0) = v;
    }
}

// ---------------------------------------------------------------------------
// k_reduce_a1: per-channel sum/sumsq of a1 (C=64) -> stats1
// ---------------------------------------------------------------------------
__global__ __launch_bounds__(256) void k_reduce_a1(
    const float* __restrict__ a1, float* __restrict__ stats1)
{
    int tid = threadIdx.x;
    int c = tid & 63, rq = tid >> 6;
    float s = 0.f, q = 0.f;
    for (int row = blockIdx.x * 4 + rq; row < NROWS; row += gridDim.x * 4) {
        float v = a1[(size_t)row * 64 + c];
        s += v; q += v * v;
    }
    __shared__ float red[2][256];
    red[0][tid] = s; red[1][tid] = q;
    __syncthreads();
    if (tid < 64) {
        s = red[0][tid] + red[0][tid + 64] + red[0][tid + 128] + red[0][tid + 192];
        q = red[1][tid] + red[1][tid + 64] + red[1][tid + 128] + red[1][tid + 192];
        atomicAdd(stats1 + tid, s);
        atomicAdd(stats1 + 64 + tid, q);
    }
}

// ---------------------------------------------------------------------------
// k_bncoef<C,NPARTS>: collapse partitioned stats -> (sc, sh) coef arrays
// ---------------------------------------------------------------------------
template <int C, int NPARTS>
__global__ __launch_bounds__(256) void k_bncoef(
    const float* __restrict__ statsIn,
    const float* __restrict__ gamma, const float* __restrict__ beta,
    float* __restrict__ scsh)
{
    int ch = threadIdx.x;
    if (ch < C) {
        float s = 0.f, q = 0.f;
        for (int p = 0; p < NPARTS; p++) {
            s += statsIn[p * 2 * C + ch];
            q += statsIn[p * 2 * C + C + ch];
        }
        float m = s * (1.f / NROWS);
        float var = fmaxf(q * (1.f / NROWS) - m * m, 0.f);
        float sc = gamma[ch] * rsqrtf(var + EPSBN);
        scsh[ch] = sc;
        scsh[C + ch] = beta[ch] - m * sc;
    }
}

// ---------------------------------------------------------------------------
// k_gather (fp32 in): s[row] = bn_relu(a[row]) + sum_j bn_relu(a[knn_j]) -> fp16
// One thread per (row, 4-ch chunk): 17 independent float4 loads in flight.
// ---------------------------------------------------------------------------
template <int CIN>
__global__ __launch_bounds__(256) void k_gather(
    const float* __restrict__ ain, const int* __restrict__ knn,
    const float* __restrict__ scsh, unsigned short* __restrict__ S)
{
    constexpr int GPR = CIN / 4;
    constexpr int R = 256 / GPR;
    constexpr int BPB = NPTS / R;

    __shared__ int nidx[R * KNN];

    int tid = threadIdx.x;
    int blk = blockIdx.x;
    int xcd = blk & 7;
    int idx = blk >> 3;
    int batch = xcd + 8 * (idx / BPB);
    int within = idx % BPB;
    int node0 = batch * NPTS + within * R;

    if (tid < R * KNN / 4) {
        const int4* ksrc = (const int4*)(knn + (size_t)node0 * KNN);
        ((int4*)nidx)[tid] = ksrc[tid];
    }
    __syncthreads();

    int t = tid & (GPR - 1);
    int r = tid / GPR;
    int col4 = t * 4;
    float4 scv = *(const float4*)(scsh + col4);
    float4 shv = *(const float4*)(scsh + CIN + col4);

    int row = node0 + r;
    const float* abase = ain + (size_t)batch * NPTS * CIN;

    float4 v = *(const float4*)(ain + (size_t)row * CIN + col4);
    float a0 = fmaxf(v.x * scv.x + shv.x, 0.f);
    float a1v = fmaxf(v.y * scv.y + shv.y, 0.f);
    float a2v = fmaxf(v.z * scv.z + shv.z, 0.f);
    float a3v = fmaxf(v.w * scv.w + shv.w, 0.f);
    #pragma unroll
    for (int jn = 0; jn < KNN; jn++) {
        int src = nidx[r * KNN + jn];
        float4 wv = *(const float4*)(abase + (size_t)src * CIN + col4);
        a0  += fmaxf(wv.x * scv.x + shv.x, 0.f);
        a1v += fmaxf(wv.y * scv.y + shv.y, 0.f);
        a2v += fmaxf(wv.z * scv.z + shv.z, 0.f);
        a3v += fmaxf(wv.w * scv.w + shv.w, 0.f);
    }
    uint2 o;
    o.x = f2hu(a0)  | ((unsigned)f2hu(a1v) << 16);
    o.y = f2hu(a2v) | ((unsigned)f2hu(a3v) << 16);
    *(uint2*)(S + (size_t)row * CIN + col4) = o;
}

// ---------------------------------------------------------------------------
// k_gather16 (fp16 in): same but input is fp16, 8 ch/thread, 16-B loads.
// ---------------------------------------------------------------------------
template <int CIN>
__global__ __launch_bounds__(256) void k_gather16(
    const unsigned short* __restrict__ ain, const int* __restrict__ knn,
    const float* __restrict__ scsh, unsigned short* __restrict__ S)
{
    constexpr int GPR = CIN / 8;            // 16 threads per row
    constexpr int R = 256 / GPR;            // 16 rows per block
    constexpr int BPB = NPTS / R;

    __shared__ int nidx[R * KNN];

    int tid = threadIdx.x;
    int blk = blockIdx.x;
    int xcd = blk & 7;
    int idx = blk >> 3;
    int batch = xcd + 8 * (idx / BPB);
    int within = idx % BPB;
    int node0 = batch * NPTS + within * R;

    if (tid < R * KNN / 4) {
        const int4* ksrc = (const int4*)(knn + (size_t)node0 * KNN);
        ((int4*)nidx)[tid] = ksrc[tid];
    }
    __syncthreads();

    int t = tid & (GPR - 1);
    int r = tid / GPR;
    int col8 = t * 8;
    float sc8[8], sh8[8];
    #pragma unroll
    for (int j = 0; j < 8; j++) { sc8[j] = scsh[col8 + j]; sh8[j] = scsh[CIN + col8 + j]; }

    int row = node0 + r;
    const unsigned short* abase = ain + (size_t)batch * NPTS * CIN;

    float acc8[8];
    {
        uint4 v = *(const uint4*)(ain + (size_t)row * CIN + col8);
        unsigned wds[4] = {v.x, v.y, v.z, v.w};
        #pragma unroll
        for (int j = 0; j < 4; j++) {
            acc8[2*j]   = fmaxf(hu2f((unsigned short)(wds[j] & 0xFFFF)) * sc8[2*j]   + sh8[2*j],   0.f);
            acc8[2*j+1] = fmaxf(hu2f((unsigned short)(wds[j] >> 16))    * sc8[2*j+1] + sh8[2*j+1], 0.f);
        }
    }
    #pragma unroll
    for (int jn = 0; jn < KNN; jn++) {
        int src = nidx[r * KNN + jn];
        uint4 v = *(const uint4*)(abase + (size_t)src * CIN + col8);
        unsigned wds[4] = {v.x, v.y, v.z, v.w};
        #pragma unroll
        for (int j = 0; j < 4; j++) {
            acc8[2*j]   += fmaxf(hu2f((unsigned short)(wds[j] & 0xFFFF)) * sc8[2*j]   + sh8[2*j],   0.f);
            acc8[2*j+1] += fmaxf(hu2f((unsigned short)(wds[j] >> 16))    * sc8[2*j+1] + sh8[2*j+1], 0.f);
        }
    }
    uint4 o;
    o.x = f2hu(acc8[0]) | ((unsigned)f2hu(acc8[1]) << 16);
    o.y = f2hu(acc8[2]) | ((unsigned)f2hu(acc8[3]) << 16);
    o.z = f2hu(acc8[4]) | ((unsigned)f2hu(acc8[5]) << 16);
    o.w = f2hu(acc8[6]) | ((unsigned)f2hu(acc8[7]) << 16);
    *(uint4*)(S + (size_t)row * CIN + col8) = o;
}

// ---------------------------------------------------------------------------
// k_gemm<CIN,COUT,STORE>: LDS-staged-A GEMM, W in registers.
// MT=64 rows/block, 2048 blocks. Block stages its 64xCIN A-slice to LDS with
// coalesced uint4 loads; waves read A via ds_read_b128 (latency-safe), W frags
// live in VGPRs per half. Stats accumulated on raw acc (affine applied once).
// STORE=true writes aout fp16.
// ---------------------------------------------------------------------------
template <int CIN, int COUT, bool STORE>
__global__ __launch_bounds__(256) void k_gemm(
    const unsigned short* __restrict__ S, const unsigned short* __restrict__ WT,
    const float* __restrict__ bias,
    unsigned short* __restrict__ aout, float* __restrict__ statsOut, unsigned* __restrict__ mm)
{
    constexpr int KC = CIN / 32;
    constexpr int NT = COUT / 64;           // n-tiles per wave (wave owns COUT/4)
    constexpr int NHALF = (NT >= 2) ? 2 : 1;
    constexpr int NTH = NT / NHALF;
    constexpr int MT = 64;
    constexpr int SST = CIN + 8;            // LDS row stride (shorts): 2-way-free banks
    constexpr int BPB = NPTS / MT;          // 128 blocks per batch

    __shared__ alignas(16) unsigned short sA[MT * SST];

    int tid = threadIdx.x;
    int blk = blockIdx.x;                   // 2048 blocks
    int xcd = blk & 7;
    int idx = blk >> 3;
    int batch = xcd + 8 * (idx / BPB);
    int within = idx % BPB;
    int node0 = batch * NPTS + within * MT;
    int pout = batch * 4 + (within >> 5);   // 64-way stats partition

    // ---- stage A: coalesced global read -> LDS (padded rows)
    {
        constexpr int TOT = MT * CIN / 8;   // uint4 count
        const uint4* src = (const uint4*)(S + (size_t)node0 * CIN);
        #pragma unroll
        for (int i = tid; i < TOT; i += 256) {
            int row = i / (CIN / 8);
            int col8 = (i % (CIN / 8)) * 8;
            *(uint4*)&sA[row * SST + col8] = src[i];
        }
    }
    __syncthreads();

    int lane = tid & 63, wv = tid >> 6;
    int n15 = lane & 15, qd = lane >> 4;
    int c0 = wv * (COUT / 4);

    #pragma unroll
    for (int half = 0; half < NHALF; half++) {
        f16x8 wf[KC][NTH];
        float bz[NTH];
        #pragma unroll
        for (int nth = 0; nth < NTH; nth++) {
            int c = c0 + (half * NTH + nth) * 16 + n15;
            bz[nth] = bias[c];
            #pragma unroll
            for (int kc = 0; kc < KC; kc++)
                wf[kc][nth] = *(const f16x8*)(WT + (size_t)c * CIN + kc * 32 + qd * 8);
        }
        float sacc[NTH], qacc[NTH], mxa[NTH], mna[NTH];
        #pragma unroll
        for (int nth = 0; nth < NTH; nth++) {
            sacc[nth] = 0.f; qacc[nth] = 0.f; mxa[nth] = -3.4e38f; mna[nth] = 3.4e38f;
        }

        #pragma unroll
        for (int mt = 0; mt < MT / 16; mt++) {
            f16x8 af[KC];
            #pragma unroll
            for (int kc = 0; kc < KC; kc++)
                af[kc] = *(const f16x8*)&sA[(mt * 16 + n15) * SST + kc * 32 + qd * 8];

            f32x4 acc[NTH];
            #pragma unroll
            for (int nth = 0; nth < NTH; nth++) acc[nth] = (f32x4)(0.f);
            #pragma unroll
            for (int kc = 0; kc < KC; kc++)
                #pragma unroll
                for (int nth = 0; nth < NTH; nth++)
                    acc[nth] = __builtin_amdgcn_mfma_f32_16x16x32_f16(af[kc], wf[kc][nth], acc[nth], 0, 0, 0);

            #pragma unroll
            for (int nth = 0; nth < NTH; nth++) {
                int c = c0 + (half * NTH + nth) * 16 + n15;
                #pragma unroll
                for (int r = 0; r < 4; r++) {
                    float a = acc[nth][r];
                    sacc[nth] += a;
                    qacc[nth] = fmaf(a, a, qacc[nth]);
                    if (!STORE) {
                        mxa[nth] = fmaxf(mxa[nth], a);
                        mna[nth] = fminf(mna[nth], a);
                    }
                    if (STORE) {
                        float v = a * DEGINV + bz[nth];
                        int node = node0 + mt * 16 + qd * 4 + r;
                        aout[(size_t)node * COUT + c] = f2hu(v);
                    }
                }
            }
        }

        // reduce over the wave's 4 row-quadrants; affine transform; atomics
        #pragma unroll
        for (int nth = 0; nth < NTH; nth++) {
            int c = c0 + (half * NTH + nth) * 16 + n15;
            float S_ = sacc[nth], Q_ = qacc[nth];
            S_ += __shfl_xor(S_, 16); S_ += __shfl_xor(S_, 32);
            Q_ += __shfl_xor(Q_, 16); Q_ += __shfl_xor(Q_, 32);
            if (!STORE) {
                float mx = mxa[nth], mn = mna[nth];
                mx = fmaxf(mx, __shfl_xor(mx, 16)); mx = fmaxf(mx, __shfl_xor(mx, 32));
                mn = fminf(mn, __shfl_xor(mn, 16)); mn = fminf(mn, __shfl_xor(mn, 32));
                if (lane < 16) {
                    atomicMax(mm + batch * COUT + c, fenc(mx * DEGINV + bz[nth]));
                    atomicMin(mm + BATCH * COUT + batch * COUT + c, fenc(mn * DEGINV + bz[nth]));
                }
            }
            if (lane < 16) {
                float b = bz[nth];
                float s = DEGINV * S_ + (float)MT * b;
                float q = DEGINV * DEGINV * Q_ + 2.f * DEGINV * b * S_ + (float)MT * b * b;
                atomicAdd(statsOut + (size_t)pout * 2 * COUT + c, s);
                atomicAdd(statsOut + (size_t)pout * 2 * COUT + COUT + c, q);
            }
        }
    }
}

// ---------------------------------------------------------------------------
// k_e2: pooled codeword from min/max + BN3, then Linear(512,512) -> a4, stats4
// ---------------------------------------------------------------------------
__global__ __launch_bounds__(256) void k_e2(
    const float* __restrict__ stats3p, const unsigned* __restrict__ mm,
    const float* __restrict__ g2g, const float* __restrict__ g2be,
    const float* __restrict__ e2w, const float* __restrict__ e2b,
    float* __restrict__ a4, float* __restrict__ stats4)
{
    __shared__ float pooled[512];
    int b = blockIdx.x, tid = threadIdx.x;
    for (int c = tid; c < 512; c += 256) {
        float s = 0.f, qq = 0.f;
        for (int p = 0; p < 64; p++) {
            s += stats3p[p * 1024 + c];
            qq += stats3p[p * 1024 + 512 + c];
        }
        float m = s * (1.f / NROWS);
        float var = fmaxf(qq * (1.f / NROWS) - m * m, 0.f);
        float sc = g2g[c] * rsqrtf(var + EPSBN);
        float sh = g2be[c] - m * sc;
        float amax = fdec(mm[b * 512 + c]);
        float amin = fdec(mm[8192 + b * 512 + c]);
        pooled[c] = fmaxf(fmaxf(sc * amax + sh, 0.f), fmaxf(sc * amin + sh, 0.f));
    }
    __syncthreads();
    int ca = tid, cb = tid + 256;
    float acc1 = e2b[ca], acc2 = e2b[cb];
    for (int f = 0; f < 512; f++) {
        float pv = pooled[f];
        acc1 += pv * e2w[f * 512 + ca];
        acc2 += pv * e2w[f * 512 + cb];
    }
    a4[b * 512 + ca] = acc1; a4[b * 512 + cb] = acc2;
    atomicAdd(stats4 + ca, acc1); atomicAdd(stats4 + 512 + ca, acc1 * acc1);
    atomicAdd(stats4 + cb, acc2); atomicAdd(stats4 + 512 + cb, acc2 * acc2);
}

// ---------------------------------------------------------------------------
// k_code: BN4+relu -> code; c1 = code@d1_w[:512], c2 = code@d2_w[:512]
// ---------------------------------------------------------------------------
__global__ __launch_bounds__(256) void k_code(
    const float* __restrict__ a4, const float* __restrict__ stats4,
    const float* __restrict__ e2g, const float* __restrict__ e2be,
    const float* __restrict__ d1w, const float* __restrict__ d2w,
    const float* __restrict__ gn,
    float* __restrict__ c1, float* __restrict__ c2,
    float* __restrict__ c1stats, float* __restrict__ gnstats)
{
    int b = blockIdx.x, tid = threadIdx.x;
    int lane = tid & 63, wv = tid >> 6;
    float p1[3] = {0, 0, 0}, p2[3] = {0, 0, 0};
    for (int c = tid; c < 512; c += 256) {
        float s = stats4[c], qq = stats4[512 + c];
        float m = s * (1.f / 16.f);
        float var = fmaxf(qq * (1.f / 16.f) - m * m, 0.f);
        float sc = e2g[c] * rsqrtf(var + EPSBN);
        float sh = e2be[c] - m * sc;
        float cv = fmaxf(sc * a4[b * 512 + c] + sh, 0.f);
        #pragma unroll
        for (int j = 0; j < 3; j++) {
            p1[j] += cv * d1w[c * 3 + j];
            p2[j] += cv * d2w[c * 3 + j];
        }
    }
    __shared__ float red[4][6];
    #pragma unroll
    for (int j = 0; j < 3; j++)
        for (int off = 32; off; off >>= 1) {
            p1[j] += __shfl_xor(p1[j], off);
            p2[j] += __shfl_xor(p2[j], off);
        }
    if (lane == 0) {
        #pragma unroll
        for (int j = 0; j < 3; j++) { red[wv][j] = p1[j]; red[wv][3 + j] = p2[j]; }
    }
    __syncthreads();
    if (tid < 3) {
        float v = red[0][tid] + red[1][tid] + red[2][tid] + red[3][tid];
        c1[b * 3 + tid] = v;
        atomicAdd(c1stats + tid, v);
        atomicAdd(c1stats + 3 + tid, v * v);
    } else if (tid < 6) {
        int j = tid - 3;
        float v = red[0][tid] + red[1][tid] + red[2][tid] + red[3][tid];
        c2[b * 3 + j] = v;
    }
    if (blockIdx.x == 0) {
        float g1[3] = {0, 0, 0}, g2s[3] = {0, 0, 0};
        for (int n = tid; n < NPTS; n += 256) {
            #pragma unroll
            for (int j = 0; j < 3; j++) {
                float g = gn[n * 3 + j];
                g1[j] += g; g2s[j] += g * g;
            }
        }
        #pragma unroll
        for (int j = 0; j < 3; j++)
            for (int off = 32; off; off >>= 1) {
                g1[j] += __shfl_xor(g1[j], off);
                g2s[j] += __shfl_xor(g2s[j], off);
            }
        __shared__ float redg[4][6];
        if (lane == 0) {
            #pragma unroll
            for (int j = 0; j < 3; j++) { redg[wv][j] = g1[j]; redg[wv][3 + j] = g2s[j]; }
        }
        __syncthreads();
        if (tid < 6)
            gnstats[tid] = redg[0][tid] + redg[1][tid] + redg[2][tid] + redg[3][tid];
    }
}

// ---------------------------------------------------------------------------
__device__ __forceinline__ void d1_coefs(
    const float* c1stats, const float* gnstats,
    const float* d1g, const float* d1be, float* scd, float* shd)
{
    #pragma unroll
    for (int j = 0; j < 3; j++) {
        float mc = c1stats[j] * (1.f / 16.f), qc = c1stats[3 + j] * (1.f / 16.f);
        float mg = gnstats[j] * (1.f / 8192.f), qg = gnstats[3 + j] * (1.f / 8192.f);
        float m = mc + mg;
        float var = fmaxf((qc - mc * mc) + (qg - mg * mg), 0.f);
        float sc = d1g[j] * rsqrtf(var + EPSBN);
        scd[j] = sc;
        shd[j] = d1be[j] - m * sc;
    }
}

// ---------------------------------------------------------------------------
__global__ __launch_bounds__(256) void k_d2stats(
    const float* __restrict__ c1, const float* __restrict__ c2, const float* __restrict__ gn,
    const float* __restrict__ c1stats, const float* __restrict__ gnstats,
    const float* __restrict__ d1g, const float* __restrict__ d1be,
    const float* __restrict__ d2w, const float* __restrict__ d2b,
    float* __restrict__ statsd2)
{
    int gid = blockIdx.x * 256 + threadIdx.x;
    int b = gid >> 13, n = gid & 8191;
    int lane = threadIdx.x & 63, wv = threadIdx.x >> 6;
    float scd[3], shd[3];
    d1_coefs(c1stats, gnstats, d1g, d1be, scd, shd);
    float z3[3];
    #pragma unroll
    for (int j = 0; j < 3; j++)
        z3[j] = fmaxf(scd[j] * (c1[b * 3 + j] + gn[n * 3 + j]) + shd[j], 0.f);
    float vals[6];
    #pragma unroll
    for (int u = 0; u < 3; u++) {
        float a = c2[b * 3 + u]
                + z3[0] * d2w[512 * 3 + u]
                + z3[1] * d2w[513 * 3 + u]
                + z3[2] * d2w[514 * 3 + u]
                + d2b[u];
        vals[u] = a; vals[3 + u] = a * a;
    }
    #pragma unroll
    for (int j = 0; j < 6; j++)
        for (int off = 32; off; off >>= 1) vals[j] += __shfl_xor(vals[j], off);
    __shared__ float red[4][6];
    if (lane == 0) {
        #pragma unroll
        for (int j = 0; j < 6; j++) red[wv][j] = vals[j];
    }
    __syncthreads();
    if (threadIdx.x < 6)
        atomicAdd(statsd2 + threadIdx.x,
                  red[0][threadIdx.x] + red[1][threadIdx.x] + red[2][threadIdx.x] + red[3][threadIdx.x]);
}

// ---------------------------------------------------------------------------
__global__ __launch_bounds__(256) void k_out(
    const float* __restrict__ c1, const float* __restrict__ c2, const float* __restrict__ gn,
    const float* __restrict__ c1stats, const float* __restrict__ gnstats,
    const float* __restrict__ statsd2,
    const float* __restrict__ d1g, const float* __restrict__ d1be,
    const float* __restrict__ d2w, const float* __restrict__ d2b,
    const float* __restrict__ d2g, const float* __restrict__ d2be,
    float* __restrict__ out)
{
    int gid = blockIdx.x * 256 + threadIdx.x;
    int b = gid >> 13, n = gid & 8191;
    float scd[3], shd[3];
    d1_coefs(c1stats, gnstats, d1g, d1be, scd, shd);
    float z3[3];
    #pragma unroll
    for (int j = 0; j < 3; j++)
        z3[j] = fmaxf(scd[j] * (c1[b * 3 + j] + gn[n * 3 + j]) + shd[j], 0.f);
    #pragma unroll
    for (int u = 0; u < 3; u++) {
        float a = c2[b * 3 + u]
                + z3[0] * d2w[512 * 3 + u]
                + z3[1] * d2w[513 * 3 + u]
                + z3[2] * d2w[514 * 3 + u]
                + d2b[u];
        float m2 = statsd2[u] * (1.f / (float)NROWS);
        float v2 = fmaxf(statsd2[3 + u] * (1.f / (float)NROWS) - m2 * m2, 0.f);
        float sc = d2g[u] * rsqrtf(v2 + EPSBN);
        float sh = d2be[u] - m2 * sc;
        out[(size_t)gid * 3 + u] = fmaxf(sc * a + sh, 0.f);
    }
}

// ---------------------------------------------------------------------------
extern "C" void kernel_launch(void* const* d_in, const int* in_sizes, int n_in,
                              void* d_out, int out_size, void* d_ws, size_t ws_size,
                              hipStream_t stream)
{
    (void)in_sizes; (void)n_in; (void)out_size; (void)ws_size;
    const float* data = (const float*)d_in[0];
    const int*   knn  = (const int*)d_in[1];
    const float* e1w = (const float*)d_in[2],  *e1b = (const float*)d_in[3];
    const float* e1g = (const float*)d_in[4],  *e1be = (const float*)d_in[5];
    const float* gc1w = (const float*)d_in[6], *gc1b = (const float*)d_in[7];
    const float* g1g = (const float*)d_in[8],  *g1be = (const float*)d_in[9];
    const float* gc2w = (const float*)d_in[10], *gc2b = (const float*)d_in[11];
    const float* g2g = (const float*)d_in[12], *g2be = (const float*)d_in[13];
    const float* e2w = (const float*)d_in[14], *e2b = (const float*)d_in[15];
    const float* e2g = (const float*)d_in[16], *e2be = (const float*)d_in[17];
    const float* d1w = (const float*)d_in[18], *d1b = (const float*)d_in[19];
    const float* d1g = (const float*)d_in[20], *d1be = (const float*)d_in[21];
    const float* d2w = (const float*)d_in[22], *d2b = (const float*)d_in[23];
    const float* d2g = (const float*)d_in[24], *d2be = (const float*)d_in[25];

    char* p = (char*)d_ws;
    auto alloc = [&](size_t bytes) -> void* {
        void* r = (void*)p;
        p += (bytes + 255) & ~(size_t)255;
        return r;
    };
    float* a1 = (float*)alloc((size_t)NROWS * 64 * 4);      // 33.5 MB fp32 (s2 aliases later)
    unsigned short* a2h = (unsigned short*)alloc((size_t)NROWS * 128 * 2); // 33.5 MB fp16
    unsigned short* s1 = (unsigned short*)alloc((size_t)NROWS * 64 * 2);   // 16.8 MB fp16
    unsigned short* W1T = (unsigned short*)alloc(8192 * 2);
    unsigned short* W2T = (unsigned short*)alloc(65536 * 2);
    float* statszone = (float*)alloc(SZ_TOT * 4);
    float* stats1  = statszone + SZ_S1;
    float* stats2p = statszone + SZ_S2P;
    float* stats3p = statszone + SZ_S3P;
    float* stats4  = statszone + SZ_S4;
    float* c1stats = statszone + SZ_C1;
    float* gnstats = statszone + SZ_GN;
    float* statsd2 = statszone + SZ_D2;
    float* scsh1   = statszone + SZ_SCSH1;
    float* scsh2   = statszone + SZ_SCSH2;
    unsigned* mm = (unsigned*)alloc(16384 * 4);
    float* a4 = (float*)alloc(16 * 512 * 4);
    float* c1 = (float*)alloc(64 * 4);
    float* c2 = (float*)alloc(64 * 4);
    float* gn = (float*)alloc(8192 * 3 * 4);
    // s2 (131072x128 fp16 = 33.5 MB) aliases a1 (a1 dead after k_gather<64>)
    unsigned short* s2 = (unsigned short*)a1;

    k_prep<<<64, 256, 0, stream>>>(gc1w, gc2w, d1w, d1b, W1T, W2T, gn, statszone, mm);
    k_cov_e1<<<512, 256, 0, stream>>>(data, knn, e1w, e1b, a1);
    k_reduce_a1<<<256, 256, 0, stream>>>(a1, stats1);
    k_bncoef<64, 1><<<1, 256, 0, stream>>>(stats1, e1g, e1be, scsh1);
    k_gather<64><<<NROWS / 16, 256, 0, stream>>>(a1, knn, scsh1, s1);
    k_gemm<64, 128, true><<<2048, 256, 0, stream>>>(s1, W1T, gc1b, a2h, stats2p, nullptr);
    k_bncoef<128, 64><<<1, 256, 0, stream>>>(stats2p, g1g, g1be, scsh2);
    k_gather16<128><<<NROWS / 16, 256, 0, stream>>>(a2h, knn, scsh2, s2);
    k_gemm<128, 512, false><<<2048, 256, 0, stream>>>(s2, W2T, gc2b, nullptr, stats3p, mm);
    k_e2<<<16, 256, 0, stream>>>(stats3p, mm, g2g, g2be, e2w, e2b, a4, stats4);
    k_code<<<16, 256, 0, stream>>>(a4, stats4, e2g, e2be, d1w, d2w, gn, c1, c2, c1stats, gnstats);
    k_d2stats<<<512, 256, 0, stream>>>(c1, c2, gn, c1stats, gnstats, d1g, d1be, d2w, d2b, statsd2);
    k_out<<<512, 256, 0, stream>>>(c1, c2, gn, c1stats, gnstats, statsd2,
                                   d1g, d1be, d2w, d2b, d2g, d2be, (float*)d_out);
}

// Round 11
// 334.919 us; speedup vs baseline: 12.7838x; 1.1443x over previous
//
#include <hip/hip_runtime.h>
#include <hip/hip_fp16.h>
#include <stdint.h>

#define BATCH 16
#define NPTS  8192
#define KNN   16
#define NROWS (BATCH*NPTS)     // 131072
#define EPSBN 1e-5f
#define DEGINV (1.0f/17.0f)

typedef _Float16 f16x8 __attribute__((ext_vector_type(8)));
typedef float    f32x4 __attribute__((ext_vector_type(4)));

__device__ __forceinline__ unsigned short f2hu(float f) {
    union { _Float16 h; unsigned short u; } cv;
    cv.h = (_Float16)f;
    return cv.u;
}
__device__ __forceinline__ float hu2f(unsigned short u) {
    union { unsigned short u; _Float16 h; } cv;
    cv.u = u;
    return (float)cv.h;
}
// order-preserving float <-> uint encoding (for atomic min/max)
__device__ __forceinline__ unsigned fenc(float f) {
    unsigned u = __float_as_uint(f);
    return (int)u >= 0 ? (u | 0x80000000u) : ~u;
}
__device__ __forceinline__ float fdec(unsigned k) {
    return (k & 0x80000000u) ? __uint_as_float(k & 0x7FFFFFFFu) : __uint_as_float(~k);
}

// stats zone layout (floats):
#define SZ_S1    0        // stats1: 64 sum + 64 sumsq
#define SZ_S2P   128      // stats2p: 64 x (128+128)
#define SZ_S3P   16512    // stats3p: 64 x (512+512)
#define SZ_S4    82048    // stats4: 512+512
#define SZ_C1    83072
#define SZ_GN    83080
#define SZ_D2    83088
#define SZ_SCSH1 83096    // 2*64 bn coefs for layer1 input
#define SZ_SCSH2 83224    // 2*128 bn coefs for layer2 input
#define SZ_TOT   83480

// ---------------------------------------------------------------------------
// k_prep: zero stats, init min/max sentinels, build fp16 W^T copies, grid feats
// ---------------------------------------------------------------------------
__global__ __launch_bounds__(256) void k_prep(
    const float* __restrict__ gc1w, const float* __restrict__ gc2w,
    const float* __restrict__ d1w, const float* __restrict__ d1b,
    unsigned short* __restrict__ W1T, unsigned short* __restrict__ W2T,
    float* __restrict__ gn, float* __restrict__ statszone, unsigned* __restrict__ mm)
{
    int t = blockIdx.x * 256 + threadIdx.x;
    int NT_ = gridDim.x * 256;
    for (int i = t; i < 65536; i += NT_) {          // W2T[c][k] = gc2_w[k][c]
        int c = i >> 7, k = i & 127;
        W2T[i] = f2hu(gc2w[k * 512 + c]);
    }
    for (int i = t; i < 8192; i += NT_) {           // W1T[c][k] = gc1_w[k][c]
        int c = i >> 6, k = i & 63;
        W1T[i] = f2hu(gc1w[k * 128 + c]);
    }
    for (int i = t; i < SZ_TOT; i += NT_) statszone[i] = 0.f;
    for (int i = t; i < 8192; i += NT_) mm[i] = 0u;                 // max enc
    for (int i = t; i < 8192; i += NT_) mm[8192 + i] = 0xFFFFFFFFu; // min enc
    for (int n = t; n < 8192; n += NT_) {
        int ix = n / 65, iy = n % 65;
        float gx = 1.f + ix * (119.f / 128.f);
        float gy = 1.f + iy * (59.f / 64.f);
        #pragma unroll
        for (int j = 0; j < 3; j++)
            gn[n * 3 + j] = gx * d1w[512 * 3 + j] + gy * d1w[513 * 3 + j] + d1b[j];
    }
}

// ---------------------------------------------------------------------------
// k_cov_e1: covariance features + Linear(12,64) -> a1 [131072][64] fp16
// ---------------------------------------------------------------------------
__global__ __launch_bounds__(256) void k_cov_e1(
    const float* __restrict__ data, const int* __restrict__ knn,
    const float* __restrict__ e1w, const float* __restrict__ e1b,
    unsigned short* __restrict__ a1)
{
    __shared__ float w[12 * 64];
    __shared__ float bias[64];
    int tid = threadIdx.x;
    for (int i = tid; i < 768; i += 256) w[i] = e1w[i];
    if (tid < 64) bias[tid] = e1b[tid];
    __syncthreads();

    int gid = blockIdx.x * 256 + tid;
    int b = gid >> 13;
    const float* db = data + (size_t)b * NPTS * 3;
    const int4* k4 = (const int4*)knn + gid * 4;

    float sx = 0, sy = 0, sz = 0, Sxx = 0, Sxy = 0, Sxz = 0, Syy = 0, Syz = 0, Szz = 0;
    #pragma unroll
    for (int jj = 0; jj < 4; jj++) {
        int4 q = k4[jj];
        int id[4] = {q.x, q.y, q.z, q.w};
        #pragma unroll
        for (int u = 0; u < 4; u++) {
            const float* p = db + (size_t)id[u] * 3;
            float x = p[0], y = p[1], z = p[2];
            sx += x; sy += y; sz += z;
            Sxx += x * x; Sxy += x * y; Sxz += x * z;
            Syy += y * y; Syz += y * z; Szz += z * z;
        }
    }
    float mx = sx * (1.f / 16.f), my = sy * (1.f / 16.f), mz = sz * (1.f / 16.f);
    const float inv15 = 1.f / 15.f;
    float x12[12];
    x12[0] = data[(size_t)gid * 3 + 0];
    x12[1] = data[(size_t)gid * 3 + 1];
    x12[2] = data[(size_t)gid * 3 + 2];
    x12[3] = (Sxx - 16.f * mx * mx) * inv15;
    x12[4] = (Sxy - 16.f * mx * my) * inv15;
    x12[5] = (Sxz - 16.f * mx * mz) * inv15;
    x12[6] = x12[4];
    x12[7] = (Syy - 16.f * my * my) * inv15;
    x12[8] = (Syz - 16.f * my * mz) * inv15;
    x12[9] = x12[5];
    x12[10] = x12[8];
    x12[11] = (Szz - 16.f * mz * mz) * inv15;

    unsigned short* arow = a1 + (size_t)gid * 64;
    for (int c0 = 0; c0 < 64; c0 += 8) {
        float v8[8];
        #pragma unroll
        for (int u = 0; u < 8; u++) {
            int c = c0 + u;
            float acc = bias[c];
            #pragma unroll
            for (int i = 0; i < 12; i++) acc += x12[i] * w[i * 64 + c];
            v8[u] = acc;
        }
        uint4 o;
        o.x = f2hu(v8[0]) | ((unsigned)f2hu(v8[1]) << 16);
        o.y = f2hu(v8[2]) | ((unsigned)f2hu(v8[3]) << 16);
        o.z = f2hu(v8[4]) | ((unsigned)f2hu(v8[5]) << 16);
        o.w = f2hu(v8[6]) | ((unsigned)f2hu(v8[7]) << 16);
        *(uint4*)(arow + c0) = o;
    }
}

// ---------------------------------------------------------------------------
// k_reduce_a1: per-channel sum/sumsq of fp16 a1 (C=64) -> stats1
// ---------------------------------------------------------------------------
__global__ __launch_bounds__(256) void k_reduce_a1(
    const unsigned short* __restrict__ a1, float* __restrict__ stats1)
{
    int tid = threadIdx.x;
    int c = tid & 63, rq = tid >> 6;
    float s = 0.f, q = 0.f;
    for (int row = blockIdx.x * 4 + rq; row < NROWS; row += gridDim.x * 4) {
        float v = hu2f(a1[(size_t)row * 64 + c]);
        s += v; q += v * v;
    }
    __shared__ float red[2][256];
    red[0][tid] = s; red[1][tid] = q;
    __syncthreads();
    if (tid < 64) {
        s = red[0][tid] + red[0][tid + 64] + red[0][tid + 128] + red[0][tid + 192];
        q = red[1][tid] + red[1][tid + 64] + red[1][tid + 128] + red[1][tid + 192];
        atomicAdd(stats1 + tid, s);
        atomicAdd(stats1 + 64 + tid, q);
    }
}

// ---------------------------------------------------------------------------
// k_bncoef<C,NPARTS>: collapse partitioned stats -> (sc, sh) coef arrays
// ---------------------------------------------------------------------------
template <int C, int NPARTS>
__global__ __launch_bounds__(256) void k_bncoef(
    const float* __restrict__ statsIn,
    const float* __restrict__ gamma, const float* __restrict__ beta,
    float* __restrict__ scsh)
{
    int ch = threadIdx.x;
    if (ch < C) {
        float s = 0.f, q = 0.f;
        for (int p = 0; p < NPARTS; p++) {
            s += statsIn[p * 2 * C + ch];
            q += statsIn[p * 2 * C + C + ch];
        }
        float m = s * (1.f / NROWS);
        float var = fmaxf(q * (1.f / NROWS) - m * m, 0.f);
        float sc = gamma[ch] * rsqrtf(var + EPSBN);
        scsh[ch] = sc;
        scsh[C + ch] = beta[ch] - m * sc;
    }
}

// ---------------------------------------------------------------------------
// k_gather16 (fp16 in): s[row] = bn_relu(a[row]) + sum_j bn_relu(a[knn_j]) -> fp16
// 8 ch/thread, 16-B loads, 17 independent loads in flight per thread.
// ---------------------------------------------------------------------------
template <int CIN>
__global__ __launch_bounds__(256) void k_gather16(
    const unsigned short* __restrict__ ain, const int* __restrict__ knn,
    const float* __restrict__ scsh, unsigned short* __restrict__ S)
{
    constexpr int GPR = CIN / 8;            // threads per row
    constexpr int R = 256 / GPR;            // rows per block
    constexpr int BPB = NPTS / R;

    __shared__ int nidx[R * KNN];

    int tid = threadIdx.x;
    int blk = blockIdx.x;
    int xcd = blk & 7;
    int idx = blk >> 3;
    int batch = xcd + 8 * (idx / BPB);
    int within = idx % BPB;
    int node0 = batch * NPTS + within * R;

    if (tid < R * KNN / 4) {
        const int4* ksrc = (const int4*)(knn + (size_t)node0 * KNN);
        ((int4*)nidx)[tid] = ksrc[tid];
    }
    __syncthreads();

    int t = tid & (GPR - 1);
    int r = tid / GPR;
    int col8 = t * 8;
    float sc8[8], sh8[8];
    #pragma unroll
    for (int j = 0; j < 8; j++) { sc8[j] = scsh[col8 + j]; sh8[j] = scsh[CIN + col8 + j]; }

    int row = node0 + r;
    const unsigned short* abase = ain + (size_t)batch * NPTS * CIN;

    float acc8[8];
    {
        uint4 v = *(const uint4*)(ain + (size_t)row * CIN + col8);
        unsigned wds[4] = {v.x, v.y, v.z, v.w};
        #pragma unroll
        for (int j = 0; j < 4; j++) {
            acc8[2*j]   = fmaxf(hu2f((unsigned short)(wds[j] & 0xFFFF)) * sc8[2*j]   + sh8[2*j],   0.f);
            acc8[2*j+1] = fmaxf(hu2f((unsigned short)(wds[j] >> 16))    * sc8[2*j+1] + sh8[2*j+1], 0.f);
        }
    }
    #pragma unroll
    for (int jn = 0; jn < KNN; jn++) {
        int src = nidx[r * KNN + jn];
        uint4 v = *(const uint4*)(abase + (size_t)src * CIN + col8);
        unsigned wds[4] = {v.x, v.y, v.z, v.w};
        #pragma unroll
        for (int j = 0; j < 4; j++) {
            acc8[2*j]   += fmaxf(hu2f((unsigned short)(wds[j] & 0xFFFF)) * sc8[2*j]   + sh8[2*j],   0.f);
            acc8[2*j+1] += fmaxf(hu2f((unsigned short)(wds[j] >> 16))    * sc8[2*j+1] + sh8[2*j+1], 0.f);
        }
    }
    uint4 o;
    o.x = f2hu(acc8[0]) | ((unsigned)f2hu(acc8[1]) << 16);
    o.y = f2hu(acc8[2]) | ((unsigned)f2hu(acc8[3]) << 16);
    o.z = f2hu(acc8[4]) | ((unsigned)f2hu(acc8[5]) << 16);
    o.w = f2hu(acc8[6]) | ((unsigned)f2hu(acc8[7]) << 16);
    *(uint4*)(S + (size_t)row * CIN + col8) = o;
}

// ---------------------------------------------------------------------------
// k_gemm<CIN,COUT,NSPLIT,STORE>: LDS-staged-A GEMM, small register-resident W.
// MT=128 rows/block. Grid = (NROWS/128)*NSPLIT. Each block handles COUT/NSPLIT
// channels; each wave 32 channels -> wf[KC][2] = KC*2 fragments (<=32 VGPR),
// trivially register-resident. Inner loop: 4 ds_read + MFMA only.
// N-blocks of one M-tile are consecutive on the same XCD (L2 A-reuse).
// ---------------------------------------------------------------------------
template <int CIN, int COUT, int NSPLIT, bool STORE>
__global__ __launch_bounds__(256) void k_gemm(
    const unsigned short* __restrict__ S, const unsigned short* __restrict__ WT,
    const float* __restrict__ bias,
    unsigned short* __restrict__ aout, float* __restrict__ statsOut, unsigned* __restrict__ mm)
{
    constexpr int KC = CIN / 32;
    constexpr int MT = 128;
    constexpr int SST = CIN + 8;            // LDS row stride (shorts)
    constexpr int CPB = COUT / NSPLIT;      // channels per block (128)
    constexpr int CPW = CPB / 4;            // channels per wave (32) -> NT=2
    constexpr int NT = CPW / 16;            // 2

    __shared__ alignas(16) unsigned short sA[MT * SST];

    int tid = threadIdx.x;
    int blk = blockIdx.x;
    int xcd = blk & 7;
    int rest = blk >> 3;                    // [0, 128*NSPLIT)
    int nq = rest % NSPLIT;
    int mseq = rest / NSPLIT;               // [0,128)
    int phase = mseq >> 6;                  // {0,1}
    int within = mseq & 63;                 // [0,64)
    int batch = xcd + 8 * phase;
    int node0 = batch * NPTS + within * MT;
    int cbase = nq * CPB;
    int pout = batch * 4 + (within >> 4);   // 64-way stats partition

    // ---- stage A: coalesced global read -> LDS (padded rows)
    {
        constexpr int TOT = MT * CIN / 8;   // uint4 count
        const uint4* src = (const uint4*)(S + (size_t)node0 * CIN);
        #pragma unroll
        for (int i = tid; i < TOT; i += 256) {
            int row = i / (CIN / 8);
            int col8 = (i % (CIN / 8)) * 8;
            *(uint4*)&sA[row * SST + col8] = src[i];
        }
    }
    __syncthreads();

    int lane = tid & 63, wv = tid >> 6;
    int n15 = lane & 15, qd = lane >> 4;
    int c0 = cbase + wv * CPW;

    // W fragments: KC*NT (<= 8) f16x8, register-resident
    f16x8 wf[KC][NT];
    float bz[NT];
    #pragma unroll
    for (int nt = 0; nt < NT; nt++) {
        int c = c0 + nt * 16 + n15;
        bz[nt] = bias[c];
        #pragma unroll
        for (int kc = 0; kc < KC; kc++)
            wf[kc][nt] = *(const f16x8*)(WT + (size_t)c * CIN + kc * 32 + qd * 8);
    }
    float sacc[NT], qacc[NT], mxa[NT], mna[NT];
    #pragma unroll
    for (int nt = 0; nt < NT; nt++) {
        sacc[nt] = 0.f; qacc[nt] = 0.f; mxa[nt] = -3.4e38f; mna[nt] = 3.4e38f;
    }

    #pragma unroll
    for (int mt = 0; mt < MT / 16; mt++) {
        f16x8 af[KC];
        #pragma unroll
        for (int kc = 0; kc < KC; kc++)
            af[kc] = *(const f16x8*)&sA[(mt * 16 + n15) * SST + kc * 32 + qd * 8];

        f32x4 acc[NT];
        #pragma unroll
        for (int nt = 0; nt < NT; nt++) acc[nt] = (f32x4)(0.f);
        #pragma unroll
        for (int kc = 0; kc < KC; kc++)
            #pragma unroll
            for (int nt = 0; nt < NT; nt++)
                acc[nt] = __builtin_amdgcn_mfma_f32_16x16x32_f16(af[kc], wf[kc][nt], acc[nt], 0, 0, 0);

        #pragma unroll
        for (int nt = 0; nt < NT; nt++) {
            int c = c0 + nt * 16 + n15;
            #pragma unroll
            for (int r = 0; r < 4; r++) {
                float a = acc[nt][r];
                sacc[nt] += a;
                qacc[nt] = fmaf(a, a, qacc[nt]);
                if (!STORE) {
                    mxa[nt] = fmaxf(mxa[nt], a);
                    mna[nt] = fminf(mna[nt], a);
                }
                if (STORE) {
                    float v = a * DEGINV + bz[nt];
                    int node = node0 + mt * 16 + qd * 4 + r;
                    aout[(size_t)node * COUT + c] = f2hu(v);
                }
            }
        }
    }

    // reduce over the wave's 4 row-quadrants; affine transform; atomics
    #pragma unroll
    for (int nt = 0; nt < NT; nt++) {
        int c = c0 + nt * 16 + n15;
        float S_ = sacc[nt], Q_ = qacc[nt];
        S_ += __shfl_xor(S_, 16); S_ += __shfl_xor(S_, 32);
        Q_ += __shfl_xor(Q_, 16); Q_ += __shfl_xor(Q_, 32);
        if (!STORE) {
            float mx = mxa[nt], mn = mna[nt];
            mx = fmaxf(mx, __shfl_xor(mx, 16)); mx = fmaxf(mx, __shfl_xor(mx, 32));
            mn = fminf(mn, __shfl_xor(mn, 16)); mn = fminf(mn, __shfl_xor(mn, 32));
            if (lane < 16) {
                atomicMax(mm + batch * COUT + c, fenc(mx * DEGINV + bz[nt]));
                atomicMin(mm + BATCH * COUT + batch * COUT + c, fenc(mn * DEGINV + bz[nt]));
            }
        }
        if (lane < 16) {
            float b = bz[nt];
            float s = DEGINV * S_ + (float)MT * b;
            float q = DEGINV * DEGINV * Q_ + 2.f * DEGINV * b * S_ + (float)MT * b * b;
            atomicAdd(statsOut + (size_t)pout * 2 * COUT + c, s);
            atomicAdd(statsOut + (size_t)pout * 2 * COUT + COUT + c, q);
        }
    }
}

// ---------------------------------------------------------------------------
// k_e2: pooled codeword from min/max + BN3, then Linear(512,512) -> a4, stats4
// ---------------------------------------------------------------------------
__global__ __launch_bounds__(256) void k_e2(
    const float* __restrict__ stats3p, const unsigned* __restrict__ mm,
    const float* __restrict__ g2g, const float* __restrict__ g2be,
    const float* __restrict__ e2w, const float* __restrict__ e2b,
    float* __restrict__ a4, float* __restrict__ stats4)
{
    __shared__ float pooled[512];
    int b = blockIdx.x, tid = threadIdx.x;
    for (int c = tid; c < 512; c += 256) {
        float s = 0.f, qq = 0.f;
        for (int p = 0; p < 64; p++) {
            s += stats3p[p * 1024 + c];
            qq += stats3p[p * 1024 + 512 + c];
        }
        float m = s * (1.f / NROWS);
        float var = fmaxf(qq * (1.f / NROWS) - m * m, 0.f);
        float sc = g2g[c] * rsqrtf(var + EPSBN);
        float sh = g2be[c] - m * sc;
        float amax = fdec(mm[b * 512 + c]);
        float amin = fdec(mm[8192 + b * 512 + c]);
        pooled[c] = fmaxf(fmaxf(sc * amax + sh, 0.f), fmaxf(sc * amin + sh, 0.f));
    }
    __syncthreads();
    int ca = tid, cb = tid + 256;
    float acc1 = e2b[ca], acc2 = e2b[cb];
    for (int f = 0; f < 512; f++) {
        float pv = pooled[f];
        acc1 += pv * e2w[f * 512 + ca];
        acc2 += pv * e2w[f * 512 + cb];
    }
    a4[b * 512 + ca] = acc1; a4[b * 512 + cb] = acc2;
    atomicAdd(stats4 + ca, acc1); atomicAdd(stats4 + 512 + ca, acc1 * acc1);
    atomicAdd(stats4 + cb, acc2); atomicAdd(stats4 + 512 + cb, acc2 * acc2);
}

// ---------------------------------------------------------------------------
// k_code: BN4+relu -> code; c1 = code@d1_w[:512], c2 = code@d2_w[:512]
// ---------------------------------------------------------------------------
__global__ __launch_bounds__(256) void k_code(
    const float* __restrict__ a4, const float* __restrict__ stats4,
    const float* __restrict__ e2g, const float* __restrict__ e2be,
    const float* __restrict__ d1w, const float* __restrict__ d2w,
    const float* __restrict__ gn,
    float* __restrict__ c1, float* __restrict__ c2,
    float* __restrict__ c1stats, float* __restrict__ gnstats)
{
    int b = blockIdx.x, tid = threadIdx.x;
    int lane = tid & 63, wv = tid >> 6;
    float p1[3] = {0, 0, 0}, p2[3] = {0, 0, 0};
    for (int c = tid; c < 512; c += 256) {
        float s = stats4[c], qq = stats4[512 + c];
        float m = s * (1.f / 16.f);
        float var = fmaxf(qq * (1.f / 16.f) - m * m, 0.f);
        float sc = e2g[c] * rsqrtf(var + EPSBN);
        float sh = e2be[c] - m * sc;
        float cv = fmaxf(sc * a4[b * 512 + c] + sh, 0.f);
        #pragma unroll
        for (int j = 0; j < 3; j++) {
            p1[j] += cv * d1w[c * 3 + j];
            p2[j] += cv * d2w[c * 3 + j];
        }
    }
    __shared__ float red[4][6];
    #pragma unroll
    for (int j = 0; j < 3; j++)
        for (int off = 32; off; off >>= 1) {
            p1[j] += __shfl_xor(p1[j], off);
            p2[j] += __shfl_xor(p2[j], off);
        }
    if (lane == 0) {
        #pragma unroll
        for (int j = 0; j < 3; j++) { red[wv][j] = p1[j]; red[wv][3 + j] = p2[j]; }
    }
    __syncthreads();
    if (tid < 3) {
        float v = red[0][tid] + red[1][tid] + red[2][tid] + red[3][tid];
        c1[b * 3 + tid] = v;
        atomicAdd(c1stats + tid, v);
        atomicAdd(c1stats + 3 + tid, v * v);
    } else if (tid < 6) {
        int j = tid - 3;
        float v = red[0][tid] + red[1][tid] + red[2][tid] + red[3][tid];
        c2[b * 3 + j] = v;
    }
    if (blockIdx.x == 0) {
        float g1[3] = {0, 0, 0}, g2s[3] = {0, 0, 0};
        for (int n = tid; n < NPTS; n += 256) {
            #pragma unroll
            for (int j = 0; j < 3; j++) {
                float g = gn[n * 3 + j];
                g1[j] += g; g2s[j] += g * g;
            }
        }
        #pragma unroll
        for (int j = 0; j < 3; j++)
            for (int off = 32; off; off >>= 1) {
                g1[j] += __shfl_xor(g1[j], off);
                g2s[j] += __shfl_xor(g2s[j], off);
            }
        __shared__ float redg[4][6];
        if (lane == 0) {
            #pragma unroll
            for (int j = 0; j < 3; j++) { redg[wv][j] = g1[j]; redg[wv][3 + j] = g2s[j]; }
        }
        __syncthreads();
        if (tid < 6)
            gnstats[tid] = redg[0][tid] + redg[1][tid] + redg[2][tid] + redg[3][tid];
    }
}

// ---------------------------------------------------------------------------
__device__ __forceinline__ void d1_coefs(
    const float* c1stats, const float* gnstats,
    const float* d1g, const float* d1be, float* scd, float* shd)
{
    #pragma unroll
    for (int j = 0; j < 3; j++) {
        float mc = c1stats[j] * (1.f / 16.f), qc = c1stats[3 + j] * (1.f / 16.f);
        float mg = gnstats[j] * (1.f / 8192.f), qg = gnstats[3 + j] * (1.f / 8192.f);
        float m = mc + mg;
        float var = fmaxf((qc - mc * mc) + (qg - mg * mg), 0.f);
        float sc = d1g[j] * rsqrtf(var + EPSBN);
        scd[j] = sc;
        shd[j] = d1be[j] - m * sc;
    }
}

// ---------------------------------------------------------------------------
__global__ __launch_bounds__(256) void k_d2stats(
    const float* __restrict__ c1, const float* __restrict__ c2, const float* __restrict__ gn,
    const float* __restrict__ c1stats, const float* __restrict__ gnstats,
    const float* __restrict__ d1g, const float* __restrict__ d1be,
    const float* __restrict__ d2w, const float* __restrict__ d2b,
    float* __restrict__ statsd2)
{
    int gid = blockIdx.x * 256 + threadIdx.x;
    int b = gid >> 13, n = gid & 8191;
    int lane = threadIdx.x & 63, wv = threadIdx.x >> 6;
    float scd[3], shd[3];
    d1_coefs(c1stats, gnstats, d1g, d1be, scd, shd);
    float z3[3];
    #pragma unroll
    for (int j = 0; j < 3; j++)
        z3[j] = fmaxf(scd[j] * (c1[b * 3 + j] + gn[n * 3 + j]) + shd[j], 0.f);
    float vals[6];
    #pragma unroll
    for (int u = 0; u < 3; u++) {
        float a = c2[b * 3 + u]
                + z3[0] * d2w[512 * 3 + u]
                + z3[1] * d2w[513 * 3 + u]
                + z3[2] * d2w[514 * 3 + u]
                + d2b[u];
        vals[u] = a; vals[3 + u] = a * a;
    }
    #pragma unroll
    for (int j = 0; j < 6; j++)
        for (int off = 32; off; off >>= 1) vals[j] += __shfl_xor(vals[j], off);
    __shared__ float red[4][6];
    if (lane == 0) {
        #pragma unroll
        for (int j = 0; j < 6; j++) red[wv][j] = vals[j];
    }
    __syncthreads();
    if (threadIdx.x < 6)
        atomicAdd(statsd2 + threadIdx.x,
                  red[0][threadIdx.x] + red[1][threadIdx.x] + red[2][threadIdx.x] + red[3][threadIdx.x]);
}

// ---------------------------------------------------------------------------
__global__ __launch_bounds__(256) void k_out(
    const float* __restrict__ c1, const float* __restrict__ c2, const float* __restrict__ gn,
    const float* __restrict__ c1stats, const float* __restrict__ gnstats,
    const float* __restrict__ statsd2,
    const float* __restrict__ d1g, const float* __restrict__ d1be,
    const float* __restrict__ d2w, const float* __restrict__ d2b,
    const float* __restrict__ d2g, const float* __restrict__ d2be,
    float* __restrict__ out)
{
    int gid = blockIdx.x * 256 + threadIdx.x;
    int b = gid >> 13, n = gid & 8191;
    float scd[3], shd[3];
    d1_coefs(c1stats, gnstats, d1g, d1be, scd, shd);
    float z3[3];
    #pragma unroll
    for (int j = 0; j < 3; j++)
        z3[j] = fmaxf(scd[j] * (c1[b * 3 + j] + gn[n * 3 + j]) + shd[j], 0.f);
    #pragma unroll
    for (int u = 0; u < 3; u++) {
        float a = c2[b * 3 + u]
                + z3[0] * d2w[512 * 3 + u]
                + z3[1] * d2w[513 * 3 + u]
                + z3[2] * d2w[514 * 3 + u]
                + d2b[u];
        float m2 = statsd2[u] * (1.f / (float)NROWS);
        float v2 = fmaxf(statsd2[3 + u] * (1.f / (float)NROWS) - m2 * m2, 0.f);
        float sc = d2g[u] * rsqrtf(v2 + EPSBN);
        float sh = d2be[u] - m2 * sc;
        out[(size_t)gid * 3 + u] = fmaxf(sc * a + sh, 0.f);
    }
}

// ---------------------------------------------------------------------------
extern "C" void kernel_launch(void* const* d_in, const int* in_sizes, int n_in,
                              void* d_out, int out_size, void* d_ws, size_t ws_size,
                              hipStream_t stream)
{
    (void)in_sizes; (void)n_in; (void)out_size; (void)ws_size;
    const float* data = (const float*)d_in[0];
    const int*   knn  = (const int*)d_in[1];
    const float* e1w = (const float*)d_in[2],  *e1b = (const float*)d_in[3];
    const float* e1g = (const float*)d_in[4],  *e1be = (const float*)d_in[5];
    const float* gc1w = (const float*)d_in[6], *gc1b = (const float*)d_in[7];
    const float* g1g = (const float*)d_in[8],  *g1be = (const float*)d_in[9];
    const float* gc2w = (const float*)d_in[10], *gc2b = (const float*)d_in[11];
    const float* g2g = (const float*)d_in[12], *g2be = (const float*)d_in[13];
    const float* e2w = (const float*)d_in[14], *e2b = (const float*)d_in[15];
    const float* e2g = (const float*)d_in[16], *e2be = (const float*)d_in[17];
    const float* d1w = (const float*)d_in[18], *d1b = (const float*)d_in[19];
    const float* d1g = (const float*)d_in[20], *d1be = (const float*)d_in[21];
    const float* d2w = (const float*)d_in[22], *d2b = (const float*)d_in[23];
    const float* d2g = (const float*)d_in[24], *d2be = (const float*)d_in[25];

    char* p = (char*)d_ws;
    auto alloc = [&](size_t bytes) -> void* {
        void* r = (void*)p;
        p += (bytes + 255) & ~(size_t)255;
        return r;
    };
    unsigned short* a1  = (unsigned short*)alloc((size_t)NROWS * 64 * 2);  // 16.8 MB fp16
    unsigned short* a2h = (unsigned short*)alloc((size_t)NROWS * 128 * 2); // 33.5 MB fp16
    unsigned short* s1  = (unsigned short*)alloc((size_t)NROWS * 64 * 2);  // 16.8 MB fp16
    unsigned short* s2  = (unsigned short*)alloc((size_t)NROWS * 128 * 2); // 33.5 MB fp16
    unsigned short* W1T = (unsigned short*)alloc(8192 * 2);
    unsigned short* W2T = (unsigned short*)alloc(65536 * 2);
    float* statszone = (float*)alloc(SZ_TOT * 4);
    float* stats1  = statszone + SZ_S1;
    float* stats2p = statszone + SZ_S2P;
    float* stats3p = statszone + SZ_S3P;
    float* stats4  = statszone + SZ_S4;
    float* c1stats = statszone + SZ_C1;
    float* gnstats = statszone + SZ_GN;
    float* statsd2 = statszone + SZ_D2;
    float* scsh1   = statszone + SZ_SCSH1;
    float* scsh2   = statszone + SZ_SCSH2;
    unsigned* mm = (unsigned*)alloc(16384 * 4);
    float* a4 = (float*)alloc(16 * 512 * 4);
    float* c1 = (float*)alloc(64 * 4);
    float* c2 = (float*)alloc(64 * 4);
    float* gn = (float*)alloc(8192 * 3 * 4);

    k_prep<<<64, 256, 0, stream>>>(gc1w, gc2w, d1w, d1b, W1T, W2T, gn, statszone, mm);
    k_cov_e1<<<512, 256, 0, stream>>>(data, knn, e1w, e1b, a1);
    k_reduce_a1<<<256, 256, 0, stream>>>(a1, stats1);
    k_bncoef<64, 1><<<1, 256, 0, stream>>>(stats1, e1g, e1be, scsh1);
    k_gather16<64><<<NROWS / 32, 256, 0, stream>>>(a1, knn, scsh1, s1);
    k_gemm<64, 128, 1, true><<<1024, 256, 0, stream>>>(s1, W1T, gc1b, a2h, stats2p, nullptr);
    k_bncoef<128, 64><<<1, 256, 0, stream>>>(stats2p, g1g, g1be, scsh2);
    k_gather16<128><<<NROWS / 16, 256, 0, stream>>>(a2h, knn, scsh2, s2);
    k_gemm<128, 512, 4, false><<<4096, 256, 0, stream>>>(s2, W2T, gc2b, nullptr, stats3p, mm);
    k_e2<<<16, 256, 0, stream>>>(stats3p, mm, g2g, g2be, e2w, e2b, a4, stats4);
    k_code<<<16, 256, 0, stream>>>(a4, stats4, e2g, e2be, d1w, d2w, gn, c1, c2, c1stats, gnstats);
    k_d2stats<<<512, 256, 0, stream>>>(c1, c2, gn, c1stats, gnstats, d1g, d1be, d2w, d2b, statsd2);
    k_out<<<512, 256, 0, stream>>>(c1, c2, gn, c1stats, gnstats, statsd2,
                                   d1g, d1be, d2w, d2b, d2g, d2be, (float*)d_out);
}